// Round 10
// baseline (2464.082 us; speedup 1.0000x reference)
//
#include <hip/hip_runtime.h>
#include <cfloat>
#include <cmath>

// ---------------------------------------------------------------------------
// Round 9: decoder memory fixes.
// (1) convt_mfma grid: XCD-slab swizzle (bx%8 -> slab of consecutive nt;
//     parity + mg inner). Each XCD's input slab stays L2-resident across all
//     8 parity sweeps -> kills the 330 MB dec3 overfetch.
// (2) d3 stored bf16 (RNE) instead of fp32: dec3 write traffic halves; dec4's
//     re-read working set 67->33.5 MB (~fits aggregate L2). dec4 consumed a
//     bf16 cast of d3 anyway -> numerics unchanged at recon scale.
// Encoder (bf16-pair MFMA) / VQ unchanged from R8.
// ---------------------------------------------------------------------------

using f32x4  = __attribute__((ext_vector_type(4))) float;
using bf16x8 = __attribute__((ext_vector_type(8))) short;
typedef float f32x4u __attribute__((ext_vector_type(4), aligned(4)));
typedef unsigned short u16x4u __attribute__((ext_vector_type(4), aligned(4)));
typedef unsigned short u16x4a __attribute__((ext_vector_type(4), aligned(2)));

__device__ __forceinline__ unsigned short f32_to_bf16(float f) {
    unsigned int u = __float_as_uint(f);
    u += 0x7fffu + ((u >> 16) & 1u);          // round-to-nearest-even
    return (unsigned short)(u >> 16);
}
__device__ __forceinline__ void split_bf16(float v, unsigned short& h, unsigned short& l) {
    h = f32_to_bf16(v);
    float hf = __uint_as_float((unsigned)h << 16);
    l = f32_to_bf16(v - hf);
}
__device__ __forceinline__ void store_act(float* p, float v) { *p = v; }
__device__ __forceinline__ void store_act(unsigned short* p, float v) { *p = f32_to_bf16(v); }

template <typename V>
__device__ __forceinline__ bf16x8 pack_b(V r0, V r1) {
    bf16x8 b;
    b[0] = (short)r0[0]; b[1] = (short)r0[1]; b[2] = (short)r0[2]; b[3] = (short)r0[3];
    b[4] = (short)r1[0]; b[5] = (short)r1[1]; b[6] = (short)r1[2]; b[7] = (short)r1[3];
    return b;
}

// ---------------- prep: weight hi/lo split ----------------
__global__ __launch_bounds__(256)
void prep_split_w(const float* __restrict__ w, short* __restrict__ whi,
                  short* __restrict__ wlo, long total)
{
    long idx = (long)blockIdx.x * blockDim.x + threadIdx.x;
    if (idx >= total) return;
    unsigned short h, l;
    split_bf16(w[idx], h, l);
    whi[idx] = (short)h; wlo[idx] = (short)l;
}

// ---------------- pad input -> hi/lo bf16 pitched planes --------------------
__global__ __launch_bounds__(256)
void pad_input_split(const float* __restrict__ x, unsigned short* __restrict__ xhi,
                     unsigned short* __restrict__ xlo)
{
    const int D = 64, PD = 66, PRX = 68, BC = 6;
    long total = (long)BC * PD * PD * PRX;
    long idx = (long)blockIdx.x * blockDim.x + threadIdx.x;
    if (idx >= total) return;
    int px = (int)(idx % PRX); long t = idx / PRX;
    int py = (int)(t % PD); t /= PD;
    int pz = (int)(t % PD); int c = (int)(t / PD);
    int ix = px - 1, iy = py - 1, iz = pz - 1;
    float v = 0.0f;
    if ((unsigned)ix < (unsigned)D && (unsigned)iy < (unsigned)D && (unsigned)iz < (unsigned)D)
        v = x[(((long)c * D + iz) * D + iy) * D + ix];
    unsigned short h, l;
    split_bf16(v, h, l);
    xhi[idx] = h; xlo[idx] = l;
}

__global__ __launch_bounds__(256)
void zero_halo_ps(unsigned short* __restrict__ p, int C, int PD, int PRX)
{
    long total = (long)C * PD * PD * PRX;
    long idx = (long)blockIdx.x * blockDim.x + threadIdx.x;
    if (idx >= total) return;
    int px = (int)(idx % PRX); long t = idx / PRX;
    int py = (int)(t % PD); t /= PD;
    int pz = (int)(t % PD);
    if (px == 0 || px >= PD - 1 || py == 0 || py == PD - 1 || pz == 0 || pz == PD - 1)
        p[idx] = 0;
}

template <typename T>
__global__ __launch_bounds__(256) void zero_halo_t(T* __restrict__ p, int C, int PD)
{
    long total = (long)C * PD * PD * PD;
    long idx = (long)blockIdx.x * blockDim.x + threadIdx.x;
    if (idx >= total) return;
    int px = (int)(idx % PD); long t = idx / PD;
    int py = (int)(t % PD); t /= PD;
    int pz = (int)(t % PD);
    if (px == 0 || px == PD - 1 || py == 0 || py == PD - 1 || pz == 0 || pz == PD - 1)
        p[idx] = (T)0;
}

// ---------------------------------------------------------------------------
// Conv3d k4 s2 p1 as MFMA implicit GEMM, bf16 hi/lo pair inputs (R8, unchanged)
// ---------------------------------------------------------------------------
template <int CIN, int COUT, int DOUT, int PD, int PRX, int MTW, int OWT,
          int OWHALF, int KSPLIT, int OUTSPLIT>
__global__ __launch_bounds__(256)
void conv_s2_mfma(const unsigned short* __restrict__ xhi,
                  const unsigned short* __restrict__ xlo,
                  const short* __restrict__ Whi, const short* __restrict__ Wlo,
                  const float* __restrict__ bias,
                  unsigned short* __restrict__ yhi, unsigned short* __restrict__ ylo,
                  float* __restrict__ yf,
                  int OPD, int OPRX, int po, long sstride)
{
    constexpr int K = CIN * 64;
    constexpr int MWAVES = COUT / (16 * MTW);
    constexpr int RPB = 4 / MWAVES;
    constexpr int KN = (CIN * 2) / KSPLIT;

    int bx = blockIdx.x;
    const int ks = (KSPLIT > 1) ? (bx % KSPLIT) : 0;
    const int rowblk = (KSPLIT > 1) ? (bx / KSPLIT) : bx;
    const int lane = (int)threadIdx.x & 63, w = (int)threadIdx.x >> 6;
    const int mi = (MWAVES == 4) ? w : 0;
    const int ri = (MWAVES == 4) ? 0 : w;
    const int rowid = rowblk * RPB + ri;
    const int n16 = lane & 15, quad = lane >> 4;

    int b, od, oh, ow;
    if (OWHALF) {
        constexpr int NOH = DOUT / 2;
        const int ohb = rowid % NOH; int t = rowid / NOH;
        od = t % DOUT; b = t / DOUT;
        oh = ohb * 2 + (n16 >> 3);
        ow = n16 & 7;
    } else {
        const int owt = rowid % OWT; int t = rowid / OWT;
        oh = t % DOUT; t /= DOUT;
        od = t % DOUT; b = t / DOUT;
        ow = owt * 16 + n16;
    }

    const int co0 = mi * (MTW * 16);

    f32x4 acc[MTW];
    #pragma unroll
    for (int mt = 0; mt < MTW; ++mt)
        #pragma unroll
        for (int r = 0; r < 4; ++r) {
            int co = co0 + mt * 16 + quad * 4 + r;
            acc[mt][r] = (ks == 0) ? bias[co] : 0.0f;
        }

    const int sg0 = ks * KN;
    const long chs = (long)PD * PD * PRX;
    long off = ((long)(b * CIN + (sg0 >> 1)) * PD + (2 * od + (quad >> 1))) * PD * PRX
             + (long)(2 * oh + (quad & 1) * 2) * PRX + 2 * ow;
    const unsigned short* phi = xhi + off;
    const unsigned short* plo = xlo + off;
    const long incA = 2L * PD * PRX;
    const long incB = chs - 2L * PD * PRX;

    const short* a0h = Whi + (long)(co0 + n16) * K + sg0 * 32 + quad * 8;
    const short* a0l = Wlo + (long)(co0 + n16) * K + sg0 * 32 + quad * 8;

    #pragma unroll 2
    for (int s = 0; s < KN; ++s) {
        u16x4u h0 = *(const u16x4u*)phi;
        u16x4u h1 = *(const u16x4u*)(phi + PRX);
        u16x4u l0 = *(const u16x4u*)plo;
        u16x4u l1 = *(const u16x4u*)(plo + PRX);
        bf16x8 bhi = pack_b(h0, h1);
        bf16x8 blo = pack_b(l0, l1);
        #pragma unroll
        for (int mt = 0; mt < MTW; ++mt) {
            bf16x8 ah = *(const bf16x8*)(a0h + (long)mt * 16 * K + s * 32);
            bf16x8 al = *(const bf16x8*)(a0l + (long)mt * 16 * K + s * 32);
            acc[mt] = __builtin_amdgcn_mfma_f32_16x16x32_bf16(ah, bhi, acc[mt], 0, 0, 0);
            acc[mt] = __builtin_amdgcn_mfma_f32_16x16x32_bf16(ah, blo, acc[mt], 0, 0, 0);
            acc[mt] = __builtin_amdgcn_mfma_f32_16x16x32_bf16(al, bhi, acc[mt], 0, 0, 0);
        }
        long inc = (s & 1) ? incB : incA;
        phi += inc; plo += inc;
    }

    if (OUTSPLIT) {
        #pragma unroll
        for (int mt = 0; mt < MTW; ++mt)
            #pragma unroll
            for (int r = 0; r < 4; ++r) {
                int co = co0 + mt * 16 + quad * 4 + r;
                float v = fmaxf(acc[mt][r], 0.0f);
                unsigned short h, l;
                split_bf16(v, h, l);
                long o = (((long)(b * COUT + co) * OPD + od + po) * OPD + oh + po) * OPRX
                       + ow + po;
                yhi[o] = h; ylo[o] = l;
            }
    } else {
        #pragma unroll
        for (int mt = 0; mt < MTW; ++mt)
            #pragma unroll
            for (int r = 0; r < 4; ++r) {
                int co = co0 + mt * 16 + quad * 4 + r;
                long o = (long)ks * sstride
                       + (((long)(b * COUT + co) * OPD + od) * OPD + oh) * OPRX + ow;
                yf[o] = acc[mt][r];
            }
    }
}

__global__ __launch_bounds__(256)
void combine4_relu(const float* __restrict__ p, float* __restrict__ y, long N, long ss)
{
    long idx = (long)blockIdx.x * blockDim.x + threadIdx.x;
    if (idx >= N) return;
    float v = p[idx] + p[idx + ss] + p[idx + 2 * ss] + p[idx + 3 * ss];
    y[idx] = fmaxf(v, 0.0f);
}

// ---------------- 1x1 conv (fp32 exact) ----------------
__global__ __launch_bounds__(128)
void conv1x1_b(const float* __restrict__ x, const float* __restrict__ w,
               const float* __restrict__ bias, float* __restrict__ y)
{
    const int co = blockIdx.x & 255, b = blockIdx.x >> 8;
    const int s4 = (int)threadIdx.x * 4;
    const float* xb = x + (long)b * 256 * 512 + s4;
    const float* wr = w + (long)co * 256;      // uniform -> s_load
    float bv = bias[co];
    float4 acc = {bv, bv, bv, bv};
    for (int ci = 0; ci < 256; ++ci) {
        float wv = wr[ci];
        float4 xv = *(const float4*)(xb + (long)ci * 512);
        acc.x = fmaf(xv.x, wv, acc.x); acc.y = fmaf(xv.y, wv, acc.y);
        acc.z = fmaf(xv.z, wv, acc.z); acc.w = fmaf(xv.w, wv, acc.w);
    }
    *(float4*)(y + (long)(b * 256 + co) * 512 + s4) = acc;
}

// ---------------- VQ (fp32 exact; unchanged) ----------------
__global__ void codenorm_kernel(const float* __restrict__ cb, float* __restrict__ norms)
{
    int k = blockIdx.x;
    int lane = threadIdx.x;
    float s = 0.0f;
    const float* row = cb + (long)k * 256;
    for (int d = lane; d < 256; d += 64) { float v = row[d]; s = fmaf(v, v, s); }
    for (int off = 32; off > 0; off >>= 1) s += __shfl_down(s, off);
    if (lane == 0) norms[k] = s;
}

__global__ __launch_bounds__(256)
void vq_kernel(const float* __restrict__ lat, const float* __restrict__ cb,
               const float* __restrict__ norms, unsigned short* __restrict__ q,
               float* __restrict__ idx_out)
{
    __shared__ __align__(16) float row[256];
    __shared__ float s_best[256];
    __shared__ int   s_bidx[256];
    int r = blockIdx.x;
    int t = threadIdx.x;
    row[t] = lat[(long)r * 256 + t];
    __syncthreads();

    const float4* rowv = (const float4*)row;
    float latn = 0.0f;
    #pragma unroll 4
    for (int d = 0; d < 64; ++d) {
        float4 rv = rowv[d];
        latn = fmaf(rv.x, rv.x, latn); latn = fmaf(rv.y, rv.y, latn);
        latn = fmaf(rv.z, rv.z, latn); latn = fmaf(rv.w, rv.w, latn);
    }

    float best = FLT_MAX;
    int bidx = 0x7fffffff;
    for (int j = 0; j < 4; ++j) {
        int k = t + 256 * j;
        const float4* cr = (const float4*)(cb + (long)k * 256);
        float dot = 0.0f;
        #pragma unroll 4
        for (int d = 0; d < 64; ++d) {
            float4 c = cr[d]; float4 rv = rowv[d];
            dot = fmaf(rv.x, c.x, dot); dot = fmaf(rv.y, c.y, dot);
            dot = fmaf(rv.z, c.z, dot); dot = fmaf(rv.w, c.w, dot);
        }
        float sc = latn - 2.0f * dot + norms[k];
        if (sc < best || (sc == best && k < bidx)) { best = sc; bidx = k; }
    }
    s_best[t] = best; s_bidx[t] = bidx;
    __syncthreads();
    for (int off = 128; off > 0; off >>= 1) {
        if (t < off) {
            float o = s_best[t + off]; int oi = s_bidx[t + off];
            if (o < s_best[t] || (o == s_best[t] && oi < s_bidx[t])) {
                s_best[t] = o; s_bidx[t] = oi;
            }
        }
        __syncthreads();
    }
    int bk = s_bidx[0];
    int b = r >> 9, n = r & 511;
    int zz = n >> 6, yy = (n >> 3) & 7, xx = n & 7;
    q[(long)(b * 256 + t) * 1000 + ((long)(zz + 1) * 10 + (yy + 1)) * 10 + (xx + 1)]
        = f32_to_bf16(cb[(long)bk * 256 + t]);
    if (t == 0) idx_out[r] = (float)bk;
}

// ---------------- decoder: MFMA implicit-GEMM ConvTranspose ----------------
__global__ __launch_bounds__(256)
void prep_convt_w(const float* __restrict__ w, short* __restrict__ Ap,
                  int Cin, int Cout)
{
    const int K = Cin * 8;
    long total = 8L * Cout * K;
    long idx = (long)blockIdx.x * blockDim.x + threadIdx.x;
    if (idx >= total) return;
    int k = (int)(idx % K);
    int co = (int)((idx / K) % Cout);
    int p = (int)(idx / ((long)K * Cout));
    int ci = k >> 3, a = k & 7;
    int az = (a >> 2) & 1, ay = (a >> 1) & 1, ax = a & 1;
    int pz = p >> 2, py = (p >> 1) & 1, px = p & 1;
    int kd = (1 - pz) + 2 * az, kh = (1 - py) + 2 * ay, kw = (1 - px) + 2 * ax;
    float v = w[((long)ci * Cout + co) * 64 + kd * 16 + kh * 4 + kw];
    Ap[idx] = (short)f32_to_bf16(v);
}

// Grid: bx = local*8 + xcd; nt = xcd*(NT/8) + local%SLAB; p, mg inner.
// Each XCD sweeps one contiguous nt-slab for all 8 parities -> slab stays
// L2-resident, kills the cross-parity refetch (R8: 330 MB -> ~compulsory).
template <int DIN, int OPAD, typename OutT>
__global__ __launch_bounds__(256)
void convt_mfma(const unsigned short* __restrict__ Xp, const short* __restrict__ Ap,
                const float* __restrict__ bias, OutT* __restrict__ Y,
                int Cin, int Cout)
{
    constexpr int PD = DIN + 2;
    constexpr int PD3 = PD * PD * PD;
    constexpr int T = DIN >> 2;
    constexpr int NT = T * T * T;
    constexpr int SLAB = NT / 8;
    constexpr int OPD = 2 * DIN + 2 * OPAD;
    const int K = Cin * 8;
    const int MG = Cout >> 6;

    int bx = blockIdx.x;
    const int xcd = bx & 7;
    int local = bx >> 3;
    const int mg = local % MG; local /= MG;
    const int ntin = local % SLAB;
    const int p = local / SLAB;
    const int nt = xcd * SLAB + ntin;
    const int pz = p >> 2, py = (p >> 1) & 1, px = p & 1;

    const int lane = threadIdx.x & 63, wave = threadIdx.x >> 6;
    const int n16 = lane & 15, quad = lane >> 4;

    const int tx = nt % T, ty = (nt / T) % T, tz = nt / (T * T);
    const int mz = tz * 4 + wave, my = ty * 4 + (n16 >> 2), mx = tx * 4 + (n16 & 3);
    const int sp = ((mz + pz) * PD + (my + py)) * PD + (mx + px);

    const unsigned short* xq = Xp + (long)quad * PD3 + sp;

    const int cobase = mg * 64;
    const short* ap0 = Ap + ((long)p * Cout + cobase + n16) * K + quad * 8;

    f32x4 acc[4];
    #pragma unroll
    for (int cb = 0; cb < 4; ++cb) {
        const float* bp = bias + cobase + cb * 16 + quad * 4;
        acc[cb][0] = bp[0]; acc[cb][1] = bp[1]; acc[cb][2] = bp[2]; acc[cb][3] = bp[3];
    }

    const int nsteps = K >> 5;
    for (int s = 0; s < nsteps; ++s) {
        bf16x8 bf;
        bf[0] = (short)xq[(PD + 1) * PD + 1];
        bf[1] = (short)xq[(PD + 1) * PD];
        bf[2] = (short)xq[PD * PD + 1];
        bf[3] = (short)xq[PD * PD];
        bf[4] = (short)xq[PD + 1];
        bf[5] = (short)xq[PD];
        bf[6] = (short)xq[1];
        bf[7] = (short)xq[0];
        #pragma unroll
        for (int cb = 0; cb < 4; ++cb) {
            bf16x8 af = *(const bf16x8*)(ap0 + (long)cb * 16 * K + s * 32);
            acc[cb] = __builtin_amdgcn_mfma_f32_16x16x32_bf16(af, bf, acc[cb], 0, 0, 0);
        }
        xq += 4 * PD3;
    }

    const int opz = 2 * mz + pz + OPAD, opy = 2 * my + py + OPAD, opx = 2 * mx + px + OPAD;
    const long spo = ((long)opz * OPD + opy) * OPD + opx;
    #pragma unroll
    for (int cb = 0; cb < 4; ++cb) {
        #pragma unroll
        for (int r = 0; r < 4; ++r) {
            int co = cobase + cb * 16 + quad * 4 + r;
            float v = fmaxf(acc[cb][r], 0.0f);
            store_act(Y + (long)co * OPD * OPD * OPD + spo, v);
        }
    }
}

// ---------------- dec4 as MFMA GEMM: d3 now bf16 ----------------
__global__ __launch_bounds__(256)
void prep_dec4A(const float* __restrict__ w, short* __restrict__ Aw)
{
    int idx = blockIdx.x * 256 + (int)threadIdx.x;    // 0..65535
    int m = idx >> 12, k = idx & 4095;
    float v = (m < 3) ? w[m * 4096 + k] : 0.0f;
    Aw[idx] = (short)f32_to_bf16(v);
}

__global__ __launch_bounds__(256)
void conv_dec4_mfma(const unsigned short* __restrict__ d3, const short* __restrict__ Aw,
                    const float* __restrict__ bias, float* __restrict__ y)
{
    constexpr int D = 64, Dout = 61;
    const int oh = blockIdx.x % Dout, od = blockIdx.x / Dout;
    const int lane = (int)threadIdx.x & 63, wave = (int)threadIdx.x >> 6;
    const int n16 = lane & 15, quad = lane >> 4;
    const int ow = wave * 16 + n16;

    f32x4 acc;
    #pragma unroll
    for (int r = 0; r < 4; ++r) {
        int co = quad * 4 + r;
        acc[r] = (co < 3) ? bias[co] : 0.0f;
    }

    const short* ap = Aw + (long)n16 * 4096 + quad * 8;   // m = lane&15
    const int kd0 = quad >> 1;
    const int kh0 = (quad & 1) * 2;
    const unsigned short* base0 = d3 + ((long)(od + kd0) * D + (oh + kh0)) * D + ow;

    #pragma unroll 4
    for (int s = 0; s < 128; ++s) {
        const int ci = s >> 1;
        const unsigned short* base = base0 + ((long)ci * D + (s & 1) * 2) * D * D;
        u16x4a r0 = *(const u16x4a*)base;          // (kd, kh,   kw=0..3)
        u16x4a r1 = *(const u16x4a*)(base + D);    // (kd, kh+1, kw=0..3)
        bf16x8 bf = pack_b(r0, r1);
        bf16x8 af = *(const bf16x8*)(ap + s * 32);
        acc = __builtin_amdgcn_mfma_f32_16x16x32_bf16(af, bf, acc, 0, 0, 0);
    }

    if (ow < Dout && quad == 0) {
        #pragma unroll
        for (int r = 0; r < 3; ++r)
            y[((long)(r * Dout + od) * Dout + oh) * Dout + ow] = tanhf(acc[r]);
    }
}

extern "C" void kernel_launch(void* const* d_in, const int* in_sizes, int n_in,
                              void* d_out, int out_size, void* d_ws, size_t ws_size,
                              hipStream_t stream)
{
    const float* x        = (const float*)d_in[0];
    const float* enc_w1   = (const float*)d_in[1];
    const float* enc_b1   = (const float*)d_in[2];
    const float* enc_w2   = (const float*)d_in[3];
    const float* enc_b2   = (const float*)d_in[4];
    const float* enc_w3   = (const float*)d_in[5];
    const float* enc_b3   = (const float*)d_in[6];
    const float* enc_w4   = (const float*)d_in[7];
    const float* enc_b4   = (const float*)d_in[8];
    const float* codebook = (const float*)d_in[9];
    const float* dec_w1   = (const float*)d_in[10];
    const float* dec_b1   = (const float*)d_in[11];
    const float* dec_w2   = (const float*)d_in[12];
    const float* dec_b2   = (const float*)d_in[13];
    const float* dec_w3   = (const float*)d_in[14];
    const float* dec_b3   = (const float*)d_in[15];
    const float* dec_w4   = (const float*)d_in[16];
    const float* dec_b4   = (const float*)d_in[17];

    float* out = (float*)d_out;
    float* idx_out = out + 2L * 3 * 61 * 61 * 61;

    // ---- workspace (byte offsets) ----
    char* wsb = (char*)d_ws;
    float*          cn   = (float*)wsb;                        //      4,096
    unsigned short* qp   = (unsigned short*)(wsb + 4096);      //  1,024,000
    short*          Ap1  = (short*)(wsb + 1028096);            //  8,388,608
    short*          Ap2  = (short*)(wsb + 9416704);            //  4,194,304
    short*          Ap3  = (short*)(wsb + 13611008);           //  1,048,576
    short*          Aw4  = (short*)(wsb + 14659584);           //    131,072
    short*          W1hi = (short*)(wsb + 14790656);           //     24,576
    short*          W1lo = (short*)(wsb + 14815232);           //     24,576
    short*          W2hi = (short*)(wsb + 14839808);           //  1,048,576
    short*          W2lo = (short*)(wsb + 15888384);           //  1,048,576
    short*          W3hi = (short*)(wsb + 16936960);           //  4,194,304
    short*          W3lo = (short*)(wsb + 21131264);           //  4,194,304
    char* arena = wsb + 25325568;
    // encoder phase:
    unsigned short* xphi = (unsigned short*)arena;                    // (2,3,66,66,68)
    unsigned short* xplo = (unsigned short*)(arena + 3554496);
    unsigned short* h1hi = (unsigned short*)(arena + 7108992);        // (2,64,34,34,36)
    unsigned short* h1lo = (unsigned short*)(arena + 17762688);
    unsigned short* h2hi = (unsigned short*)(arena + 28416384);       // (2,128,18,18,20)
    unsigned short* h2lo = (unsigned short*)(arena + 31734144);
    float*          pp3  = (float*)(arena + 35051904);                // 4x(2,256,8^3)
    float*          h3   = (float*)(arena + 39246208);                // (2,256,512)
    float*          lat  = (float*)(arena + 40294784);                // (2,256,512)
    // decoder phase (after VQ; overlaps encoder buffers):
    unsigned short* d1 = (unsigned short*)arena;                      // (256,18^3) bf16
    unsigned short* d2 = (unsigned short*)(arena + 2985984);          // (128,34^3) bf16
    unsigned short* d3 = (unsigned short*)(arena + 13047808);         // (64,64^3) bf16
    // arena peak 80.2 MB; total 105.5 MB (< 112.2 MB proven in R0)

    dim3 blk(256);
    auto nblk = [](long n) { return dim3((unsigned)((n + 255) / 256)); };

    // ---- weight prep ----
    prep_convt_w<<<nblk(8L * 256 * 2048), blk, 0, stream>>>(dec_w1, Ap1, 256, 256);
    prep_convt_w<<<nblk(8L * 128 * 2048), blk, 0, stream>>>(dec_w2, Ap2, 256, 128);
    prep_convt_w<<<nblk(8L * 64 * 1024), blk, 0, stream>>>(dec_w3, Ap3, 128, 64);
    prep_dec4A<<<dim3(256), blk, 0, stream>>>(dec_w4, Aw4);
    prep_split_w<<<nblk(12288), blk, 0, stream>>>(enc_w1, W1hi, W1lo, 12288);
    prep_split_w<<<nblk(524288), blk, 0, stream>>>(enc_w2, W2hi, W2lo, 524288);
    prep_split_w<<<nblk(2097152), blk, 0, stream>>>(enc_w3, W3hi, W3lo, 2097152);

    // ---- encoder (MFMA, bf16-pair) ----
    pad_input_split<<<nblk(6L * 66 * 66 * 68), blk, 0, stream>>>(x, xphi, xplo);
    zero_halo_ps<<<nblk(128L * 34 * 34 * 36), blk, 0, stream>>>(h1hi, 128, 34, 36);
    zero_halo_ps<<<nblk(128L * 34 * 34 * 36), blk, 0, stream>>>(h1lo, 128, 34, 36);
    conv_s2_mfma<3, 64, 32, 66, 68, 4, 2, 0, 1, 1><<<dim3(1024), blk, 0, stream>>>(
        xphi, xplo, W1hi, W1lo, enc_b1, h1hi, h1lo, nullptr, 34, 36, 1, 0);
    zero_halo_ps<<<nblk(256L * 18 * 18 * 20), blk, 0, stream>>>(h2hi, 256, 18, 20);
    zero_halo_ps<<<nblk(256L * 18 * 18 * 20), blk, 0, stream>>>(h2lo, 256, 18, 20);
    conv_s2_mfma<64, 128, 16, 34, 36, 2, 1, 0, 1, 1><<<dim3(512), blk, 0, stream>>>(
        h1hi, h1lo, W2hi, W2lo, enc_b2, h2hi, h2lo, nullptr, 18, 20, 1, 0);
    conv_s2_mfma<128, 256, 8, 18, 20, 4, 1, 1, 4, 0><<<dim3(256), blk, 0, stream>>>(
        h2hi, h2lo, W3hi, W3lo, enc_b3, nullptr, nullptr, pp3, 8, 8, 0, 262144);
    combine4_relu<<<nblk(262144), blk, 0, stream>>>(pp3, h3, 262144, 262144);
    conv1x1_b<<<dim3(512), dim3(128), 0, stream>>>(h3, enc_w4, enc_b4, lat);

    // ---- VQ (fp32 exact) ----
    codenorm_kernel<<<dim3(1024), dim3(64), 0, stream>>>(codebook, cn);
    zero_halo_t<unsigned short><<<nblk(512L * 10 * 10 * 10), blk, 0, stream>>>(qp, 512, 10);
    vq_kernel<<<dim3(1024), blk, 0, stream>>>(lat, codebook, cn, qp, idx_out);

    // ---- decoder halos ----
    zero_halo_t<unsigned short><<<nblk(256L * 18 * 18 * 18), blk, 0, stream>>>(d1, 256, 18);
    zero_halo_t<unsigned short><<<nblk(128L * 34 * 34 * 34), blk, 0, stream>>>(d2, 128, 34);

    // ---- decoder (MFMA) per batch ----
    for (int b = 0; b < 2; ++b) {
        const unsigned short* qb = qp + (long)b * 256 * 1000;
        float* outb = out + (long)b * 3 * 226981;
        convt_mfma<8, 1, unsigned short><<<dim3(8 * 8 * 4), blk, 0, stream>>>(
            qb, Ap1, dec_b1, d1, 256, 256);
        convt_mfma<16, 1, unsigned short><<<dim3(8 * 64 * 2), blk, 0, stream>>>(
            d1, Ap2, dec_b2, d2, 256, 128);
        convt_mfma<32, 0, unsigned short><<<dim3(8 * 512), blk, 0, stream>>>(
            d2, Ap3, dec_b3, d3, 128, 64);
        conv_dec4_mfma<<<dim3(61 * 61), blk, 0, stream>>>(d3, Aw4, dec_b4, outb);
    }
}

// Round 11
// 2301.614 us; speedup vs baseline: 1.0706x; 1.0706x over previous
//
#include <hip/hip_runtime.h>
#include <cfloat>
#include <cmath>

// ---------------------------------------------------------------------------
// Round 10: fix the R10 dec4 regression.
// (1) d3 back to fp32: f32x4u (align(4)) loads emit global_load_dwordx4;
//     the bf16 u16x4a (align(2)) loads were split into 4x ushort scalar
//     loads -> VMEM-instruction bound (430 us, nothing busy).
// (2) dec4 grid: od-slab XCD swizzle (bx&7 owns 8 consecutive od, oh-major
//     inside) -> each XCD's 4-plane (4.2 MB) hot set stays L2-resident,
//     consecutive od reuse 3/4 planes.
// dec3 keeps R9's nt-slab XCD swizzle (proven). Encoder/VQ unchanged.
// ---------------------------------------------------------------------------

using f32x4  = __attribute__((ext_vector_type(4))) float;
using bf16x8 = __attribute__((ext_vector_type(8))) short;
typedef float f32x4u __attribute__((ext_vector_type(4), aligned(4)));
typedef unsigned short u16x4u __attribute__((ext_vector_type(4), aligned(4)));

__device__ __forceinline__ unsigned short f32_to_bf16(float f) {
    unsigned int u = __float_as_uint(f);
    u += 0x7fffu + ((u >> 16) & 1u);          // round-to-nearest-even
    return (unsigned short)(u >> 16);
}
__device__ __forceinline__ void split_bf16(float v, unsigned short& h, unsigned short& l) {
    h = f32_to_bf16(v);
    float hf = __uint_as_float((unsigned)h << 16);
    l = f32_to_bf16(v - hf);
}
__device__ __forceinline__ void store_act(float* p, float v) { *p = v; }
__device__ __forceinline__ void store_act(unsigned short* p, float v) { *p = f32_to_bf16(v); }

template <typename V>
__device__ __forceinline__ bf16x8 pack_b(V r0, V r1) {
    bf16x8 b;
    b[0] = (short)r0[0]; b[1] = (short)r0[1]; b[2] = (short)r0[2]; b[3] = (short)r0[3];
    b[4] = (short)r1[0]; b[5] = (short)r1[1]; b[6] = (short)r1[2]; b[7] = (short)r1[3];
    return b;
}

// ---------------- prep: weight hi/lo split ----------------
__global__ __launch_bounds__(256)
void prep_split_w(const float* __restrict__ w, short* __restrict__ whi,
                  short* __restrict__ wlo, long total)
{
    long idx = (long)blockIdx.x * blockDim.x + threadIdx.x;
    if (idx >= total) return;
    unsigned short h, l;
    split_bf16(w[idx], h, l);
    whi[idx] = (short)h; wlo[idx] = (short)l;
}

// ---------------- pad input -> hi/lo bf16 pitched planes --------------------
__global__ __launch_bounds__(256)
void pad_input_split(const float* __restrict__ x, unsigned short* __restrict__ xhi,
                     unsigned short* __restrict__ xlo)
{
    const int D = 64, PD = 66, PRX = 68, BC = 6;
    long total = (long)BC * PD * PD * PRX;
    long idx = (long)blockIdx.x * blockDim.x + threadIdx.x;
    if (idx >= total) return;
    int px = (int)(idx % PRX); long t = idx / PRX;
    int py = (int)(t % PD); t /= PD;
    int pz = (int)(t % PD); int c = (int)(t / PD);
    int ix = px - 1, iy = py - 1, iz = pz - 1;
    float v = 0.0f;
    if ((unsigned)ix < (unsigned)D && (unsigned)iy < (unsigned)D && (unsigned)iz < (unsigned)D)
        v = x[(((long)c * D + iz) * D + iy) * D + ix];
    unsigned short h, l;
    split_bf16(v, h, l);
    xhi[idx] = h; xlo[idx] = l;
}

__global__ __launch_bounds__(256)
void zero_halo_ps(unsigned short* __restrict__ p, int C, int PD, int PRX)
{
    long total = (long)C * PD * PD * PRX;
    long idx = (long)blockIdx.x * blockDim.x + threadIdx.x;
    if (idx >= total) return;
    int px = (int)(idx % PRX); long t = idx / PRX;
    int py = (int)(t % PD); t /= PD;
    int pz = (int)(t % PD);
    if (px == 0 || px >= PD - 1 || py == 0 || py == PD - 1 || pz == 0 || pz == PD - 1)
        p[idx] = 0;
}

template <typename T>
__global__ __launch_bounds__(256) void zero_halo_t(T* __restrict__ p, int C, int PD)
{
    long total = (long)C * PD * PD * PD;
    long idx = (long)blockIdx.x * blockDim.x + threadIdx.x;
    if (idx >= total) return;
    int px = (int)(idx % PD); long t = idx / PD;
    int py = (int)(t % PD); t /= PD;
    int pz = (int)(t % PD);
    if (px == 0 || px == PD - 1 || py == 0 || py == PD - 1 || pz == 0 || pz == PD - 1)
        p[idx] = (T)0;
}

// ---------------------------------------------------------------------------
// Conv3d k4 s2 p1 as MFMA implicit GEMM, bf16 hi/lo pair inputs (unchanged)
// ---------------------------------------------------------------------------
template <int CIN, int COUT, int DOUT, int PD, int PRX, int MTW, int OWT,
          int OWHALF, int KSPLIT, int OUTSPLIT>
__global__ __launch_bounds__(256)
void conv_s2_mfma(const unsigned short* __restrict__ xhi,
                  const unsigned short* __restrict__ xlo,
                  const short* __restrict__ Whi, const short* __restrict__ Wlo,
                  const float* __restrict__ bias,
                  unsigned short* __restrict__ yhi, unsigned short* __restrict__ ylo,
                  float* __restrict__ yf,
                  int OPD, int OPRX, int po, long sstride)
{
    constexpr int K = CIN * 64;
    constexpr int MWAVES = COUT / (16 * MTW);
    constexpr int RPB = 4 / MWAVES;
    constexpr int KN = (CIN * 2) / KSPLIT;

    int bx = blockIdx.x;
    const int ks = (KSPLIT > 1) ? (bx % KSPLIT) : 0;
    const int rowblk = (KSPLIT > 1) ? (bx / KSPLIT) : bx;
    const int lane = (int)threadIdx.x & 63, w = (int)threadIdx.x >> 6;
    const int mi = (MWAVES == 4) ? w : 0;
    const int ri = (MWAVES == 4) ? 0 : w;
    const int rowid = rowblk * RPB + ri;
    const int n16 = lane & 15, quad = lane >> 4;

    int b, od, oh, ow;
    if (OWHALF) {
        constexpr int NOH = DOUT / 2;
        const int ohb = rowid % NOH; int t = rowid / NOH;
        od = t % DOUT; b = t / DOUT;
        oh = ohb * 2 + (n16 >> 3);
        ow = n16 & 7;
    } else {
        const int owt = rowid % OWT; int t = rowid / OWT;
        oh = t % DOUT; t /= DOUT;
        od = t % DOUT; b = t / DOUT;
        ow = owt * 16 + n16;
    }

    const int co0 = mi * (MTW * 16);

    f32x4 acc[MTW];
    #pragma unroll
    for (int mt = 0; mt < MTW; ++mt)
        #pragma unroll
        for (int r = 0; r < 4; ++r) {
            int co = co0 + mt * 16 + quad * 4 + r;
            acc[mt][r] = (ks == 0) ? bias[co] : 0.0f;
        }

    const int sg0 = ks * KN;
    const long chs = (long)PD * PD * PRX;
    long off = ((long)(b * CIN + (sg0 >> 1)) * PD + (2 * od + (quad >> 1))) * PD * PRX
             + (long)(2 * oh + (quad & 1) * 2) * PRX + 2 * ow;
    const unsigned short* phi = xhi + off;
    const unsigned short* plo = xlo + off;
    const long incA = 2L * PD * PRX;
    const long incB = chs - 2L * PD * PRX;

    const short* a0h = Whi + (long)(co0 + n16) * K + sg0 * 32 + quad * 8;
    const short* a0l = Wlo + (long)(co0 + n16) * K + sg0 * 32 + quad * 8;

    #pragma unroll 2
    for (int s = 0; s < KN; ++s) {
        u16x4u h0 = *(const u16x4u*)phi;
        u16x4u h1 = *(const u16x4u*)(phi + PRX);
        u16x4u l0 = *(const u16x4u*)plo;
        u16x4u l1 = *(const u16x4u*)(plo + PRX);
        bf16x8 bhi = pack_b(h0, h1);
        bf16x8 blo = pack_b(l0, l1);
        #pragma unroll
        for (int mt = 0; mt < MTW; ++mt) {
            bf16x8 ah = *(const bf16x8*)(a0h + (long)mt * 16 * K + s * 32);
            bf16x8 al = *(const bf16x8*)(a0l + (long)mt * 16 * K + s * 32);
            acc[mt] = __builtin_amdgcn_mfma_f32_16x16x32_bf16(ah, bhi, acc[mt], 0, 0, 0);
            acc[mt] = __builtin_amdgcn_mfma_f32_16x16x32_bf16(ah, blo, acc[mt], 0, 0, 0);
            acc[mt] = __builtin_amdgcn_mfma_f32_16x16x32_bf16(al, bhi, acc[mt], 0, 0, 0);
        }
        long inc = (s & 1) ? incB : incA;
        phi += inc; plo += inc;
    }

    if (OUTSPLIT) {
        #pragma unroll
        for (int mt = 0; mt < MTW; ++mt)
            #pragma unroll
            for (int r = 0; r < 4; ++r) {
                int co = co0 + mt * 16 + quad * 4 + r;
                float v = fmaxf(acc[mt][r], 0.0f);
                unsigned short h, l;
                split_bf16(v, h, l);
                long o = (((long)(b * COUT + co) * OPD + od + po) * OPD + oh + po) * OPRX
                       + ow + po;
                yhi[o] = h; ylo[o] = l;
            }
    } else {
        #pragma unroll
        for (int mt = 0; mt < MTW; ++mt)
            #pragma unroll
            for (int r = 0; r < 4; ++r) {
                int co = co0 + mt * 16 + quad * 4 + r;
                long o = (long)ks * sstride
                       + (((long)(b * COUT + co) * OPD + od) * OPD + oh) * OPRX + ow;
                yf[o] = acc[mt][r];
            }
    }
}

__global__ __launch_bounds__(256)
void combine4_relu(const float* __restrict__ p, float* __restrict__ y, long N, long ss)
{
    long idx = (long)blockIdx.x * blockDim.x + threadIdx.x;
    if (idx >= N) return;
    float v = p[idx] + p[idx + ss] + p[idx + 2 * ss] + p[idx + 3 * ss];
    y[idx] = fmaxf(v, 0.0f);
}

// ---------------- 1x1 conv (fp32 exact) ----------------
__global__ __launch_bounds__(128)
void conv1x1_b(const float* __restrict__ x, const float* __restrict__ w,
               const float* __restrict__ bias, float* __restrict__ y)
{
    const int co = blockIdx.x & 255, b = blockIdx.x >> 8;
    const int s4 = (int)threadIdx.x * 4;
    const float* xb = x + (long)b * 256 * 512 + s4;
    const float* wr = w + (long)co * 256;      // uniform -> s_load
    float bv = bias[co];
    float4 acc = {bv, bv, bv, bv};
    for (int ci = 0; ci < 256; ++ci) {
        float wv = wr[ci];
        float4 xv = *(const float4*)(xb + (long)ci * 512);
        acc.x = fmaf(xv.x, wv, acc.x); acc.y = fmaf(xv.y, wv, acc.y);
        acc.z = fmaf(xv.z, wv, acc.z); acc.w = fmaf(xv.w, wv, acc.w);
    }
    *(float4*)(y + (long)(b * 256 + co) * 512 + s4) = acc;
}

// ---------------- VQ (fp32 exact; unchanged) ----------------
__global__ void codenorm_kernel(const float* __restrict__ cb, float* __restrict__ norms)
{
    int k = blockIdx.x;
    int lane = threadIdx.x;
    float s = 0.0f;
    const float* row = cb + (long)k * 256;
    for (int d = lane; d < 256; d += 64) { float v = row[d]; s = fmaf(v, v, s); }
    for (int off = 32; off > 0; off >>= 1) s += __shfl_down(s, off);
    if (lane == 0) norms[k] = s;
}

__global__ __launch_bounds__(256)
void vq_kernel(const float* __restrict__ lat, const float* __restrict__ cb,
               const float* __restrict__ norms, unsigned short* __restrict__ q,
               float* __restrict__ idx_out)
{
    __shared__ __align__(16) float row[256];
    __shared__ float s_best[256];
    __shared__ int   s_bidx[256];
    int r = blockIdx.x;
    int t = threadIdx.x;
    row[t] = lat[(long)r * 256 + t];
    __syncthreads();

    const float4* rowv = (const float4*)row;
    float latn = 0.0f;
    #pragma unroll 4
    for (int d = 0; d < 64; ++d) {
        float4 rv = rowv[d];
        latn = fmaf(rv.x, rv.x, latn); latn = fmaf(rv.y, rv.y, latn);
        latn = fmaf(rv.z, rv.z, latn); latn = fmaf(rv.w, rv.w, latn);
    }

    float best = FLT_MAX;
    int bidx = 0x7fffffff;
    for (int j = 0; j < 4; ++j) {
        int k = t + 256 * j;
        const float4* cr = (const float4*)(cb + (long)k * 256);
        float dot = 0.0f;
        #pragma unroll 4
        for (int d = 0; d < 64; ++d) {
            float4 c = cr[d]; float4 rv = rowv[d];
            dot = fmaf(rv.x, c.x, dot); dot = fmaf(rv.y, c.y, dot);
            dot = fmaf(rv.z, c.z, dot); dot = fmaf(rv.w, c.w, dot);
        }
        float sc = latn - 2.0f * dot + norms[k];
        if (sc < best || (sc == best && k < bidx)) { best = sc; bidx = k; }
    }
    s_best[t] = best; s_bidx[t] = bidx;
    __syncthreads();
    for (int off = 128; off > 0; off >>= 1) {
        if (t < off) {
            float o = s_best[t + off]; int oi = s_bidx[t + off];
            if (o < s_best[t] || (o == s_best[t] && oi < s_bidx[t])) {
                s_best[t] = o; s_bidx[t] = oi;
            }
        }
        __syncthreads();
    }
    int bk = s_bidx[0];
    int b = r >> 9, n = r & 511;
    int zz = n >> 6, yy = (n >> 3) & 7, xx = n & 7;
    q[(long)(b * 256 + t) * 1000 + ((long)(zz + 1) * 10 + (yy + 1)) * 10 + (xx + 1)]
        = f32_to_bf16(cb[(long)bk * 256 + t]);
    if (t == 0) idx_out[r] = (float)bk;
}

// ---------------- decoder: MFMA implicit-GEMM ConvTranspose ----------------
__global__ __launch_bounds__(256)
void prep_convt_w(const float* __restrict__ w, short* __restrict__ Ap,
                  int Cin, int Cout)
{
    const int K = Cin * 8;
    long total = 8L * Cout * K;
    long idx = (long)blockIdx.x * blockDim.x + threadIdx.x;
    if (idx >= total) return;
    int k = (int)(idx % K);
    int co = (int)((idx / K) % Cout);
    int p = (int)(idx / ((long)K * Cout));
    int ci = k >> 3, a = k & 7;
    int az = (a >> 2) & 1, ay = (a >> 1) & 1, ax = a & 1;
    int pz = p >> 2, py = (p >> 1) & 1, px = p & 1;
    int kd = (1 - pz) + 2 * az, kh = (1 - py) + 2 * ay, kw = (1 - px) + 2 * ax;
    float v = w[((long)ci * Cout + co) * 64 + kd * 16 + kh * 4 + kw];
    Ap[idx] = (short)f32_to_bf16(v);
}

// nt-slab XCD swizzle (R9, proven): bx&7 -> slab of consecutive nt; p,mg inner.
template <int DIN, int OPAD, typename OutT>
__global__ __launch_bounds__(256)
void convt_mfma(const unsigned short* __restrict__ Xp, const short* __restrict__ Ap,
                const float* __restrict__ bias, OutT* __restrict__ Y,
                int Cin, int Cout)
{
    constexpr int PD = DIN + 2;
    constexpr int PD3 = PD * PD * PD;
    constexpr int T = DIN >> 2;
    constexpr int NT = T * T * T;
    constexpr int SLAB = NT / 8;
    constexpr int OPD = 2 * DIN + 2 * OPAD;
    const int K = Cin * 8;
    const int MG = Cout >> 6;

    int bx = blockIdx.x;
    const int xcd = bx & 7;
    int local = bx >> 3;
    const int mg = local % MG; local /= MG;
    const int ntin = local % SLAB;
    const int p = local / SLAB;
    const int nt = xcd * SLAB + ntin;
    const int pz = p >> 2, py = (p >> 1) & 1, px = p & 1;

    const int lane = threadIdx.x & 63, wave = threadIdx.x >> 6;
    const int n16 = lane & 15, quad = lane >> 4;

    const int tx = nt % T, ty = (nt / T) % T, tz = nt / (T * T);
    const int mz = tz * 4 + wave, my = ty * 4 + (n16 >> 2), mx = tx * 4 + (n16 & 3);
    const int sp = ((mz + pz) * PD + (my + py)) * PD + (mx + px);

    const unsigned short* xq = Xp + (long)quad * PD3 + sp;

    const int cobase = mg * 64;
    const short* ap0 = Ap + ((long)p * Cout + cobase + n16) * K + quad * 8;

    f32x4 acc[4];
    #pragma unroll
    for (int cb = 0; cb < 4; ++cb) {
        const float* bp = bias + cobase + cb * 16 + quad * 4;
        acc[cb][0] = bp[0]; acc[cb][1] = bp[1]; acc[cb][2] = bp[2]; acc[cb][3] = bp[3];
    }

    const int nsteps = K >> 5;
    for (int s = 0; s < nsteps; ++s) {
        bf16x8 bf;
        bf[0] = (short)xq[(PD + 1) * PD + 1];
        bf[1] = (short)xq[(PD + 1) * PD];
        bf[2] = (short)xq[PD * PD + 1];
        bf[3] = (short)xq[PD * PD];
        bf[4] = (short)xq[PD + 1];
        bf[5] = (short)xq[PD];
        bf[6] = (short)xq[1];
        bf[7] = (short)xq[0];
        #pragma unroll
        for (int cb = 0; cb < 4; ++cb) {
            bf16x8 af = *(const bf16x8*)(ap0 + (long)cb * 16 * K + s * 32);
            acc[cb] = __builtin_amdgcn_mfma_f32_16x16x32_bf16(af, bf, acc[cb], 0, 0, 0);
        }
        xq += 4 * PD3;
    }

    const int opz = 2 * mz + pz + OPAD, opy = 2 * my + py + OPAD, opx = 2 * mx + px + OPAD;
    const long spo = ((long)opz * OPD + opy) * OPD + opx;
    #pragma unroll
    for (int cb = 0; cb < 4; ++cb) {
        #pragma unroll
        for (int r = 0; r < 4; ++r) {
            int co = cobase + cb * 16 + quad * 4 + r;
            float v = fmaxf(acc[cb][r], 0.0f);
            store_act(Y + (long)co * OPD * OPD * OPD + spo, v);
        }
    }
}

// ---------------- dec4 as MFMA GEMM: fp32 d3, od-slab XCD swizzle -----------
__global__ __launch_bounds__(256)
void prep_dec4A(const float* __restrict__ w, short* __restrict__ Aw)
{
    int idx = blockIdx.x * 256 + (int)threadIdx.x;    // 0..65535
    int m = idx >> 12, k = idx & 4095;
    float v = (m < 3) ? w[m * 4096 + k] : 0.0f;
    Aw[idx] = (short)f32_to_bf16(v);
}

// grid = 8 * 8*61: xcd = bx&7 owns od in [xcd*8, xcd*8+7] (guard od<61),
// oh-major inside -> one od's 4-z-plane hot set (4.2 MB) stays L2-resident,
// consecutive od reuse 3/4 planes.
__global__ __launch_bounds__(256)
void conv_dec4_mfma(const float* __restrict__ d3, const short* __restrict__ Aw,
                    const float* __restrict__ bias, float* __restrict__ y)
{
    constexpr int D = 64, Dout = 61;
    int bx = blockIdx.x;
    const int slab = bx & 7;
    const int i = bx >> 3;                 // 0..487
    const int od = slab * 8 + i / Dout;
    const int oh = i % Dout;
    if (od >= Dout) return;
    const int lane = (int)threadIdx.x & 63, wave = (int)threadIdx.x >> 6;
    const int n16 = lane & 15, quad = lane >> 4;
    const int ow = wave * 16 + n16;

    f32x4 acc;
    #pragma unroll
    for (int r = 0; r < 4; ++r) {
        int co = quad * 4 + r;
        acc[r] = (co < 3) ? bias[co] : 0.0f;
    }

    const short* ap = Aw + (long)n16 * 4096 + quad * 8;   // m = lane&15
    const int kd0 = quad >> 1;
    const int kh0 = (quad & 1) * 2;
    const float* base0 = d3 + ((long)(od + kd0) * D + (oh + kh0)) * D + ow;

    #pragma unroll 4
    for (int s = 0; s < 128; ++s) {
        const int ci = s >> 1;
        const float* base = base0 + ((long)ci * D + (s & 1) * 2) * D * D;
        f32x4u r0 = *(const f32x4u*)base;          // (kd, kh,   kw=0..3)
        f32x4u r1 = *(const f32x4u*)(base + D);    // (kd, kh+1, kw=0..3)
        bf16x8 bf;
        bf[0] = (short)(__float_as_uint(r0.x) >> 16);
        bf[1] = (short)(__float_as_uint(r0.y) >> 16);
        bf[2] = (short)(__float_as_uint(r0.z) >> 16);
        bf[3] = (short)(__float_as_uint(r0.w) >> 16);
        bf[4] = (short)(__float_as_uint(r1.x) >> 16);
        bf[5] = (short)(__float_as_uint(r1.y) >> 16);
        bf[6] = (short)(__float_as_uint(r1.z) >> 16);
        bf[7] = (short)(__float_as_uint(r1.w) >> 16);
        bf16x8 af = *(const bf16x8*)(ap + s * 32);
        acc = __builtin_amdgcn_mfma_f32_16x16x32_bf16(af, bf, acc, 0, 0, 0);
    }

    if (ow < Dout && quad == 0) {
        #pragma unroll
        for (int r = 0; r < 3; ++r)
            y[((long)(r * Dout + od) * Dout + oh) * Dout + ow] = tanhf(acc[r]);
    }
}

extern "C" void kernel_launch(void* const* d_in, const int* in_sizes, int n_in,
                              void* d_out, int out_size, void* d_ws, size_t ws_size,
                              hipStream_t stream)
{
    const float* x        = (const float*)d_in[0];
    const float* enc_w1   = (const float*)d_in[1];
    const float* enc_b1   = (const float*)d_in[2];
    const float* enc_w2   = (const float*)d_in[3];
    const float* enc_b2   = (const float*)d_in[4];
    const float* enc_w3   = (const float*)d_in[5];
    const float* enc_b3   = (const float*)d_in[6];
    const float* enc_w4   = (const float*)d_in[7];
    const float* enc_b4   = (const float*)d_in[8];
    const float* codebook = (const float*)d_in[9];
    const float* dec_w1   = (const float*)d_in[10];
    const float* dec_b1   = (const float*)d_in[11];
    const float* dec_w2   = (const float*)d_in[12];
    const float* dec_b2   = (const float*)d_in[13];
    const float* dec_w3   = (const float*)d_in[14];
    const float* dec_b3   = (const float*)d_in[15];
    const float* dec_w4   = (const float*)d_in[16];
    const float* dec_b4   = (const float*)d_in[17];

    float* out = (float*)d_out;
    float* idx_out = out + 2L * 3 * 61 * 61 * 61;

    // ---- workspace (byte offsets) ----
    char* wsb = (char*)d_ws;
    float*          cn   = (float*)wsb;                        //      4,096
    unsigned short* qp   = (unsigned short*)(wsb + 4096);      //  1,024,000
    short*          Ap1  = (short*)(wsb + 1028096);            //  8,388,608
    short*          Ap2  = (short*)(wsb + 9416704);            //  4,194,304
    short*          Ap3  = (short*)(wsb + 13611008);           //  1,048,576
    short*          Aw4  = (short*)(wsb + 14659584);           //    131,072
    short*          W1hi = (short*)(wsb + 14790656);           //     24,576
    short*          W1lo = (short*)(wsb + 14815232);           //     24,576
    short*          W2hi = (short*)(wsb + 14839808);           //  1,048,576
    short*          W2lo = (short*)(wsb + 15888384);           //  1,048,576
    short*          W3hi = (short*)(wsb + 16936960);           //  4,194,304
    short*          W3lo = (short*)(wsb + 21131264);           //  4,194,304
    char* arena = wsb + 25325568;
    // encoder phase:
    unsigned short* xphi = (unsigned short*)arena;                    // (2,3,66,66,68)
    unsigned short* xplo = (unsigned short*)(arena + 3554496);
    unsigned short* h1hi = (unsigned short*)(arena + 7108992);        // (2,64,34,34,36)
    unsigned short* h1lo = (unsigned short*)(arena + 17762688);
    unsigned short* h2hi = (unsigned short*)(arena + 28416384);       // (2,128,18,18,20)
    unsigned short* h2lo = (unsigned short*)(arena + 31734144);
    float*          pp3  = (float*)(arena + 35051904);                // 4x(2,256,8^3)
    float*          h3   = (float*)(arena + 39246208);                // (2,256,512)
    float*          lat  = (float*)(arena + 40294784);                // (2,256,512)
    // decoder phase (after VQ; overlaps encoder buffers):
    unsigned short* d1 = (unsigned short*)arena;                      // (256,18^3) bf16
    unsigned short* d2 = (unsigned short*)(arena + 2985984);          // (128,34^3) bf16
    float*          d3 = (float*)(arena + 13047808);                  // (64,64^3) fp32
    // arena peak 80.2 MB; total 105.5 MB (< 112.2 MB proven in R0)

    dim3 blk(256);
    auto nblk = [](long n) { return dim3((unsigned)((n + 255) / 256)); };

    // ---- weight prep ----
    prep_convt_w<<<nblk(8L * 256 * 2048), blk, 0, stream>>>(dec_w1, Ap1, 256, 256);
    prep_convt_w<<<nblk(8L * 128 * 2048), blk, 0, stream>>>(dec_w2, Ap2, 256, 128);
    prep_convt_w<<<nblk(8L * 64 * 1024), blk, 0, stream>>>(dec_w3, Ap3, 128, 64);
    prep_dec4A<<<dim3(256), blk, 0, stream>>>(dec_w4, Aw4);
    prep_split_w<<<nblk(12288), blk, 0, stream>>>(enc_w1, W1hi, W1lo, 12288);
    prep_split_w<<<nblk(524288), blk, 0, stream>>>(enc_w2, W2hi, W2lo, 524288);
    prep_split_w<<<nblk(2097152), blk, 0, stream>>>(enc_w3, W3hi, W3lo, 2097152);

    // ---- encoder (MFMA, bf16-pair) ----
    pad_input_split<<<nblk(6L * 66 * 66 * 68), blk, 0, stream>>>(x, xphi, xplo);
    zero_halo_ps<<<nblk(128L * 34 * 34 * 36), blk, 0, stream>>>(h1hi, 128, 34, 36);
    zero_halo_ps<<<nblk(128L * 34 * 34 * 36), blk, 0, stream>>>(h1lo, 128, 34, 36);
    conv_s2_mfma<3, 64, 32, 66, 68, 4, 2, 0, 1, 1><<<dim3(1024), blk, 0, stream>>>(
        xphi, xplo, W1hi, W1lo, enc_b1, h1hi, h1lo, nullptr, 34, 36, 1, 0);
    zero_halo_ps<<<nblk(256L * 18 * 18 * 20), blk, 0, stream>>>(h2hi, 256, 18, 20);
    zero_halo_ps<<<nblk(256L * 18 * 18 * 20), blk, 0, stream>>>(h2lo, 256, 18, 20);
    conv_s2_mfma<64, 128, 16, 34, 36, 2, 1, 0, 1, 1><<<dim3(512), blk, 0, stream>>>(
        h1hi, h1lo, W2hi, W2lo, enc_b2, h2hi, h2lo, nullptr, 18, 20, 1, 0);
    conv_s2_mfma<128, 256, 8, 18, 20, 4, 1, 1, 4, 0><<<dim3(256), blk, 0, stream>>>(
        h2hi, h2lo, W3hi, W3lo, enc_b3, nullptr, nullptr, pp3, 8, 8, 0, 262144);
    combine4_relu<<<nblk(262144), blk, 0, stream>>>(pp3, h3, 262144, 262144);
    conv1x1_b<<<dim3(512), dim3(128), 0, stream>>>(h3, enc_w4, enc_b4, lat);

    // ---- VQ (fp32 exact) ----
    codenorm_kernel<<<dim3(1024), dim3(64), 0, stream>>>(codebook, cn);
    zero_halo_t<unsigned short><<<nblk(512L * 10 * 10 * 10), blk, 0, stream>>>(qp, 512, 10);
    vq_kernel<<<dim3(1024), blk, 0, stream>>>(lat, codebook, cn, qp, idx_out);

    // ---- decoder halos ----
    zero_halo_t<unsigned short><<<nblk(256L * 18 * 18 * 18), blk, 0, stream>>>(d1, 256, 18);
    zero_halo_t<unsigned short><<<nblk(128L * 34 * 34 * 34), blk, 0, stream>>>(d2, 128, 34);

    // ---- decoder (MFMA) per batch ----
    for (int b = 0; b < 2; ++b) {
        const unsigned short* qb = qp + (long)b * 256 * 1000;
        float* outb = out + (long)b * 3 * 226981;
        convt_mfma<8, 1, unsigned short><<<dim3(8 * 8 * 4), blk, 0, stream>>>(
            qb, Ap1, dec_b1, d1, 256, 256);
        convt_mfma<16, 1, unsigned short><<<dim3(8 * 64 * 2), blk, 0, stream>>>(
            d1, Ap2, dec_b2, d2, 256, 128);
        convt_mfma<32, 0, float><<<dim3(8 * 512), blk, 0, stream>>>(
            d2, Ap3, dec_b3, d3, 128, 64);
        conv_dec4_mfma<<<dim3(8 * 8 * 61), blk, 0, stream>>>(d3, Aw4, dec_b4, outb);
    }
}

// Round 12
// 1881.505 us; speedup vs baseline: 1.3096x; 1.2233x over previous
//
#include <hip/hip_runtime.h>
#include <cfloat>
#include <cmath>

// ---------------------------------------------------------------------------
// Round 11: dec4 MFMA density fix. Each wave now computes 4 oh rows (acc[4]):
// 5 sliding-window y-row loads + 1 A-load feed 4 MFMAs per K-step (was 3 VMEM
// per 1 MFMA). A-stream per wave /4, load latency amortized 4x. od-slab XCD
// swizzle kept (R11's FETCH is at the compulsory minimum). Numerics identical
// (same truncation-to-bf16). Everything else unchanged from R11.
// ---------------------------------------------------------------------------

using f32x4  = __attribute__((ext_vector_type(4))) float;
using bf16x8 = __attribute__((ext_vector_type(8))) short;
typedef float f32x4u __attribute__((ext_vector_type(4), aligned(4)));
typedef unsigned short u16x4u __attribute__((ext_vector_type(4), aligned(4)));

__device__ __forceinline__ unsigned short f32_to_bf16(float f) {
    unsigned int u = __float_as_uint(f);
    u += 0x7fffu + ((u >> 16) & 1u);          // round-to-nearest-even
    return (unsigned short)(u >> 16);
}
__device__ __forceinline__ void split_bf16(float v, unsigned short& h, unsigned short& l) {
    h = f32_to_bf16(v);
    float hf = __uint_as_float((unsigned)h << 16);
    l = f32_to_bf16(v - hf);
}
__device__ __forceinline__ void store_act(float* p, float v) { *p = v; }
__device__ __forceinline__ void store_act(unsigned short* p, float v) { *p = f32_to_bf16(v); }

template <typename V>
__device__ __forceinline__ bf16x8 pack_b(V r0, V r1) {
    bf16x8 b;
    b[0] = (short)r0[0]; b[1] = (short)r0[1]; b[2] = (short)r0[2]; b[3] = (short)r0[3];
    b[4] = (short)r1[0]; b[5] = (short)r1[1]; b[6] = (short)r1[2]; b[7] = (short)r1[3];
    return b;
}

// ---------------- prep: weight hi/lo split ----------------
__global__ __launch_bounds__(256)
void prep_split_w(const float* __restrict__ w, short* __restrict__ whi,
                  short* __restrict__ wlo, long total)
{
    long idx = (long)blockIdx.x * blockDim.x + threadIdx.x;
    if (idx >= total) return;
    unsigned short h, l;
    split_bf16(w[idx], h, l);
    whi[idx] = (short)h; wlo[idx] = (short)l;
}

// ---------------- pad input -> hi/lo bf16 pitched planes --------------------
__global__ __launch_bounds__(256)
void pad_input_split(const float* __restrict__ x, unsigned short* __restrict__ xhi,
                     unsigned short* __restrict__ xlo)
{
    const int D = 64, PD = 66, PRX = 68, BC = 6;
    long total = (long)BC * PD * PD * PRX;
    long idx = (long)blockIdx.x * blockDim.x + threadIdx.x;
    if (idx >= total) return;
    int px = (int)(idx % PRX); long t = idx / PRX;
    int py = (int)(t % PD); t /= PD;
    int pz = (int)(t % PD); int c = (int)(t / PD);
    int ix = px - 1, iy = py - 1, iz = pz - 1;
    float v = 0.0f;
    if ((unsigned)ix < (unsigned)D && (unsigned)iy < (unsigned)D && (unsigned)iz < (unsigned)D)
        v = x[(((long)c * D + iz) * D + iy) * D + ix];
    unsigned short h, l;
    split_bf16(v, h, l);
    xhi[idx] = h; xlo[idx] = l;
}

__global__ __launch_bounds__(256)
void zero_halo_ps(unsigned short* __restrict__ p, int C, int PD, int PRX)
{
    long total = (long)C * PD * PD * PRX;
    long idx = (long)blockIdx.x * blockDim.x + threadIdx.x;
    if (idx >= total) return;
    int px = (int)(idx % PRX); long t = idx / PRX;
    int py = (int)(t % PD); t /= PD;
    int pz = (int)(t % PD);
    if (px == 0 || px >= PD - 1 || py == 0 || py == PD - 1 || pz == 0 || pz == PD - 1)
        p[idx] = 0;
}

template <typename T>
__global__ __launch_bounds__(256) void zero_halo_t(T* __restrict__ p, int C, int PD)
{
    long total = (long)C * PD * PD * PD;
    long idx = (long)blockIdx.x * blockDim.x + threadIdx.x;
    if (idx >= total) return;
    int px = (int)(idx % PD); long t = idx / PD;
    int py = (int)(t % PD); t /= PD;
    int pz = (int)(t % PD);
    if (px == 0 || px == PD - 1 || py == 0 || py == PD - 1 || pz == 0 || pz == PD - 1)
        p[idx] = (T)0;
}

// ---------------------------------------------------------------------------
// Conv3d k4 s2 p1 as MFMA implicit GEMM, bf16 hi/lo pair inputs (unchanged)
// ---------------------------------------------------------------------------
template <int CIN, int COUT, int DOUT, int PD, int PRX, int MTW, int OWT,
          int OWHALF, int KSPLIT, int OUTSPLIT>
__global__ __launch_bounds__(256)
void conv_s2_mfma(const unsigned short* __restrict__ xhi,
                  const unsigned short* __restrict__ xlo,
                  const short* __restrict__ Whi, const short* __restrict__ Wlo,
                  const float* __restrict__ bias,
                  unsigned short* __restrict__ yhi, unsigned short* __restrict__ ylo,
                  float* __restrict__ yf,
                  int OPD, int OPRX, int po, long sstride)
{
    constexpr int K = CIN * 64;
    constexpr int MWAVES = COUT / (16 * MTW);
    constexpr int RPB = 4 / MWAVES;
    constexpr int KN = (CIN * 2) / KSPLIT;

    int bx = blockIdx.x;
    const int ks = (KSPLIT > 1) ? (bx % KSPLIT) : 0;
    const int rowblk = (KSPLIT > 1) ? (bx / KSPLIT) : bx;
    const int lane = (int)threadIdx.x & 63, w = (int)threadIdx.x >> 6;
    const int mi = (MWAVES == 4) ? w : 0;
    const int ri = (MWAVES == 4) ? 0 : w;
    const int rowid = rowblk * RPB + ri;
    const int n16 = lane & 15, quad = lane >> 4;

    int b, od, oh, ow;
    if (OWHALF) {
        constexpr int NOH = DOUT / 2;
        const int ohb = rowid % NOH; int t = rowid / NOH;
        od = t % DOUT; b = t / DOUT;
        oh = ohb * 2 + (n16 >> 3);
        ow = n16 & 7;
    } else {
        const int owt = rowid % OWT; int t = rowid / OWT;
        oh = t % DOUT; t /= DOUT;
        od = t % DOUT; b = t / DOUT;
        ow = owt * 16 + n16;
    }

    const int co0 = mi * (MTW * 16);

    f32x4 acc[MTW];
    #pragma unroll
    for (int mt = 0; mt < MTW; ++mt)
        #pragma unroll
        for (int r = 0; r < 4; ++r) {
            int co = co0 + mt * 16 + quad * 4 + r;
            acc[mt][r] = (ks == 0) ? bias[co] : 0.0f;
        }

    const int sg0 = ks * KN;
    const long chs = (long)PD * PD * PRX;
    long off = ((long)(b * CIN + (sg0 >> 1)) * PD + (2 * od + (quad >> 1))) * PD * PRX
             + (long)(2 * oh + (quad & 1) * 2) * PRX + 2 * ow;
    const unsigned short* phi = xhi + off;
    const unsigned short* plo = xlo + off;
    const long incA = 2L * PD * PRX;
    const long incB = chs - 2L * PD * PRX;

    const short* a0h = Whi + (long)(co0 + n16) * K + sg0 * 32 + quad * 8;
    const short* a0l = Wlo + (long)(co0 + n16) * K + sg0 * 32 + quad * 8;

    #pragma unroll 2
    for (int s = 0; s < KN; ++s) {
        u16x4u h0 = *(const u16x4u*)phi;
        u16x4u h1 = *(const u16x4u*)(phi + PRX);
        u16x4u l0 = *(const u16x4u*)plo;
        u16x4u l1 = *(const u16x4u*)(plo + PRX);
        bf16x8 bhi = pack_b(h0, h1);
        bf16x8 blo = pack_b(l0, l1);
        #pragma unroll
        for (int mt = 0; mt < MTW; ++mt) {
            bf16x8 ah = *(const bf16x8*)(a0h + (long)mt * 16 * K + s * 32);
            bf16x8 al = *(const bf16x8*)(a0l + (long)mt * 16 * K + s * 32);
            acc[mt] = __builtin_amdgcn_mfma_f32_16x16x32_bf16(ah, bhi, acc[mt], 0, 0, 0);
            acc[mt] = __builtin_amdgcn_mfma_f32_16x16x32_bf16(ah, blo, acc[mt], 0, 0, 0);
            acc[mt] = __builtin_amdgcn_mfma_f32_16x16x32_bf16(al, bhi, acc[mt], 0, 0, 0);
        }
        long inc = (s & 1) ? incB : incA;
        phi += inc; plo += inc;
    }

    if (OUTSPLIT) {
        #pragma unroll
        for (int mt = 0; mt < MTW; ++mt)
            #pragma unroll
            for (int r = 0; r < 4; ++r) {
                int co = co0 + mt * 16 + quad * 4 + r;
                float v = fmaxf(acc[mt][r], 0.0f);
                unsigned short h, l;
                split_bf16(v, h, l);
                long o = (((long)(b * COUT + co) * OPD + od + po) * OPD + oh + po) * OPRX
                       + ow + po;
                yhi[o] = h; ylo[o] = l;
            }
    } else {
        #pragma unroll
        for (int mt = 0; mt < MTW; ++mt)
            #pragma unroll
            for (int r = 0; r < 4; ++r) {
                int co = co0 + mt * 16 + quad * 4 + r;
                long o = (long)ks * sstride
                       + (((long)(b * COUT + co) * OPD + od) * OPD + oh) * OPRX + ow;
                yf[o] = acc[mt][r];
            }
    }
}

__global__ __launch_bounds__(256)
void combine4_relu(const float* __restrict__ p, float* __restrict__ y, long N, long ss)
{
    long idx = (long)blockIdx.x * blockDim.x + threadIdx.x;
    if (idx >= N) return;
    float v = p[idx] + p[idx + ss] + p[idx + 2 * ss] + p[idx + 3 * ss];
    y[idx] = fmaxf(v, 0.0f);
}

// ---------------- 1x1 conv (fp32 exact) ----------------
__global__ __launch_bounds__(128)
void conv1x1_b(const float* __restrict__ x, const float* __restrict__ w,
               const float* __restrict__ bias, float* __restrict__ y)
{
    const int co = blockIdx.x & 255, b = blockIdx.x >> 8;
    const int s4 = (int)threadIdx.x * 4;
    const float* xb = x + (long)b * 256 * 512 + s4;
    const float* wr = w + (long)co * 256;      // uniform -> s_load
    float bv = bias[co];
    float4 acc = {bv, bv, bv, bv};
    for (int ci = 0; ci < 256; ++ci) {
        float wv = wr[ci];
        float4 xv = *(const float4*)(xb + (long)ci * 512);
        acc.x = fmaf(xv.x, wv, acc.x); acc.y = fmaf(xv.y, wv, acc.y);
        acc.z = fmaf(xv.z, wv, acc.z); acc.w = fmaf(xv.w, wv, acc.w);
    }
    *(float4*)(y + (long)(b * 256 + co) * 512 + s4) = acc;
}

// ---------------- VQ (fp32 exact; unchanged) ----------------
__global__ void codenorm_kernel(const float* __restrict__ cb, float* __restrict__ norms)
{
    int k = blockIdx.x;
    int lane = threadIdx.x;
    float s = 0.0f;
    const float* row = cb + (long)k * 256;
    for (int d = lane; d < 256; d += 64) { float v = row[d]; s = fmaf(v, v, s); }
    for (int off = 32; off > 0; off >>= 1) s += __shfl_down(s, off);
    if (lane == 0) norms[k] = s;
}

__global__ __launch_bounds__(256)
void vq_kernel(const float* __restrict__ lat, const float* __restrict__ cb,
               const float* __restrict__ norms, unsigned short* __restrict__ q,
               float* __restrict__ idx_out)
{
    __shared__ __align__(16) float row[256];
    __shared__ float s_best[256];
    __shared__ int   s_bidx[256];
    int r = blockIdx.x;
    int t = threadIdx.x;
    row[t] = lat[(long)r * 256 + t];
    __syncthreads();

    const float4* rowv = (const float4*)row;
    float latn = 0.0f;
    #pragma unroll 4
    for (int d = 0; d < 64; ++d) {
        float4 rv = rowv[d];
        latn = fmaf(rv.x, rv.x, latn); latn = fmaf(rv.y, rv.y, latn);
        latn = fmaf(rv.z, rv.z, latn); latn = fmaf(rv.w, rv.w, latn);
    }

    float best = FLT_MAX;
    int bidx = 0x7fffffff;
    for (int j = 0; j < 4; ++j) {
        int k = t + 256 * j;
        const float4* cr = (const float4*)(cb + (long)k * 256);
        float dot = 0.0f;
        #pragma unroll 4
        for (int d = 0; d < 64; ++d) {
            float4 c = cr[d]; float4 rv = rowv[d];
            dot = fmaf(rv.x, c.x, dot); dot = fmaf(rv.y, c.y, dot);
            dot = fmaf(rv.z, c.z, dot); dot = fmaf(rv.w, c.w, dot);
        }
        float sc = latn - 2.0f * dot + norms[k];
        if (sc < best || (sc == best && k < bidx)) { best = sc; bidx = k; }
    }
    s_best[t] = best; s_bidx[t] = bidx;
    __syncthreads();
    for (int off = 128; off > 0; off >>= 1) {
        if (t < off) {
            float o = s_best[t + off]; int oi = s_bidx[t + off];
            if (o < s_best[t] || (o == s_best[t] && oi < s_bidx[t])) {
                s_best[t] = o; s_bidx[t] = oi;
            }
        }
        __syncthreads();
    }
    int bk = s_bidx[0];
    int b = r >> 9, n = r & 511;
    int zz = n >> 6, yy = (n >> 3) & 7, xx = n & 7;
    q[(long)(b * 256 + t) * 1000 + ((long)(zz + 1) * 10 + (yy + 1)) * 10 + (xx + 1)]
        = f32_to_bf16(cb[(long)bk * 256 + t]);
    if (t == 0) idx_out[r] = (float)bk;
}

// ---------------- decoder: MFMA implicit-GEMM ConvTranspose ----------------
__global__ __launch_bounds__(256)
void prep_convt_w(const float* __restrict__ w, short* __restrict__ Ap,
                  int Cin, int Cout)
{
    const int K = Cin * 8;
    long total = 8L * Cout * K;
    long idx = (long)blockIdx.x * blockDim.x + threadIdx.x;
    if (idx >= total) return;
    int k = (int)(idx % K);
    int co = (int)((idx / K) % Cout);
    int p = (int)(idx / ((long)K * Cout));
    int ci = k >> 3, a = k & 7;
    int az = (a >> 2) & 1, ay = (a >> 1) & 1, ax = a & 1;
    int pz = p >> 2, py = (p >> 1) & 1, px = p & 1;
    int kd = (1 - pz) + 2 * az, kh = (1 - py) + 2 * ay, kw = (1 - px) + 2 * ax;
    float v = w[((long)ci * Cout + co) * 64 + kd * 16 + kh * 4 + kw];
    Ap[idx] = (short)f32_to_bf16(v);
}

// nt-slab XCD swizzle (R9, proven): bx&7 -> slab of consecutive nt; p,mg inner.
template <int DIN, int OPAD, typename OutT>
__global__ __launch_bounds__(256)
void convt_mfma(const unsigned short* __restrict__ Xp, const short* __restrict__ Ap,
                const float* __restrict__ bias, OutT* __restrict__ Y,
                int Cin, int Cout)
{
    constexpr int PD = DIN + 2;
    constexpr int PD3 = PD * PD * PD;
    constexpr int T = DIN >> 2;
    constexpr int NT = T * T * T;
    constexpr int SLAB = NT / 8;
    constexpr int OPD = 2 * DIN + 2 * OPAD;
    const int K = Cin * 8;
    const int MG = Cout >> 6;

    int bx = blockIdx.x;
    const int xcd = bx & 7;
    int local = bx >> 3;
    const int mg = local % MG; local /= MG;
    const int ntin = local % SLAB;
    const int p = local / SLAB;
    const int nt = xcd * SLAB + ntin;
    const int pz = p >> 2, py = (p >> 1) & 1, px = p & 1;

    const int lane = threadIdx.x & 63, wave = threadIdx.x >> 6;
    const int n16 = lane & 15, quad = lane >> 4;

    const int tx = nt % T, ty = (nt / T) % T, tz = nt / (T * T);
    const int mz = tz * 4 + wave, my = ty * 4 + (n16 >> 2), mx = tx * 4 + (n16 & 3);
    const int sp = ((mz + pz) * PD + (my + py)) * PD + (mx + px);

    const unsigned short* xq = Xp + (long)quad * PD3 + sp;

    const int cobase = mg * 64;
    const short* ap0 = Ap + ((long)p * Cout + cobase + n16) * K + quad * 8;

    f32x4 acc[4];
    #pragma unroll
    for (int cb = 0; cb < 4; ++cb) {
        const float* bp = bias + cobase + cb * 16 + quad * 4;
        acc[cb][0] = bp[0]; acc[cb][1] = bp[1]; acc[cb][2] = bp[2]; acc[cb][3] = bp[3];
    }

    const int nsteps = K >> 5;
    for (int s = 0; s < nsteps; ++s) {
        bf16x8 bf;
        bf[0] = (short)xq[(PD + 1) * PD + 1];
        bf[1] = (short)xq[(PD + 1) * PD];
        bf[2] = (short)xq[PD * PD + 1];
        bf[3] = (short)xq[PD * PD];
        bf[4] = (short)xq[PD + 1];
        bf[5] = (short)xq[PD];
        bf[6] = (short)xq[1];
        bf[7] = (short)xq[0];
        #pragma unroll
        for (int cb = 0; cb < 4; ++cb) {
            bf16x8 af = *(const bf16x8*)(ap0 + (long)cb * 16 * K + s * 32);
            acc[cb] = __builtin_amdgcn_mfma_f32_16x16x32_bf16(af, bf, acc[cb], 0, 0, 0);
        }
        xq += 4 * PD3;
    }

    const int opz = 2 * mz + pz + OPAD, opy = 2 * my + py + OPAD, opx = 2 * mx + px + OPAD;
    const long spo = ((long)opz * OPD + opy) * OPD + opx;
    #pragma unroll
    for (int cb = 0; cb < 4; ++cb) {
        #pragma unroll
        for (int r = 0; r < 4; ++r) {
            int co = cobase + cb * 16 + quad * 4 + r;
            float v = fmaxf(acc[cb][r], 0.0f);
            store_act(Y + (long)co * OPD * OPD * OPD + spo, v);
        }
    }
}

// ---------------- dec4 as MFMA GEMM: 4 oh rows per wave ----------------
__global__ __launch_bounds__(256)
void prep_dec4A(const float* __restrict__ w, short* __restrict__ Aw)
{
    int idx = blockIdx.x * 256 + (int)threadIdx.x;    // 0..65535
    int m = idx >> 12, k = idx & 4095;
    float v = (m < 3) ? w[m * 4096 + k] : 0.0f;
    Aw[idx] = (short)f32_to_bf16(v);
}

// grid = 8 slabs * 8 od * 16 oh-tiles = 1024. slab=bx&7 owns od in
// [slab*8, slab*8+7] (guard od<61). Each wave: 4 acc (oh0..oh0+3) built from
// 5 sliding-window row loads + 1 shared A-load per K-step -> 6 VMEM / 4 MFMA.
__global__ __launch_bounds__(256)
void conv_dec4_mfma(const float* __restrict__ d3, const short* __restrict__ Aw,
                    const float* __restrict__ bias, float* __restrict__ y)
{
    constexpr int D = 64, Dout = 61;
    int bx = blockIdx.x;
    const int slab = bx & 7;
    const int i = bx >> 3;                 // 0..127
    const int od = slab * 8 + (i >> 4);
    const int oh0 = (i & 15) * 4;          // covers oh0..oh0+3 (guard < 61)
    if (od >= Dout) return;
    const int lane = (int)threadIdx.x & 63, wave = (int)threadIdx.x >> 6;
    const int n16 = lane & 15, quad = lane >> 4;
    const int ow = wave * 16 + n16;

    f32x4 acc[4];
    #pragma unroll
    for (int j = 0; j < 4; ++j)
        #pragma unroll
        for (int r = 0; r < 4; ++r) {
            int co = quad * 4 + r;
            acc[j][r] = (co < 3) ? bias[co] : 0.0f;
        }

    const short* ap = Aw + (long)n16 * 4096 + quad * 8;   // m = lane&15
    const int kd0 = quad >> 1;             // z-tap base (s parity adds 2)
    const int kh0 = (quad & 1) * 2;        // y-tap base
    const float* basez = d3 + ((long)(od + kd0) * D) * D + ow;
    int yoff[5];
    #pragma unroll
    for (int r = 0; r < 5; ++r) yoff[r] = min(oh0 + kh0 + r, D - 1) * D;  // clamped rows feed only discarded fragments

    #pragma unroll 4
    for (int s = 0; s < 128; ++s) {
        const int ci = s >> 1;
        const float* plane = basez + ((long)ci * D + (s & 1) * 2) * D * D;
        // 5 row loads (dwordx4), packed once to bf16 halves
        unsigned p0[5], p1[5];
        #pragma unroll
        for (int r = 0; r < 5; ++r) {
            f32x4u v = *(const f32x4u*)(plane + yoff[r]);
            p0[r] = (__float_as_uint(v[0]) >> 16) | (__float_as_uint(v[1]) & 0xffff0000u);
            p1[r] = (__float_as_uint(v[2]) >> 16) | (__float_as_uint(v[3]) & 0xffff0000u);
        }
        bf16x8 af = *(const bf16x8*)(ap + s * 32);
        #pragma unroll
        for (int j = 0; j < 4; ++j) {
            union { unsigned u[4]; bf16x8 b; } fr;
            fr.u[0] = p0[j];     fr.u[1] = p1[j];
            fr.u[2] = p0[j + 1]; fr.u[3] = p1[j + 1];
            acc[j] = __builtin_amdgcn_mfma_f32_16x16x32_bf16(af, fr.b, acc[j], 0, 0, 0);
        }
    }

    if (ow < Dout && quad == 0) {
        #pragma unroll
        for (int j = 0; j < 4; ++j) {
            const int oh = oh0 + j;
            if (oh >= Dout) continue;
            #pragma unroll
            for (int r = 0; r < 3; ++r)
                y[((long)(r * Dout + od) * Dout + oh) * Dout + ow] = tanhf(acc[j][r]);
        }
    }
}

extern "C" void kernel_launch(void* const* d_in, const int* in_sizes, int n_in,
                              void* d_out, int out_size, void* d_ws, size_t ws_size,
                              hipStream_t stream)
{
    const float* x        = (const float*)d_in[0];
    const float* enc_w1   = (const float*)d_in[1];
    const float* enc_b1   = (const float*)d_in[2];
    const float* enc_w2   = (const float*)d_in[3];
    const float* enc_b2   = (const float*)d_in[4];
    const float* enc_w3   = (const float*)d_in[5];
    const float* enc_b3   = (const float*)d_in[6];
    const float* enc_w4   = (const float*)d_in[7];
    const float* enc_b4   = (const float*)d_in[8];
    const float* codebook = (const float*)d_in[9];
    const float* dec_w1   = (const float*)d_in[10];
    const float* dec_b1   = (const float*)d_in[11];
    const float* dec_w2   = (const float*)d_in[12];
    const float* dec_b2   = (const float*)d_in[13];
    const float* dec_w3   = (const float*)d_in[14];
    const float* dec_b3   = (const float*)d_in[15];
    const float* dec_w4   = (const float*)d_in[16];
    const float* dec_b4   = (const float*)d_in[17];

    float* out = (float*)d_out;
    float* idx_out = out + 2L * 3 * 61 * 61 * 61;

    // ---- workspace (byte offsets) ----
    char* wsb = (char*)d_ws;
    float*          cn   = (float*)wsb;                        //      4,096
    unsigned short* qp   = (unsigned short*)(wsb + 4096);      //  1,024,000
    short*          Ap1  = (short*)(wsb + 1028096);            //  8,388,608
    short*          Ap2  = (short*)(wsb + 9416704);            //  4,194,304
    short*          Ap3  = (short*)(wsb + 13611008);           //  1,048,576
    short*          Aw4  = (short*)(wsb + 14659584);           //    131,072
    short*          W1hi = (short*)(wsb + 14790656);           //     24,576
    short*          W1lo = (short*)(wsb + 14815232);           //     24,576
    short*          W2hi = (short*)(wsb + 14839808);           //  1,048,576
    short*          W2lo = (short*)(wsb + 15888384);           //  1,048,576
    short*          W3hi = (short*)(wsb + 16936960);           //  4,194,304
    short*          W3lo = (short*)(wsb + 21131264);           //  4,194,304
    char* arena = wsb + 25325568;
    // encoder phase:
    unsigned short* xphi = (unsigned short*)arena;                    // (2,3,66,66,68)
    unsigned short* xplo = (unsigned short*)(arena + 3554496);
    unsigned short* h1hi = (unsigned short*)(arena + 7108992);        // (2,64,34,34,36)
    unsigned short* h1lo = (unsigned short*)(arena + 17762688);
    unsigned short* h2hi = (unsigned short*)(arena + 28416384);       // (2,128,18,18,20)
    unsigned short* h2lo = (unsigned short*)(arena + 31734144);
    float*          pp3  = (float*)(arena + 35051904);                // 4x(2,256,8^3)
    float*          h3   = (float*)(arena + 39246208);                // (2,256,512)
    float*          lat  = (float*)(arena + 40294784);                // (2,256,512)
    // decoder phase (after VQ; overlaps encoder buffers):
    unsigned short* d1 = (unsigned short*)arena;                      // (256,18^3) bf16
    unsigned short* d2 = (unsigned short*)(arena + 2985984);          // (128,34^3) bf16
    float*          d3 = (float*)(arena + 13047808);                  // (64,64^3) fp32
    // arena peak 80.2 MB; total 105.5 MB (< 112.2 MB proven in R0)

    dim3 blk(256);
    auto nblk = [](long n) { return dim3((unsigned)((n + 255) / 256)); };

    // ---- weight prep ----
    prep_convt_w<<<nblk(8L * 256 * 2048), blk, 0, stream>>>(dec_w1, Ap1, 256, 256);
    prep_convt_w<<<nblk(8L * 128 * 2048), blk, 0, stream>>>(dec_w2, Ap2, 256, 128);
    prep_convt_w<<<nblk(8L * 64 * 1024), blk, 0, stream>>>(dec_w3, Ap3, 128, 64);
    prep_dec4A<<<dim3(256), blk, 0, stream>>>(dec_w4, Aw4);
    prep_split_w<<<nblk(12288), blk, 0, stream>>>(enc_w1, W1hi, W1lo, 12288);
    prep_split_w<<<nblk(524288), blk, 0, stream>>>(enc_w2, W2hi, W2lo, 524288);
    prep_split_w<<<nblk(2097152), blk, 0, stream>>>(enc_w3, W3hi, W3lo, 2097152);

    // ---- encoder (MFMA, bf16-pair) ----
    pad_input_split<<<nblk(6L * 66 * 66 * 68), blk, 0, stream>>>(x, xphi, xplo);
    zero_halo_ps<<<nblk(128L * 34 * 34 * 36), blk, 0, stream>>>(h1hi, 128, 34, 36);
    zero_halo_ps<<<nblk(128L * 34 * 34 * 36), blk, 0, stream>>>(h1lo, 128, 34, 36);
    conv_s2_mfma<3, 64, 32, 66, 68, 4, 2, 0, 1, 1><<<dim3(1024), blk, 0, stream>>>(
        xphi, xplo, W1hi, W1lo, enc_b1, h1hi, h1lo, nullptr, 34, 36, 1, 0);
    zero_halo_ps<<<nblk(256L * 18 * 18 * 20), blk, 0, stream>>>(h2hi, 256, 18, 20);
    zero_halo_ps<<<nblk(256L * 18 * 18 * 20), blk, 0, stream>>>(h2lo, 256, 18, 20);
    conv_s2_mfma<64, 128, 16, 34, 36, 2, 1, 0, 1, 1><<<dim3(512), blk, 0, stream>>>(
        h1hi, h1lo, W2hi, W2lo, enc_b2, h2hi, h2lo, nullptr, 18, 20, 1, 0);
    conv_s2_mfma<128, 256, 8, 18, 20, 4, 1, 1, 4, 0><<<dim3(256), blk, 0, stream>>>(
        h2hi, h2lo, W3hi, W3lo, enc_b3, nullptr, nullptr, pp3, 8, 8, 0, 262144);
    combine4_relu<<<nblk(262144), blk, 0, stream>>>(pp3, h3, 262144, 262144);
    conv1x1_b<<<dim3(512), dim3(128), 0, stream>>>(h3, enc_w4, enc_b4, lat);

    // ---- VQ (fp32 exact) ----
    codenorm_kernel<<<dim3(1024), dim3(64), 0, stream>>>(codebook, cn);
    zero_halo_t<unsigned short><<<nblk(512L * 10 * 10 * 10), blk, 0, stream>>>(qp, 512, 10);
    vq_kernel<<<dim3(1024), blk, 0, stream>>>(lat, codebook, cn, qp, idx_out);

    // ---- decoder halos ----
    zero_halo_t<unsigned short><<<nblk(256L * 18 * 18 * 18), blk, 0, stream>>>(d1, 256, 18);
    zero_halo_t<unsigned short><<<nblk(128L * 34 * 34 * 34), blk, 0, stream>>>(d2, 128, 34);

    // ---- decoder (MFMA) per batch ----
    for (int b = 0; b < 2; ++b) {
        const unsigned short* qb = qp + (long)b * 256 * 1000;
        float* outb = out + (long)b * 3 * 226981;
        convt_mfma<8, 1, unsigned short><<<dim3(8 * 8 * 4), blk, 0, stream>>>(
            qb, Ap1, dec_b1, d1, 256, 256);
        convt_mfma<16, 1, unsigned short><<<dim3(8 * 64 * 2), blk, 0, stream>>>(
            d1, Ap2, dec_b2, d2, 256, 128);
        convt_mfma<32, 0, float><<<dim3(8 * 512), blk, 0, stream>>>(
            d2, Ap3, dec_b3, d3, 128, 64);
        conv_dec4_mfma<<<dim3(8 * 8 * 16), blk, 0, stream>>>(d3, Aw4, dec_b4, outb);
    }
}

// Round 13
// 1881.161 us; speedup vs baseline: 1.3099x; 1.0002x over previous
//
#include <hip/hip_runtime.h>
#include <cfloat>
#include <cmath>

// ---------------------------------------------------------------------------
// Round 12: convt_mfma de-latency fix.
// (1) CIN/COUT now template params -> K-loop trip count is compile-time,
//     #pragma unroll 4 lets the compiler pipeline the 12 loads of steps
//     s+1..s+3 over step s's MFMAs (the runtime-arg loop had VGPR=24 and a
//     vmcnt(0) serialization every step -> 345 us with nothing busy).
// (2) Block decomposition: px innermost (pairs 8 blocks apart) -> the two
//     x-parity halves of every 64B output line are written while the line is
//     still L2-resident -> write amplification 2.3x -> ~1x.
// XCD nt-slab swizzle kept. Per-wave MFMA order unchanged => bit-identical.
// Everything else unchanged from R12.
// ---------------------------------------------------------------------------

using f32x4  = __attribute__((ext_vector_type(4))) float;
using bf16x8 = __attribute__((ext_vector_type(8))) short;
typedef float f32x4u __attribute__((ext_vector_type(4), aligned(4)));
typedef unsigned short u16x4u __attribute__((ext_vector_type(4), aligned(4)));

__device__ __forceinline__ unsigned short f32_to_bf16(float f) {
    unsigned int u = __float_as_uint(f);
    u += 0x7fffu + ((u >> 16) & 1u);          // round-to-nearest-even
    return (unsigned short)(u >> 16);
}
__device__ __forceinline__ void split_bf16(float v, unsigned short& h, unsigned short& l) {
    h = f32_to_bf16(v);
    float hf = __uint_as_float((unsigned)h << 16);
    l = f32_to_bf16(v - hf);
}
__device__ __forceinline__ void store_act(float* p, float v) { *p = v; }
__device__ __forceinline__ void store_act(unsigned short* p, float v) { *p = f32_to_bf16(v); }

template <typename V>
__device__ __forceinline__ bf16x8 pack_b(V r0, V r1) {
    bf16x8 b;
    b[0] = (short)r0[0]; b[1] = (short)r0[1]; b[2] = (short)r0[2]; b[3] = (short)r0[3];
    b[4] = (short)r1[0]; b[5] = (short)r1[1]; b[6] = (short)r1[2]; b[7] = (short)r1[3];
    return b;
}

// ---------------- prep: weight hi/lo split ----------------
__global__ __launch_bounds__(256)
void prep_split_w(const float* __restrict__ w, short* __restrict__ whi,
                  short* __restrict__ wlo, long total)
{
    long idx = (long)blockIdx.x * blockDim.x + threadIdx.x;
    if (idx >= total) return;
    unsigned short h, l;
    split_bf16(w[idx], h, l);
    whi[idx] = (short)h; wlo[idx] = (short)l;
}

// ---------------- pad input -> hi/lo bf16 pitched planes --------------------
__global__ __launch_bounds__(256)
void pad_input_split(const float* __restrict__ x, unsigned short* __restrict__ xhi,
                     unsigned short* __restrict__ xlo)
{
    const int D = 64, PD = 66, PRX = 68, BC = 6;
    long total = (long)BC * PD * PD * PRX;
    long idx = (long)blockIdx.x * blockDim.x + threadIdx.x;
    if (idx >= total) return;
    int px = (int)(idx % PRX); long t = idx / PRX;
    int py = (int)(t % PD); t /= PD;
    int pz = (int)(t % PD); int c = (int)(t / PD);
    int ix = px - 1, iy = py - 1, iz = pz - 1;
    float v = 0.0f;
    if ((unsigned)ix < (unsigned)D && (unsigned)iy < (unsigned)D && (unsigned)iz < (unsigned)D)
        v = x[(((long)c * D + iz) * D + iy) * D + ix];
    unsigned short h, l;
    split_bf16(v, h, l);
    xhi[idx] = h; xlo[idx] = l;
}

__global__ __launch_bounds__(256)
void zero_halo_ps(unsigned short* __restrict__ p, int C, int PD, int PRX)
{
    long total = (long)C * PD * PD * PRX;
    long idx = (long)blockIdx.x * blockDim.x + threadIdx.x;
    if (idx >= total) return;
    int px = (int)(idx % PRX); long t = idx / PRX;
    int py = (int)(t % PD); t /= PD;
    int pz = (int)(t % PD);
    if (px == 0 || px >= PD - 1 || py == 0 || py == PD - 1 || pz == 0 || pz == PD - 1)
        p[idx] = 0;
}

template <typename T>
__global__ __launch_bounds__(256) void zero_halo_t(T* __restrict__ p, int C, int PD)
{
    long total = (long)C * PD * PD * PD;
    long idx = (long)blockIdx.x * blockDim.x + threadIdx.x;
    if (idx >= total) return;
    int px = (int)(idx % PD); long t = idx / PD;
    int py = (int)(t % PD); t /= PD;
    int pz = (int)(t % PD);
    if (px == 0 || px == PD - 1 || py == 0 || py == PD - 1 || pz == 0 || pz == PD - 1)
        p[idx] = (T)0;
}

// ---------------------------------------------------------------------------
// Conv3d k4 s2 p1 as MFMA implicit GEMM, bf16 hi/lo pair inputs (unchanged)
// ---------------------------------------------------------------------------
template <int CIN, int COUT, int DOUT, int PD, int PRX, int MTW, int OWT,
          int OWHALF, int KSPLIT, int OUTSPLIT>
__global__ __launch_bounds__(256)
void conv_s2_mfma(const unsigned short* __restrict__ xhi,
                  const unsigned short* __restrict__ xlo,
                  const short* __restrict__ Whi, const short* __restrict__ Wlo,
                  const float* __restrict__ bias,
                  unsigned short* __restrict__ yhi, unsigned short* __restrict__ ylo,
                  float* __restrict__ yf,
                  int OPD, int OPRX, int po, long sstride)
{
    constexpr int K = CIN * 64;
    constexpr int MWAVES = COUT / (16 * MTW);
    constexpr int RPB = 4 / MWAVES;
    constexpr int KN = (CIN * 2) / KSPLIT;

    int bx = blockIdx.x;
    const int ks = (KSPLIT > 1) ? (bx % KSPLIT) : 0;
    const int rowblk = (KSPLIT > 1) ? (bx / KSPLIT) : bx;
    const int lane = (int)threadIdx.x & 63, w = (int)threadIdx.x >> 6;
    const int mi = (MWAVES == 4) ? w : 0;
    const int ri = (MWAVES == 4) ? 0 : w;
    const int rowid = rowblk * RPB + ri;
    const int n16 = lane & 15, quad = lane >> 4;

    int b, od, oh, ow;
    if (OWHALF) {
        constexpr int NOH = DOUT / 2;
        const int ohb = rowid % NOH; int t = rowid / NOH;
        od = t % DOUT; b = t / DOUT;
        oh = ohb * 2 + (n16 >> 3);
        ow = n16 & 7;
    } else {
        const int owt = rowid % OWT; int t = rowid / OWT;
        oh = t % DOUT; t /= DOUT;
        od = t % DOUT; b = t / DOUT;
        ow = owt * 16 + n16;
    }

    const int co0 = mi * (MTW * 16);

    f32x4 acc[MTW];
    #pragma unroll
    for (int mt = 0; mt < MTW; ++mt)
        #pragma unroll
        for (int r = 0; r < 4; ++r) {
            int co = co0 + mt * 16 + quad * 4 + r;
            acc[mt][r] = (ks == 0) ? bias[co] : 0.0f;
        }

    const int sg0 = ks * KN;
    const long chs = (long)PD * PD * PRX;
    long off = ((long)(b * CIN + (sg0 >> 1)) * PD + (2 * od + (quad >> 1))) * PD * PRX
             + (long)(2 * oh + (quad & 1) * 2) * PRX + 2 * ow;
    const unsigned short* phi = xhi + off;
    const unsigned short* plo = xlo + off;
    const long incA = 2L * PD * PRX;
    const long incB = chs - 2L * PD * PRX;

    const short* a0h = Whi + (long)(co0 + n16) * K + sg0 * 32 + quad * 8;
    const short* a0l = Wlo + (long)(co0 + n16) * K + sg0 * 32 + quad * 8;

    #pragma unroll 2
    for (int s = 0; s < KN; ++s) {
        u16x4u h0 = *(const u16x4u*)phi;
        u16x4u h1 = *(const u16x4u*)(phi + PRX);
        u16x4u l0 = *(const u16x4u*)plo;
        u16x4u l1 = *(const u16x4u*)(plo + PRX);
        bf16x8 bhi = pack_b(h0, h1);
        bf16x8 blo = pack_b(l0, l1);
        #pragma unroll
        for (int mt = 0; mt < MTW; ++mt) {
            bf16x8 ah = *(const bf16x8*)(a0h + (long)mt * 16 * K + s * 32);
            bf16x8 al = *(const bf16x8*)(a0l + (long)mt * 16 * K + s * 32);
            acc[mt] = __builtin_amdgcn_mfma_f32_16x16x32_bf16(ah, bhi, acc[mt], 0, 0, 0);
            acc[mt] = __builtin_amdgcn_mfma_f32_16x16x32_bf16(ah, blo, acc[mt], 0, 0, 0);
            acc[mt] = __builtin_amdgcn_mfma_f32_16x16x32_bf16(al, bhi, acc[mt], 0, 0, 0);
        }
        long inc = (s & 1) ? incB : incA;
        phi += inc; plo += inc;
    }

    if (OUTSPLIT) {
        #pragma unroll
        for (int mt = 0; mt < MTW; ++mt)
            #pragma unroll
            for (int r = 0; r < 4; ++r) {
                int co = co0 + mt * 16 + quad * 4 + r;
                float v = fmaxf(acc[mt][r], 0.0f);
                unsigned short h, l;
                split_bf16(v, h, l);
                long o = (((long)(b * COUT + co) * OPD + od + po) * OPD + oh + po) * OPRX
                       + ow + po;
                yhi[o] = h; ylo[o] = l;
            }
    } else {
        #pragma unroll
        for (int mt = 0; mt < MTW; ++mt)
            #pragma unroll
            for (int r = 0; r < 4; ++r) {
                int co = co0 + mt * 16 + quad * 4 + r;
                long o = (long)ks * sstride
                       + (((long)(b * COUT + co) * OPD + od) * OPD + oh) * OPRX + ow;
                yf[o] = acc[mt][r];
            }
    }
}

__global__ __launch_bounds__(256)
void combine4_relu(const float* __restrict__ p, float* __restrict__ y, long N, long ss)
{
    long idx = (long)blockIdx.x * blockDim.x + threadIdx.x;
    if (idx >= N) return;
    float v = p[idx] + p[idx + ss] + p[idx + 2 * ss] + p[idx + 3 * ss];
    y[idx] = fmaxf(v, 0.0f);
}

// ---------------- 1x1 conv (fp32 exact) ----------------
__global__ __launch_bounds__(128)
void conv1x1_b(const float* __restrict__ x, const float* __restrict__ w,
               const float* __restrict__ bias, float* __restrict__ y)
{
    const int co = blockIdx.x & 255, b = blockIdx.x >> 8;
    const int s4 = (int)threadIdx.x * 4;
    const float* xb = x + (long)b * 256 * 512 + s4;
    const float* wr = w + (long)co * 256;      // uniform -> s_load
    float bv = bias[co];
    float4 acc = {bv, bv, bv, bv};
    for (int ci = 0; ci < 256; ++ci) {
        float wv = wr[ci];
        float4 xv = *(const float4*)(xb + (long)ci * 512);
        acc.x = fmaf(xv.x, wv, acc.x); acc.y = fmaf(xv.y, wv, acc.y);
        acc.z = fmaf(xv.z, wv, acc.z); acc.w = fmaf(xv.w, wv, acc.w);
    }
    *(float4*)(y + (long)(b * 256 + co) * 512 + s4) = acc;
}

// ---------------- VQ (fp32 exact; unchanged) ----------------
__global__ void codenorm_kernel(const float* __restrict__ cb, float* __restrict__ norms)
{
    int k = blockIdx.x;
    int lane = threadIdx.x;
    float s = 0.0f;
    const float* row = cb + (long)k * 256;
    for (int d = lane; d < 256; d += 64) { float v = row[d]; s = fmaf(v, v, s); }
    for (int off = 32; off > 0; off >>= 1) s += __shfl_down(s, off);
    if (lane == 0) norms[k] = s;
}

__global__ __launch_bounds__(256)
void vq_kernel(const float* __restrict__ lat, const float* __restrict__ cb,
               const float* __restrict__ norms, unsigned short* __restrict__ q,
               float* __restrict__ idx_out)
{
    __shared__ __align__(16) float row[256];
    __shared__ float s_best[256];
    __shared__ int   s_bidx[256];
    int r = blockIdx.x;
    int t = threadIdx.x;
    row[t] = lat[(long)r * 256 + t];
    __syncthreads();

    const float4* rowv = (const float4*)row;
    float latn = 0.0f;
    #pragma unroll 4
    for (int d = 0; d < 64; ++d) {
        float4 rv = rowv[d];
        latn = fmaf(rv.x, rv.x, latn); latn = fmaf(rv.y, rv.y, latn);
        latn = fmaf(rv.z, rv.z, latn); latn = fmaf(rv.w, rv.w, latn);
    }

    float best = FLT_MAX;
    int bidx = 0x7fffffff;
    for (int j = 0; j < 4; ++j) {
        int k = t + 256 * j;
        const float4* cr = (const float4*)(cb + (long)k * 256);
        float dot = 0.0f;
        #pragma unroll 4
        for (int d = 0; d < 64; ++d) {
            float4 c = cr[d]; float4 rv = rowv[d];
            dot = fmaf(rv.x, c.x, dot); dot = fmaf(rv.y, c.y, dot);
            dot = fmaf(rv.z, c.z, dot); dot = fmaf(rv.w, c.w, dot);
        }
        float sc = latn - 2.0f * dot + norms[k];
        if (sc < best || (sc == best && k < bidx)) { best = sc; bidx = k; }
    }
    s_best[t] = best; s_bidx[t] = bidx;
    __syncthreads();
    for (int off = 128; off > 0; off >>= 1) {
        if (t < off) {
            float o = s_best[t + off]; int oi = s_bidx[t + off];
            if (o < s_best[t] || (o == s_best[t] && oi < s_bidx[t])) {
                s_best[t] = o; s_bidx[t] = oi;
            }
        }
        __syncthreads();
    }
    int bk = s_bidx[0];
    int b = r >> 9, n = r & 511;
    int zz = n >> 6, yy = (n >> 3) & 7, xx = n & 7;
    q[(long)(b * 256 + t) * 1000 + ((long)(zz + 1) * 10 + (yy + 1)) * 10 + (xx + 1)]
        = f32_to_bf16(cb[(long)bk * 256 + t]);
    if (t == 0) idx_out[r] = (float)bk;
}

// ---------------- decoder: MFMA implicit-GEMM ConvTranspose ----------------
__global__ __launch_bounds__(256)
void prep_convt_w(const float* __restrict__ w, short* __restrict__ Ap,
                  int Cin, int Cout)
{
    const int K = Cin * 8;
    long total = 8L * Cout * K;
    long idx = (long)blockIdx.x * blockDim.x + threadIdx.x;
    if (idx >= total) return;
    int k = (int)(idx % K);
    int co = (int)((idx / K) % Cout);
    int p = (int)(idx / ((long)K * Cout));
    int ci = k >> 3, a = k & 7;
    int az = (a >> 2) & 1, ay = (a >> 1) & 1, ax = a & 1;
    int pz = p >> 2, py = (p >> 1) & 1, px = p & 1;
    int kd = (1 - pz) + 2 * az, kh = (1 - py) + 2 * ay, kw = (1 - px) + 2 * ax;
    float v = w[((long)ci * Cout + co) * 64 + kd * 16 + kh * 4 + kw];
    Ap[idx] = (short)f32_to_bf16(v);
}

// Templated CIN/COUT (compile-time K-loop -> pipelined). Block decomp:
// bx&7 = xcd (nt-slab, R9); local: px innermost, then mg, ntin, pzy.
// grid = 8 * 2 * MG * SLAB * 4 (same total as before).
template <int CIN, int COUT, int DIN, int OPAD, typename OutT>
__global__ __launch_bounds__(256)
void convt_mfma(const unsigned short* __restrict__ Xp, const short* __restrict__ Ap,
                const float* __restrict__ bias, OutT* __restrict__ Y)
{
    constexpr int PD = DIN + 2;
    constexpr int PD3 = PD * PD * PD;
    constexpr int T = DIN >> 2;
    constexpr int NT = T * T * T;
    constexpr int SLAB = NT / 8;
    constexpr int OPD = 2 * DIN + 2 * OPAD;
    constexpr int K = CIN * 8;
    constexpr int MG = COUT >> 6;
    constexpr int nsteps = K >> 5;

    int bx = blockIdx.x;
    const int xcd = bx & 7;
    int local = bx >> 3;
    const int px = local & 1; local >>= 1;
    const int mg = local % MG; local /= MG;
    const int ntin = local % SLAB;
    const int pzy = local / SLAB;            // 0..3
    const int pz = pzy >> 1, py = pzy & 1;
    const int p = pz * 4 + py * 2 + px;
    const int nt = xcd * SLAB + ntin;

    const int lane = threadIdx.x & 63, wave = threadIdx.x >> 6;
    const int n16 = lane & 15, quad = lane >> 4;

    const int tx = nt % T, ty = (nt / T) % T, tz = nt / (T * T);
    const int mz = tz * 4 + wave, my = ty * 4 + (n16 >> 2), mx = tx * 4 + (n16 & 3);
    const int sp = ((mz + pz) * PD + (my + py)) * PD + (mx + px);

    const unsigned short* xq = Xp + (long)quad * PD3 + sp;

    const int cobase = mg * 64;
    const short* ap0 = Ap + ((long)p * COUT + cobase + n16) * K + quad * 8;

    f32x4 acc[4];
    #pragma unroll
    for (int cb = 0; cb < 4; ++cb) {
        const float* bp = bias + cobase + cb * 16 + quad * 4;
        acc[cb][0] = bp[0]; acc[cb][1] = bp[1]; acc[cb][2] = bp[2]; acc[cb][3] = bp[3];
    }

    #pragma unroll 4
    for (int s = 0; s < nsteps; ++s) {
        const unsigned short* xs = xq + (long)s * 4 * PD3;
        bf16x8 bf;
        bf[0] = (short)xs[(PD + 1) * PD + 1];
        bf[1] = (short)xs[(PD + 1) * PD];
        bf[2] = (short)xs[PD * PD + 1];
        bf[3] = (short)xs[PD * PD];
        bf[4] = (short)xs[PD + 1];
        bf[5] = (short)xs[PD];
        bf[6] = (short)xs[1];
        bf[7] = (short)xs[0];
        #pragma unroll
        for (int cb = 0; cb < 4; ++cb) {
            bf16x8 af = *(const bf16x8*)(ap0 + (long)cb * 16 * K + s * 32);
            acc[cb] = __builtin_amdgcn_mfma_f32_16x16x32_bf16(af, bf, acc[cb], 0, 0, 0);
        }
    }

    const int opz = 2 * mz + pz + OPAD, opy = 2 * my + py + OPAD, opx = 2 * mx + px + OPAD;
    const long spo = ((long)opz * OPD + opy) * OPD + opx;
    #pragma unroll
    for (int cb = 0; cb < 4; ++cb) {
        #pragma unroll
        for (int r = 0; r < 4; ++r) {
            int co = cobase + cb * 16 + quad * 4 + r;
            float v = fmaxf(acc[cb][r], 0.0f);
            store_act(Y + (long)co * OPD * OPD * OPD + spo, v);
        }
    }
}

// ---------------- dec4 as MFMA GEMM: 4 oh rows per wave (unchanged) ---------
__global__ __launch_bounds__(256)
void prep_dec4A(const float* __restrict__ w, short* __restrict__ Aw)
{
    int idx = blockIdx.x * 256 + (int)threadIdx.x;    // 0..65535
    int m = idx >> 12, k = idx & 4095;
    float v = (m < 3) ? w[m * 4096 + k] : 0.0f;
    Aw[idx] = (short)f32_to_bf16(v);
}

__global__ __launch_bounds__(256)
void conv_dec4_mfma(const float* __restrict__ d3, const short* __restrict__ Aw,
                    const float* __restrict__ bias, float* __restrict__ y)
{
    constexpr int D = 64, Dout = 61;
    int bx = blockIdx.x;
    const int slab = bx & 7;
    const int i = bx >> 3;                 // 0..127
    const int od = slab * 8 + (i >> 4);
    const int oh0 = (i & 15) * 4;          // covers oh0..oh0+3 (guard < 61)
    if (od >= Dout) return;
    const int lane = (int)threadIdx.x & 63, wave = (int)threadIdx.x >> 6;
    const int n16 = lane & 15, quad = lane >> 4;
    const int ow = wave * 16 + n16;

    f32x4 acc[4];
    #pragma unroll
    for (int j = 0; j < 4; ++j)
        #pragma unroll
        for (int r = 0; r < 4; ++r) {
            int co = quad * 4 + r;
            acc[j][r] = (co < 3) ? bias[co] : 0.0f;
        }

    const short* ap = Aw + (long)n16 * 4096 + quad * 8;   // m = lane&15
    const int kd0 = quad >> 1;
    const int kh0 = (quad & 1) * 2;
    const float* basez = d3 + ((long)(od + kd0) * D) * D + ow;
    int yoff[5];
    #pragma unroll
    for (int r = 0; r < 5; ++r) yoff[r] = min(oh0 + kh0 + r, D - 1) * D;

    #pragma unroll 4
    for (int s = 0; s < 128; ++s) {
        const int ci = s >> 1;
        const float* plane = basez + ((long)ci * D + (s & 1) * 2) * D * D;
        unsigned p0[5], p1[5];
        #pragma unroll
        for (int r = 0; r < 5; ++r) {
            f32x4u v = *(const f32x4u*)(plane + yoff[r]);
            p0[r] = (__float_as_uint(v[0]) >> 16) | (__float_as_uint(v[1]) & 0xffff0000u);
            p1[r] = (__float_as_uint(v[2]) >> 16) | (__float_as_uint(v[3]) & 0xffff0000u);
        }
        bf16x8 af = *(const bf16x8*)(ap + s * 32);
        #pragma unroll
        for (int j = 0; j < 4; ++j) {
            union { unsigned u[4]; bf16x8 b; } fr;
            fr.u[0] = p0[j];     fr.u[1] = p1[j];
            fr.u[2] = p0[j + 1]; fr.u[3] = p1[j + 1];
            acc[j] = __builtin_amdgcn_mfma_f32_16x16x32_bf16(af, fr.b, acc[j], 0, 0, 0);
        }
    }

    if (ow < Dout && quad == 0) {
        #pragma unroll
        for (int j = 0; j < 4; ++j) {
            const int oh = oh0 + j;
            if (oh >= Dout) continue;
            #pragma unroll
            for (int r = 0; r < 3; ++r)
                y[((long)(r * Dout + od) * Dout + oh) * Dout + ow] = tanhf(acc[j][r]);
        }
    }
}

extern "C" void kernel_launch(void* const* d_in, const int* in_sizes, int n_in,
                              void* d_out, int out_size, void* d_ws, size_t ws_size,
                              hipStream_t stream)
{
    const float* x        = (const float*)d_in[0];
    const float* enc_w1   = (const float*)d_in[1];
    const float* enc_b1   = (const float*)d_in[2];
    const float* enc_w2   = (const float*)d_in[3];
    const float* enc_b2   = (const float*)d_in[4];
    const float* enc_w3   = (const float*)d_in[5];
    const float* enc_b3   = (const float*)d_in[6];
    const float* enc_w4   = (const float*)d_in[7];
    const float* enc_b4   = (const float*)d_in[8];
    const float* codebook = (const float*)d_in[9];
    const float* dec_w1   = (const float*)d_in[10];
    const float* dec_b1   = (const float*)d_in[11];
    const float* dec_w2   = (const float*)d_in[12];
    const float* dec_b2   = (const float*)d_in[13];
    const float* dec_w3   = (const float*)d_in[14];
    const float* dec_b3   = (const float*)d_in[15];
    const float* dec_w4   = (const float*)d_in[16];
    const float* dec_b4   = (const float*)d_in[17];

    float* out = (float*)d_out;
    float* idx_out = out + 2L * 3 * 61 * 61 * 61;

    // ---- workspace (byte offsets) ----
    char* wsb = (char*)d_ws;
    float*          cn   = (float*)wsb;                        //      4,096
    unsigned short* qp   = (unsigned short*)(wsb + 4096);      //  1,024,000
    short*          Ap1  = (short*)(wsb + 1028096);            //  8,388,608
    short*          Ap2  = (short*)(wsb + 9416704);            //  4,194,304
    short*          Ap3  = (short*)(wsb + 13611008);           //  1,048,576
    short*          Aw4  = (short*)(wsb + 14659584);           //    131,072
    short*          W1hi = (short*)(wsb + 14790656);           //     24,576
    short*          W1lo = (short*)(wsb + 14815232);           //     24,576
    short*          W2hi = (short*)(wsb + 14839808);           //  1,048,576
    short*          W2lo = (short*)(wsb + 15888384);           //  1,048,576
    short*          W3hi = (short*)(wsb + 16936960);           //  4,194,304
    short*          W3lo = (short*)(wsb + 21131264);           //  4,194,304
    char* arena = wsb + 25325568;
    // encoder phase:
    unsigned short* xphi = (unsigned short*)arena;                    // (2,3,66,66,68)
    unsigned short* xplo = (unsigned short*)(arena + 3554496);
    unsigned short* h1hi = (unsigned short*)(arena + 7108992);        // (2,64,34,34,36)
    unsigned short* h1lo = (unsigned short*)(arena + 17762688);
    unsigned short* h2hi = (unsigned short*)(arena + 28416384);       // (2,128,18,18,20)
    unsigned short* h2lo = (unsigned short*)(arena + 31734144);
    float*          pp3  = (float*)(arena + 35051904);                // 4x(2,256,8^3)
    float*          h3   = (float*)(arena + 39246208);                // (2,256,512)
    float*          lat  = (float*)(arena + 40294784);                // (2,256,512)
    // decoder phase (after VQ; overlaps encoder buffers):
    unsigned short* d1 = (unsigned short*)arena;                      // (256,18^3) bf16
    unsigned short* d2 = (unsigned short*)(arena + 2985984);          // (128,34^3) bf16
    float*          d3 = (float*)(arena + 13047808);                  // (64,64^3) fp32
    // arena peak 80.2 MB; total 105.5 MB (< 112.2 MB proven in R0)

    dim3 blk(256);
    auto nblk = [](long n) { return dim3((unsigned)((n + 255) / 256)); };

    // ---- weight prep ----
    prep_convt_w<<<nblk(8L * 256 * 2048), blk, 0, stream>>>(dec_w1, Ap1, 256, 256);
    prep_convt_w<<<nblk(8L * 128 * 2048), blk, 0, stream>>>(dec_w2, Ap2, 256, 128);
    prep_convt_w<<<nblk(8L * 64 * 1024), blk, 0, stream>>>(dec_w3, Ap3, 128, 64);
    prep_dec4A<<<dim3(256), blk, 0, stream>>>(dec_w4, Aw4);
    prep_split_w<<<nblk(12288), blk, 0, stream>>>(enc_w1, W1hi, W1lo, 12288);
    prep_split_w<<<nblk(524288), blk, 0, stream>>>(enc_w2, W2hi, W2lo, 524288);
    prep_split_w<<<nblk(2097152), blk, 0, stream>>>(enc_w3, W3hi, W3lo, 2097152);

    // ---- encoder (MFMA, bf16-pair) ----
    pad_input_split<<<nblk(6L * 66 * 66 * 68), blk, 0, stream>>>(x, xphi, xplo);
    zero_halo_ps<<<nblk(128L * 34 * 34 * 36), blk, 0, stream>>>(h1hi, 128, 34, 36);
    zero_halo_ps<<<nblk(128L * 34 * 34 * 36), blk, 0, stream>>>(h1lo, 128, 34, 36);
    conv_s2_mfma<3, 64, 32, 66, 68, 4, 2, 0, 1, 1><<<dim3(1024), blk, 0, stream>>>(
        xphi, xplo, W1hi, W1lo, enc_b1, h1hi, h1lo, nullptr, 34, 36, 1, 0);
    zero_halo_ps<<<nblk(256L * 18 * 18 * 20), blk, 0, stream>>>(h2hi, 256, 18, 20);
    zero_halo_ps<<<nblk(256L * 18 * 18 * 20), blk, 0, stream>>>(h2lo, 256, 18, 20);
    conv_s2_mfma<64, 128, 16, 34, 36, 2, 1, 0, 1, 1><<<dim3(512), blk, 0, stream>>>(
        h1hi, h1lo, W2hi, W2lo, enc_b2, h2hi, h2lo, nullptr, 18, 20, 1, 0);
    conv_s2_mfma<128, 256, 8, 18, 20, 4, 1, 1, 4, 0><<<dim3(256), blk, 0, stream>>>(
        h2hi, h2lo, W3hi, W3lo, enc_b3, nullptr, nullptr, pp3, 8, 8, 0, 262144);
    combine4_relu<<<nblk(262144), blk, 0, stream>>>(pp3, h3, 262144, 262144);
    conv1x1_b<<<dim3(512), dim3(128), 0, stream>>>(h3, enc_w4, enc_b4, lat);

    // ---- VQ (fp32 exact) ----
    codenorm_kernel<<<dim3(1024), dim3(64), 0, stream>>>(codebook, cn);
    zero_halo_t<unsigned short><<<nblk(512L * 10 * 10 * 10), blk, 0, stream>>>(qp, 512, 10);
    vq_kernel<<<dim3(1024), blk, 0, stream>>>(lat, codebook, cn, qp, idx_out);

    // ---- decoder halos ----
    zero_halo_t<unsigned short><<<nblk(256L * 18 * 18 * 18), blk, 0, stream>>>(d1, 256, 18);
    zero_halo_t<unsigned short><<<nblk(128L * 34 * 34 * 34), blk, 0, stream>>>(d2, 128, 34);

    // ---- decoder (MFMA) per batch ----
    for (int b = 0; b < 2; ++b) {
        const unsigned short* qb = qp + (long)b * 256 * 1000;
        float* outb = out + (long)b * 3 * 226981;
        // dec1: CIN=256 COUT=256 DIN=8:  grid = 8*2*4*1*4 = 256
        convt_mfma<256, 256, 8, 1, unsigned short><<<dim3(256), blk, 0, stream>>>(
            qb, Ap1, dec_b1, d1);
        // dec2: CIN=256 COUT=128 DIN=16: grid = 8*2*2*8*4 = 1024
        convt_mfma<256, 128, 16, 1, unsigned short><<<dim3(1024), blk, 0, stream>>>(
            d1, Ap2, dec_b2, d2);
        // dec3: CIN=128 COUT=64 DIN=32:  grid = 8*2*1*64*4 = 4096
        convt_mfma<128, 64, 32, 0, float><<<dim3(4096), blk, 0, stream>>>(
            d2, Ap3, dec_b3, d3);
        conv_dec4_mfma<<<dim3(8 * 8 * 16), blk, 0, stream>>>(d3, Aw4, dec_b4, outb);
    }
}

// Round 14
// 1798.669 us; speedup vs baseline: 1.3699x; 1.0459x over previous
//
#include <hip/hip_runtime.h>
#include <cfloat>
#include <cmath>

// ---------------------------------------------------------------------------
// Round 13: convt_mfma B-gather coalescing. R13 showed dec3 at 342 us with
// traffic at compulsory minimum and nothing busy -> the wall is address
// divergence: the old N-map (4x4x4 cube) made every ushort B-load touch ~64
// cache lines. New kernel convt_mfma_x16: n16 -> 16 consecutive mx, wave ->
// my, block -> (mz, myt, mxt, parity) with mz-slab XCD swizzle; each B-load
// is lane-contiguous (~4 lines/instr). A-indexing and K-order untouched =>
// bit-identical. dec1 (DIN=8) keeps the old kernel. Everything else = R13.
// ---------------------------------------------------------------------------

using f32x4  = __attribute__((ext_vector_type(4))) float;
using bf16x8 = __attribute__((ext_vector_type(8))) short;
typedef float f32x4u __attribute__((ext_vector_type(4), aligned(4)));
typedef unsigned short u16x4u __attribute__((ext_vector_type(4), aligned(4)));

__device__ __forceinline__ unsigned short f32_to_bf16(float f) {
    unsigned int u = __float_as_uint(f);
    u += 0x7fffu + ((u >> 16) & 1u);          // round-to-nearest-even
    return (unsigned short)(u >> 16);
}
__device__ __forceinline__ void split_bf16(float v, unsigned short& h, unsigned short& l) {
    h = f32_to_bf16(v);
    float hf = __uint_as_float((unsigned)h << 16);
    l = f32_to_bf16(v - hf);
}
__device__ __forceinline__ void store_act(float* p, float v) { *p = v; }
__device__ __forceinline__ void store_act(unsigned short* p, float v) { *p = f32_to_bf16(v); }

template <typename V>
__device__ __forceinline__ bf16x8 pack_b(V r0, V r1) {
    bf16x8 b;
    b[0] = (short)r0[0]; b[1] = (short)r0[1]; b[2] = (short)r0[2]; b[3] = (short)r0[3];
    b[4] = (short)r1[0]; b[5] = (short)r1[1]; b[6] = (short)r1[2]; b[7] = (short)r1[3];
    return b;
}

// ---------------- prep: weight hi/lo split ----------------
__global__ __launch_bounds__(256)
void prep_split_w(const float* __restrict__ w, short* __restrict__ whi,
                  short* __restrict__ wlo, long total)
{
    long idx = (long)blockIdx.x * blockDim.x + threadIdx.x;
    if (idx >= total) return;
    unsigned short h, l;
    split_bf16(w[idx], h, l);
    whi[idx] = (short)h; wlo[idx] = (short)l;
}

// ---------------- pad input -> hi/lo bf16 pitched planes --------------------
__global__ __launch_bounds__(256)
void pad_input_split(const float* __restrict__ x, unsigned short* __restrict__ xhi,
                     unsigned short* __restrict__ xlo)
{
    const int D = 64, PD = 66, PRX = 68, BC = 6;
    long total = (long)BC * PD * PD * PRX;
    long idx = (long)blockIdx.x * blockDim.x + threadIdx.x;
    if (idx >= total) return;
    int px = (int)(idx % PRX); long t = idx / PRX;
    int py = (int)(t % PD); t /= PD;
    int pz = (int)(t % PD); int c = (int)(t / PD);
    int ix = px - 1, iy = py - 1, iz = pz - 1;
    float v = 0.0f;
    if ((unsigned)ix < (unsigned)D && (unsigned)iy < (unsigned)D && (unsigned)iz < (unsigned)D)
        v = x[(((long)c * D + iz) * D + iy) * D + ix];
    unsigned short h, l;
    split_bf16(v, h, l);
    xhi[idx] = h; xlo[idx] = l;
}

__global__ __launch_bounds__(256)
void zero_halo_ps(unsigned short* __restrict__ p, int C, int PD, int PRX)
{
    long total = (long)C * PD * PD * PRX;
    long idx = (long)blockIdx.x * blockDim.x + threadIdx.x;
    if (idx >= total) return;
    int px = (int)(idx % PRX); long t = idx / PRX;
    int py = (int)(t % PD); t /= PD;
    int pz = (int)(t % PD);
    if (px == 0 || px >= PD - 1 || py == 0 || py == PD - 1 || pz == 0 || pz == PD - 1)
        p[idx] = 0;
}

template <typename T>
__global__ __launch_bounds__(256) void zero_halo_t(T* __restrict__ p, int C, int PD)
{
    long total = (long)C * PD * PD * PD;
    long idx = (long)blockIdx.x * blockDim.x + threadIdx.x;
    if (idx >= total) return;
    int px = (int)(idx % PD); long t = idx / PD;
    int py = (int)(t % PD); t /= PD;
    int pz = (int)(t % PD);
    if (px == 0 || px == PD - 1 || py == 0 || py == PD - 1 || pz == 0 || pz == PD - 1)
        p[idx] = (T)0;
}

// ---------------------------------------------------------------------------
// Conv3d k4 s2 p1 as MFMA implicit GEMM, bf16 hi/lo pair inputs (unchanged)
// ---------------------------------------------------------------------------
template <int CIN, int COUT, int DOUT, int PD, int PRX, int MTW, int OWT,
          int OWHALF, int KSPLIT, int OUTSPLIT>
__global__ __launch_bounds__(256)
void conv_s2_mfma(const unsigned short* __restrict__ xhi,
                  const unsigned short* __restrict__ xlo,
                  const short* __restrict__ Whi, const short* __restrict__ Wlo,
                  const float* __restrict__ bias,
                  unsigned short* __restrict__ yhi, unsigned short* __restrict__ ylo,
                  float* __restrict__ yf,
                  int OPD, int OPRX, int po, long sstride)
{
    constexpr int K = CIN * 64;
    constexpr int MWAVES = COUT / (16 * MTW);
    constexpr int RPB = 4 / MWAVES;
    constexpr int KN = (CIN * 2) / KSPLIT;

    int bx = blockIdx.x;
    const int ks = (KSPLIT > 1) ? (bx % KSPLIT) : 0;
    const int rowblk = (KSPLIT > 1) ? (bx / KSPLIT) : bx;
    const int lane = (int)threadIdx.x & 63, w = (int)threadIdx.x >> 6;
    const int mi = (MWAVES == 4) ? w : 0;
    const int ri = (MWAVES == 4) ? 0 : w;
    const int rowid = rowblk * RPB + ri;
    const int n16 = lane & 15, quad = lane >> 4;

    int b, od, oh, ow;
    if (OWHALF) {
        constexpr int NOH = DOUT / 2;
        const int ohb = rowid % NOH; int t = rowid / NOH;
        od = t % DOUT; b = t / DOUT;
        oh = ohb * 2 + (n16 >> 3);
        ow = n16 & 7;
    } else {
        const int owt = rowid % OWT; int t = rowid / OWT;
        oh = t % DOUT; t /= DOUT;
        od = t % DOUT; b = t / DOUT;
        ow = owt * 16 + n16;
    }

    const int co0 = mi * (MTW * 16);

    f32x4 acc[MTW];
    #pragma unroll
    for (int mt = 0; mt < MTW; ++mt)
        #pragma unroll
        for (int r = 0; r < 4; ++r) {
            int co = co0 + mt * 16 + quad * 4 + r;
            acc[mt][r] = (ks == 0) ? bias[co] : 0.0f;
        }

    const int sg0 = ks * KN;
    const long chs = (long)PD * PD * PRX;
    long off = ((long)(b * CIN + (sg0 >> 1)) * PD + (2 * od + (quad >> 1))) * PD * PRX
             + (long)(2 * oh + (quad & 1) * 2) * PRX + 2 * ow;
    const unsigned short* phi = xhi + off;
    const unsigned short* plo = xlo + off;
    const long incA = 2L * PD * PRX;
    const long incB = chs - 2L * PD * PRX;

    const short* a0h = Whi + (long)(co0 + n16) * K + sg0 * 32 + quad * 8;
    const short* a0l = Wlo + (long)(co0 + n16) * K + sg0 * 32 + quad * 8;

    #pragma unroll 2
    for (int s = 0; s < KN; ++s) {
        u16x4u h0 = *(const u16x4u*)phi;
        u16x4u h1 = *(const u16x4u*)(phi + PRX);
        u16x4u l0 = *(const u16x4u*)plo;
        u16x4u l1 = *(const u16x4u*)(plo + PRX);
        bf16x8 bhi = pack_b(h0, h1);
        bf16x8 blo = pack_b(l0, l1);
        #pragma unroll
        for (int mt = 0; mt < MTW; ++mt) {
            bf16x8 ah = *(const bf16x8*)(a0h + (long)mt * 16 * K + s * 32);
            bf16x8 al = *(const bf16x8*)(a0l + (long)mt * 16 * K + s * 32);
            acc[mt] = __builtin_amdgcn_mfma_f32_16x16x32_bf16(ah, bhi, acc[mt], 0, 0, 0);
            acc[mt] = __builtin_amdgcn_mfma_f32_16x16x32_bf16(ah, blo, acc[mt], 0, 0, 0);
            acc[mt] = __builtin_amdgcn_mfma_f32_16x16x32_bf16(al, bhi, acc[mt], 0, 0, 0);
        }
        long inc = (s & 1) ? incB : incA;
        phi += inc; plo += inc;
    }

    if (OUTSPLIT) {
        #pragma unroll
        for (int mt = 0; mt < MTW; ++mt)
            #pragma unroll
            for (int r = 0; r < 4; ++r) {
                int co = co0 + mt * 16 + quad * 4 + r;
                float v = fmaxf(acc[mt][r], 0.0f);
                unsigned short h, l;
                split_bf16(v, h, l);
                long o = (((long)(b * COUT + co) * OPD + od + po) * OPD + oh + po) * OPRX
                       + ow + po;
                yhi[o] = h; ylo[o] = l;
            }
    } else {
        #pragma unroll
        for (int mt = 0; mt < MTW; ++mt)
            #pragma unroll
            for (int r = 0; r < 4; ++r) {
                int co = co0 + mt * 16 + quad * 4 + r;
                long o = (long)ks * sstride
                       + (((long)(b * COUT + co) * OPD + od) * OPD + oh) * OPRX + ow;
                yf[o] = acc[mt][r];
            }
    }
}

__global__ __launch_bounds__(256)
void combine4_relu(const float* __restrict__ p, float* __restrict__ y, long N, long ss)
{
    long idx = (long)blockIdx.x * blockDim.x + threadIdx.x;
    if (idx >= N) return;
    float v = p[idx] + p[idx + ss] + p[idx + 2 * ss] + p[idx + 3 * ss];
    y[idx] = fmaxf(v, 0.0f);
}

// ---------------- 1x1 conv (fp32 exact) ----------------
__global__ __launch_bounds__(128)
void conv1x1_b(const float* __restrict__ x, const float* __restrict__ w,
               const float* __restrict__ bias, float* __restrict__ y)
{
    const int co = blockIdx.x & 255, b = blockIdx.x >> 8;
    const int s4 = (int)threadIdx.x * 4;
    const float* xb = x + (long)b * 256 * 512 + s4;
    const float* wr = w + (long)co * 256;      // uniform -> s_load
    float bv = bias[co];
    float4 acc = {bv, bv, bv, bv};
    for (int ci = 0; ci < 256; ++ci) {
        float wv = wr[ci];
        float4 xv = *(const float4*)(xb + (long)ci * 512);
        acc.x = fmaf(xv.x, wv, acc.x); acc.y = fmaf(xv.y, wv, acc.y);
        acc.z = fmaf(xv.z, wv, acc.z); acc.w = fmaf(xv.w, wv, acc.w);
    }
    *(float4*)(y + (long)(b * 256 + co) * 512 + s4) = acc;
}

// ---------------- VQ (fp32 exact; unchanged) ----------------
__global__ void codenorm_kernel(const float* __restrict__ cb, float* __restrict__ norms)
{
    int k = blockIdx.x;
    int lane = threadIdx.x;
    float s = 0.0f;
    const float* row = cb + (long)k * 256;
    for (int d = lane; d < 256; d += 64) { float v = row[d]; s = fmaf(v, v, s); }
    for (int off = 32; off > 0; off >>= 1) s += __shfl_down(s, off);
    if (lane == 0) norms[k] = s;
}

__global__ __launch_bounds__(256)
void vq_kernel(const float* __restrict__ lat, const float* __restrict__ cb,
               const float* __restrict__ norms, unsigned short* __restrict__ q,
               float* __restrict__ idx_out)
{
    __shared__ __align__(16) float row[256];
    __shared__ float s_best[256];
    __shared__ int   s_bidx[256];
    int r = blockIdx.x;
    int t = threadIdx.x;
    row[t] = lat[(long)r * 256 + t];
    __syncthreads();

    const float4* rowv = (const float4*)row;
    float latn = 0.0f;
    #pragma unroll 4
    for (int d = 0; d < 64; ++d) {
        float4 rv = rowv[d];
        latn = fmaf(rv.x, rv.x, latn); latn = fmaf(rv.y, rv.y, latn);
        latn = fmaf(rv.z, rv.z, latn); latn = fmaf(rv.w, rv.w, latn);
    }

    float best = FLT_MAX;
    int bidx = 0x7fffffff;
    for (int j = 0; j < 4; ++j) {
        int k = t + 256 * j;
        const float4* cr = (const float4*)(cb + (long)k * 256);
        float dot = 0.0f;
        #pragma unroll 4
        for (int d = 0; d < 64; ++d) {
            float4 c = cr[d]; float4 rv = rowv[d];
            dot = fmaf(rv.x, c.x, dot); dot = fmaf(rv.y, c.y, dot);
            dot = fmaf(rv.z, c.z, dot); dot = fmaf(rv.w, c.w, dot);
        }
        float sc = latn - 2.0f * dot + norms[k];
        if (sc < best || (sc == best && k < bidx)) { best = sc; bidx = k; }
    }
    s_best[t] = best; s_bidx[t] = bidx;
    __syncthreads();
    for (int off = 128; off > 0; off >>= 1) {
        if (t < off) {
            float o = s_best[t + off]; int oi = s_bidx[t + off];
            if (o < s_best[t] || (o == s_best[t] && oi < s_bidx[t])) {
                s_best[t] = o; s_bidx[t] = oi;
            }
        }
        __syncthreads();
    }
    int bk = s_bidx[0];
    int b = r >> 9, n = r & 511;
    int zz = n >> 6, yy = (n >> 3) & 7, xx = n & 7;
    q[(long)(b * 256 + t) * 1000 + ((long)(zz + 1) * 10 + (yy + 1)) * 10 + (xx + 1)]
        = f32_to_bf16(cb[(long)bk * 256 + t]);
    if (t == 0) idx_out[r] = (float)bk;
}

// ---------------- decoder: MFMA implicit-GEMM ConvTranspose ----------------
__global__ __launch_bounds__(256)
void prep_convt_w(const float* __restrict__ w, short* __restrict__ Ap,
                  int Cin, int Cout)
{
    const int K = Cin * 8;
    long total = 8L * Cout * K;
    long idx = (long)blockIdx.x * blockDim.x + threadIdx.x;
    if (idx >= total) return;
    int k = (int)(idx % K);
    int co = (int)((idx / K) % Cout);
    int p = (int)(idx / ((long)K * Cout));
    int ci = k >> 3, a = k & 7;
    int az = (a >> 2) & 1, ay = (a >> 1) & 1, ax = a & 1;
    int pz = p >> 2, py = (p >> 1) & 1, px = p & 1;
    int kd = (1 - pz) + 2 * az, kh = (1 - py) + 2 * ay, kw = (1 - px) + 2 * ax;
    float v = w[((long)ci * Cout + co) * 64 + kd * 16 + kh * 4 + kw];
    Ap[idx] = (short)f32_to_bf16(v);
}

// Old cube-N layout (kept for dec1, DIN=8): nt-slab XCD swizzle + px inner.
template <int CIN, int COUT, int DIN, int OPAD, typename OutT>
__global__ __launch_bounds__(256)
void convt_mfma(const unsigned short* __restrict__ Xp, const short* __restrict__ Ap,
                const float* __restrict__ bias, OutT* __restrict__ Y)
{
    constexpr int PD = DIN + 2;
    constexpr int PD3 = PD * PD * PD;
    constexpr int T = DIN >> 2;
    constexpr int NT = T * T * T;
    constexpr int SLAB = NT / 8;
    constexpr int OPD = 2 * DIN + 2 * OPAD;
    constexpr int K = CIN * 8;
    constexpr int MG = COUT >> 6;
    constexpr int nsteps = K >> 5;

    int bx = blockIdx.x;
    const int xcd = bx & 7;
    int local = bx >> 3;
    const int px = local & 1; local >>= 1;
    const int mg = local % MG; local /= MG;
    const int ntin = local % SLAB;
    const int pzy = local / SLAB;            // 0..3
    const int pz = pzy >> 1, py = pzy & 1;
    const int p = pz * 4 + py * 2 + px;
    const int nt = xcd * SLAB + ntin;

    const int lane = threadIdx.x & 63, wave = threadIdx.x >> 6;
    const int n16 = lane & 15, quad = lane >> 4;

    const int tx = nt % T, ty = (nt / T) % T, tz = nt / (T * T);
    const int mz = tz * 4 + wave, my = ty * 4 + (n16 >> 2), mx = tx * 4 + (n16 & 3);
    const int sp = ((mz + pz) * PD + (my + py)) * PD + (mx + px);

    const unsigned short* xq = Xp + (long)quad * PD3 + sp;

    const int cobase = mg * 64;
    const short* ap0 = Ap + ((long)p * COUT + cobase + n16) * K + quad * 8;

    f32x4 acc[4];
    #pragma unroll
    for (int cb = 0; cb < 4; ++cb) {
        const float* bp = bias + cobase + cb * 16 + quad * 4;
        acc[cb][0] = bp[0]; acc[cb][1] = bp[1]; acc[cb][2] = bp[2]; acc[cb][3] = bp[3];
    }

    #pragma unroll 4
    for (int s = 0; s < nsteps; ++s) {
        const unsigned short* xs = xq + (long)s * 4 * PD3;
        bf16x8 bf;
        bf[0] = (short)xs[(PD + 1) * PD + 1];
        bf[1] = (short)xs[(PD + 1) * PD];
        bf[2] = (short)xs[PD * PD + 1];
        bf[3] = (short)xs[PD * PD];
        bf[4] = (short)xs[PD + 1];
        bf[5] = (short)xs[PD];
        bf[6] = (short)xs[1];
        bf[7] = (short)xs[0];
        #pragma unroll
        for (int cb = 0; cb < 4; ++cb) {
            bf16x8 af = *(const bf16x8*)(ap0 + (long)cb * 16 * K + s * 32);
            acc[cb] = __builtin_amdgcn_mfma_f32_16x16x32_bf16(af, bf, acc[cb], 0, 0, 0);
        }
    }

    const int opz = 2 * mz + pz + OPAD, opy = 2 * my + py + OPAD, opx = 2 * mx + px + OPAD;
    const long spo = ((long)opz * OPD + opy) * OPD + opx;
    #pragma unroll
    for (int cb = 0; cb < 4; ++cb) {
        #pragma unroll
        for (int r = 0; r < 4; ++r) {
            int co = cobase + cb * 16 + quad * 4 + r;
            float v = fmaxf(acc[cb][r], 0.0f);
            store_act(Y + (long)co * OPD * OPD * OPD + spo, v);
        }
    }
}

// New x16-N layout (dec2/dec3): n16 -> 16 consecutive mx (lane-contiguous
// B-loads), wave -> my, block -> (mzin, pz, myt, mxt, mg, py, px) with
// mz-slab XCD swizzle. A-indexing / K-order unchanged => bit-identical.
template <int CIN, int COUT, int DIN, int OPAD, typename OutT>
__global__ __launch_bounds__(256)
void convt_mfma_x16(const unsigned short* __restrict__ Xp, const short* __restrict__ Ap,
                    const float* __restrict__ bias, OutT* __restrict__ Y)
{
    constexpr int PD = DIN + 2;
    constexpr int PD3 = PD * PD * PD;
    constexpr int OPD = 2 * DIN + 2 * OPAD;
    constexpr int K = CIN * 8;
    constexpr int MG = COUT >> 6;
    constexpr int nsteps = K >> 5;
    constexpr int MXT = DIN / 16;
    constexpr int MYT = DIN / 4;
    constexpr int MZS = DIN / 8;             // mz per XCD slab

    int bx = blockIdx.x;
    const int xcd = bx & 7;
    int local = bx >> 3;
    const int px = local & 1; local >>= 1;
    const int py = local & 1; local >>= 1;
    const int mg = local % MG; local /= MG;
    const int mxt = local % MXT; local /= MXT;
    const int myt = local % MYT; local /= MYT;
    const int pz = local & 1; local >>= 1;
    const int mzin = local;                  // 0..MZS-1
    const int mz = xcd * MZS + mzin;
    const int p = pz * 4 + py * 2 + px;

    const int lane = threadIdx.x & 63, wave = threadIdx.x >> 6;
    const int n16 = lane & 15, quad = lane >> 4;

    const int mx = mxt * 16 + n16;
    const int my = myt * 4 + wave;
    const int sp = ((mz + pz) * PD + (my + py)) * PD + (mx + px);

    const unsigned short* xq = Xp + (long)quad * PD3 + sp;

    const int cobase = mg * 64;
    const short* ap0 = Ap + ((long)p * COUT + cobase + n16) * K + quad * 8;

    f32x4 acc[4];
    #pragma unroll
    for (int cb = 0; cb < 4; ++cb) {
        const float* bp = bias + cobase + cb * 16 + quad * 4;
        acc[cb][0] = bp[0]; acc[cb][1] = bp[1]; acc[cb][2] = bp[2]; acc[cb][3] = bp[3];
    }

    #pragma unroll 4
    for (int s = 0; s < nsteps; ++s) {
        const unsigned short* xs = xq + (long)s * 4 * PD3;
        bf16x8 bf;
        bf[0] = (short)xs[(PD + 1) * PD + 1];
        bf[1] = (short)xs[(PD + 1) * PD];
        bf[2] = (short)xs[PD * PD + 1];
        bf[3] = (short)xs[PD * PD];
        bf[4] = (short)xs[PD + 1];
        bf[5] = (short)xs[PD];
        bf[6] = (short)xs[1];
        bf[7] = (short)xs[0];
        #pragma unroll
        for (int cb = 0; cb < 4; ++cb) {
            bf16x8 af = *(const bf16x8*)(ap0 + (long)cb * 16 * K + s * 32);
            acc[cb] = __builtin_amdgcn_mfma_f32_16x16x32_bf16(af, bf, acc[cb], 0, 0, 0);
        }
    }

    const int opz = 2 * mz + pz + OPAD, opy = 2 * my + py + OPAD, opx = 2 * mx + px + OPAD;
    const long spo = ((long)opz * OPD + opy) * OPD + opx;
    #pragma unroll
    for (int cb = 0; cb < 4; ++cb) {
        #pragma unroll
        for (int r = 0; r < 4; ++r) {
            int co = cobase + cb * 16 + quad * 4 + r;
            float v = fmaxf(acc[cb][r], 0.0f);
            store_act(Y + (long)co * OPD * OPD * OPD + spo, v);
        }
    }
}

// ---------------- dec4 as MFMA GEMM: 4 oh rows per wave (unchanged) ---------
__global__ __launch_bounds__(256)
void prep_dec4A(const float* __restrict__ w, short* __restrict__ Aw)
{
    int idx = blockIdx.x * 256 + (int)threadIdx.x;    // 0..65535
    int m = idx >> 12, k = idx & 4095;
    float v = (m < 3) ? w[m * 4096 + k] : 0.0f;
    Aw[idx] = (short)f32_to_bf16(v);
}

__global__ __launch_bounds__(256)
void conv_dec4_mfma(const float* __restrict__ d3, const short* __restrict__ Aw,
                    const float* __restrict__ bias, float* __restrict__ y)
{
    constexpr int D = 64, Dout = 61;
    int bx = blockIdx.x;
    const int slab = bx & 7;
    const int i = bx >> 3;                 // 0..127
    const int od = slab * 8 + (i >> 4);
    const int oh0 = (i & 15) * 4;          // covers oh0..oh0+3 (guard < 61)
    if (od >= Dout) return;
    const int lane = (int)threadIdx.x & 63, wave = (int)threadIdx.x >> 6;
    const int n16 = lane & 15, quad = lane >> 4;
    const int ow = wave * 16 + n16;

    f32x4 acc[4];
    #pragma unroll
    for (int j = 0; j < 4; ++j)
        #pragma unroll
        for (int r = 0; r < 4; ++r) {
            int co = quad * 4 + r;
            acc[j][r] = (co < 3) ? bias[co] : 0.0f;
        }

    const short* ap = Aw + (long)n16 * 4096 + quad * 8;   // m = lane&15
    const int kd0 = quad >> 1;
    const int kh0 = (quad & 1) * 2;
    const float* basez = d3 + ((long)(od + kd0) * D) * D + ow;
    int yoff[5];
    #pragma unroll
    for (int r = 0; r < 5; ++r) yoff[r] = min(oh0 + kh0 + r, D - 1) * D;

    #pragma unroll 4
    for (int s = 0; s < 128; ++s) {
        const int ci = s >> 1;
        const float* plane = basez + ((long)ci * D + (s & 1) * 2) * D * D;
        unsigned p0[5], p1[5];
        #pragma unroll
        for (int r = 0; r < 5; ++r) {
            f32x4u v = *(const f32x4u*)(plane + yoff[r]);
            p0[r] = (__float_as_uint(v[0]) >> 16) | (__float_as_uint(v[1]) & 0xffff0000u);
            p1[r] = (__float_as_uint(v[2]) >> 16) | (__float_as_uint(v[3]) & 0xffff0000u);
        }
        bf16x8 af = *(const bf16x8*)(ap + s * 32);
        #pragma unroll
        for (int j = 0; j < 4; ++j) {
            union { unsigned u[4]; bf16x8 b; } fr;
            fr.u[0] = p0[j];     fr.u[1] = p1[j];
            fr.u[2] = p0[j + 1]; fr.u[3] = p1[j + 1];
            acc[j] = __builtin_amdgcn_mfma_f32_16x16x32_bf16(af, fr.b, acc[j], 0, 0, 0);
        }
    }

    if (ow < Dout && quad == 0) {
        #pragma unroll
        for (int j = 0; j < 4; ++j) {
            const int oh = oh0 + j;
            if (oh >= Dout) continue;
            #pragma unroll
            for (int r = 0; r < 3; ++r)
                y[((long)(r * Dout + od) * Dout + oh) * Dout + ow] = tanhf(acc[j][r]);
        }
    }
}

extern "C" void kernel_launch(void* const* d_in, const int* in_sizes, int n_in,
                              void* d_out, int out_size, void* d_ws, size_t ws_size,
                              hipStream_t stream)
{
    const float* x        = (const float*)d_in[0];
    const float* enc_w1   = (const float*)d_in[1];
    const float* enc_b1   = (const float*)d_in[2];
    const float* enc_w2   = (const float*)d_in[3];
    const float* enc_b2   = (const float*)d_in[4];
    const float* enc_w3   = (const float*)d_in[5];
    const float* enc_b3   = (const float*)d_in[6];
    const float* enc_w4   = (const float*)d_in[7];
    const float* enc_b4   = (const float*)d_in[8];
    const float* codebook = (const float*)d_in[9];
    const float* dec_w1   = (const float*)d_in[10];
    const float* dec_b1   = (const float*)d_in[11];
    const float* dec_w2   = (const float*)d_in[12];
    const float* dec_b2   = (const float*)d_in[13];
    const float* dec_w3   = (const float*)d_in[14];
    const float* dec_b3   = (const float*)d_in[15];
    const float* dec_w4   = (const float*)d_in[16];
    const float* dec_b4   = (const float*)d_in[17];

    float* out = (float*)d_out;
    float* idx_out = out + 2L * 3 * 61 * 61 * 61;

    // ---- workspace (byte offsets) ----
    char* wsb = (char*)d_ws;
    float*          cn   = (float*)wsb;                        //      4,096
    unsigned short* qp   = (unsigned short*)(wsb + 4096);      //  1,024,000
    short*          Ap1  = (short*)(wsb + 1028096);            //  8,388,608
    short*          Ap2  = (short*)(wsb + 9416704);            //  4,194,304
    short*          Ap3  = (short*)(wsb + 13611008);           //  1,048,576
    short*          Aw4  = (short*)(wsb + 14659584);           //    131,072
    short*          W1hi = (short*)(wsb + 14790656);           //     24,576
    short*          W1lo = (short*)(wsb + 14815232);           //     24,576
    short*          W2hi = (short*)(wsb + 14839808);           //  1,048,576
    short*          W2lo = (short*)(wsb + 15888384);           //  1,048,576
    short*          W3hi = (short*)(wsb + 16936960);           //  4,194,304
    short*          W3lo = (short*)(wsb + 21131264);           //  4,194,304
    char* arena = wsb + 25325568;
    // encoder phase:
    unsigned short* xphi = (unsigned short*)arena;                    // (2,3,66,66,68)
    unsigned short* xplo = (unsigned short*)(arena + 3554496);
    unsigned short* h1hi = (unsigned short*)(arena + 7108992);        // (2,64,34,34,36)
    unsigned short* h1lo = (unsigned short*)(arena + 17762688);
    unsigned short* h2hi = (unsigned short*)(arena + 28416384);       // (2,128,18,18,20)
    unsigned short* h2lo = (unsigned short*)(arena + 31734144);
    float*          pp3  = (float*)(arena + 35051904);                // 4x(2,256,8^3)
    float*          h3   = (float*)(arena + 39246208);                // (2,256,512)
    float*          lat  = (float*)(arena + 40294784);                // (2,256,512)
    // decoder phase (after VQ; overlaps encoder buffers):
    unsigned short* d1 = (unsigned short*)arena;                      // (256,18^3) bf16
    unsigned short* d2 = (unsigned short*)(arena + 2985984);          // (128,34^3) bf16
    float*          d3 = (float*)(arena + 13047808);                  // (64,64^3) fp32
    // arena peak 80.2 MB; total 105.5 MB (< 112.2 MB proven in R0)

    dim3 blk(256);
    auto nblk = [](long n) { return dim3((unsigned)((n + 255) / 256)); };

    // ---- weight prep ----
    prep_convt_w<<<nblk(8L * 256 * 2048), blk, 0, stream>>>(dec_w1, Ap1, 256, 256);
    prep_convt_w<<<nblk(8L * 128 * 2048), blk, 0, stream>>>(dec_w2, Ap2, 256, 128);
    prep_convt_w<<<nblk(8L * 64 * 1024), blk, 0, stream>>>(dec_w3, Ap3, 128, 64);
    prep_dec4A<<<dim3(256), blk, 0, stream>>>(dec_w4, Aw4);
    prep_split_w<<<nblk(12288), blk, 0, stream>>>(enc_w1, W1hi, W1lo, 12288);
    prep_split_w<<<nblk(524288), blk, 0, stream>>>(enc_w2, W2hi, W2lo, 524288);
    prep_split_w<<<nblk(2097152), blk, 0, stream>>>(enc_w3, W3hi, W3lo, 2097152);

    // ---- encoder (MFMA, bf16-pair) ----
    pad_input_split<<<nblk(6L * 66 * 66 * 68), blk, 0, stream>>>(x, xphi, xplo);
    zero_halo_ps<<<nblk(128L * 34 * 34 * 36), blk, 0, stream>>>(h1hi, 128, 34, 36);
    zero_halo_ps<<<nblk(128L * 34 * 34 * 36), blk, 0, stream>>>(h1lo, 128, 34, 36);
    conv_s2_mfma<3, 64, 32, 66, 68, 4, 2, 0, 1, 1><<<dim3(1024), blk, 0, stream>>>(
        xphi, xplo, W1hi, W1lo, enc_b1, h1hi, h1lo, nullptr, 34, 36, 1, 0);
    zero_halo_ps<<<nblk(256L * 18 * 18 * 20), blk, 0, stream>>>(h2hi, 256, 18, 20);
    zero_halo_ps<<<nblk(256L * 18 * 18 * 20), blk, 0, stream>>>(h2lo, 256, 18, 20);
    conv_s2_mfma<64, 128, 16, 34, 36, 2, 1, 0, 1, 1><<<dim3(512), blk, 0, stream>>>(
        h1hi, h1lo, W2hi, W2lo, enc_b2, h2hi, h2lo, nullptr, 18, 20, 1, 0);
    conv_s2_mfma<128, 256, 8, 18, 20, 4, 1, 1, 4, 0><<<dim3(256), blk, 0, stream>>>(
        h2hi, h2lo, W3hi, W3lo, enc_b3, nullptr, nullptr, pp3, 8, 8, 0, 262144);
    combine4_relu<<<nblk(262144), blk, 0, stream>>>(pp3, h3, 262144, 262144);
    conv1x1_b<<<dim3(512), dim3(128), 0, stream>>>(h3, enc_w4, enc_b4, lat);

    // ---- VQ (fp32 exact) ----
    codenorm_kernel<<<dim3(1024), dim3(64), 0, stream>>>(codebook, cn);
    zero_halo_t<unsigned short><<<nblk(512L * 10 * 10 * 10), blk, 0, stream>>>(qp, 512, 10);
    vq_kernel<<<dim3(1024), blk, 0, stream>>>(lat, codebook, cn, qp, idx_out);

    // ---- decoder halos ----
    zero_halo_t<unsigned short><<<nblk(256L * 18 * 18 * 18), blk, 0, stream>>>(d1, 256, 18);
    zero_halo_t<unsigned short><<<nblk(128L * 34 * 34 * 34), blk, 0, stream>>>(d2, 128, 34);

    // ---- decoder (MFMA) per batch ----
    for (int b = 0; b < 2; ++b) {
        const unsigned short* qb = qp + (long)b * 256 * 1000;
        float* outb = out + (long)b * 3 * 226981;
        // dec1 (DIN=8, old layout): grid = 8*2*4*1*4 = 256
        convt_mfma<256, 256, 8, 1, unsigned short><<<dim3(256), blk, 0, stream>>>(
            qb, Ap1, dec_b1, d1);
        // dec2 (x16): grid = 8 * (2*2*2*1*4*2*2) = 1024
        convt_mfma_x16<256, 128, 16, 1, unsigned short><<<dim3(1024), blk, 0, stream>>>(
            d1, Ap2, dec_b2, d2);
        // dec3 (x16): grid = 8 * (2*2*1*2*8*2*4) = 4096
        convt_mfma_x16<128, 64, 32, 0, float><<<dim3(4096), blk, 0, stream>>>(
            d2, Ap3, dec_b3, d3);
        conv_dec4_mfma<<<dim3(8 * 8 * 16), blk, 0, stream>>>(d3, Aw4, dec_b4, outb);
    }
}

// Round 15
// 1579.266 us; speedup vs baseline: 1.5603x; 1.1389x over previous
//
#include <hip/hip_runtime.h>
#include <cfloat>
#include <cmath>

// ---------------------------------------------------------------------------
// Round 14: convt B-gather as aligned dwordx2 pairs.
// Per (z,y)-row the two x-taps {px,px+1} are extracted from ONE 4B-aligned
// u16x4 load at (mx&~1) via a 64-bit shift (o=(n16&1)+px in {0,1,2}); the
// A-table k-slot ax-mapping is flipped (kw=(1-px)+2*(1-ax)) so dword halves
// land in the right MFMA slots with no repacking. dec3 additionally pairs two
// mx-tiles per wave (A-load reuse): 12 VMEM / 8 MFMA (was 12/4).
// dec1 keeps the old cube kernel/table. Everything else = R14.
// ---------------------------------------------------------------------------

using f32x4  = __attribute__((ext_vector_type(4))) float;
using bf16x8 = __attribute__((ext_vector_type(8))) short;
typedef float f32x4u __attribute__((ext_vector_type(4), aligned(4)));
typedef unsigned short u16x4u __attribute__((ext_vector_type(4), aligned(4)));

__device__ __forceinline__ unsigned short f32_to_bf16(float f) {
    unsigned int u = __float_as_uint(f);
    u += 0x7fffu + ((u >> 16) & 1u);          // round-to-nearest-even
    return (unsigned short)(u >> 16);
}
__device__ __forceinline__ void split_bf16(float v, unsigned short& h, unsigned short& l) {
    h = f32_to_bf16(v);
    float hf = __uint_as_float((unsigned)h << 16);
    l = f32_to_bf16(v - hf);
}
__device__ __forceinline__ void store_act(float* p, float v) { *p = v; }
__device__ __forceinline__ void store_act(unsigned short* p, float v) { *p = f32_to_bf16(v); }

template <typename V>
__device__ __forceinline__ bf16x8 pack_b(V r0, V r1) {
    bf16x8 b;
    b[0] = (short)r0[0]; b[1] = (short)r0[1]; b[2] = (short)r0[2]; b[3] = (short)r0[3];
    b[4] = (short)r1[0]; b[5] = (short)r1[1]; b[6] = (short)r1[2]; b[7] = (short)r1[3];
    return b;
}

// ---------------- prep: weight hi/lo split ----------------
__global__ __launch_bounds__(256)
void prep_split_w(const float* __restrict__ w, short* __restrict__ whi,
                  short* __restrict__ wlo, long total)
{
    long idx = (long)blockIdx.x * blockDim.x + threadIdx.x;
    if (idx >= total) return;
    unsigned short h, l;
    split_bf16(w[idx], h, l);
    whi[idx] = (short)h; wlo[idx] = (short)l;
}

// ---------------- pad input -> hi/lo bf16 pitched planes --------------------
__global__ __launch_bounds__(256)
void pad_input_split(const float* __restrict__ x, unsigned short* __restrict__ xhi,
                     unsigned short* __restrict__ xlo)
{
    const int D = 64, PD = 66, PRX = 68, BC = 6;
    long total = (long)BC * PD * PD * PRX;
    long idx = (long)blockIdx.x * blockDim.x + threadIdx.x;
    if (idx >= total) return;
    int px = (int)(idx % PRX); long t = idx / PRX;
    int py = (int)(t % PD); t /= PD;
    int pz = (int)(t % PD); int c = (int)(t / PD);
    int ix = px - 1, iy = py - 1, iz = pz - 1;
    float v = 0.0f;
    if ((unsigned)ix < (unsigned)D && (unsigned)iy < (unsigned)D && (unsigned)iz < (unsigned)D)
        v = x[(((long)c * D + iz) * D + iy) * D + ix];
    unsigned short h, l;
    split_bf16(v, h, l);
    xhi[idx] = h; xlo[idx] = l;
}

__global__ __launch_bounds__(256)
void zero_halo_ps(unsigned short* __restrict__ p, int C, int PD, int PRX)
{
    long total = (long)C * PD * PD * PRX;
    long idx = (long)blockIdx.x * blockDim.x + threadIdx.x;
    if (idx >= total) return;
    int px = (int)(idx % PRX); long t = idx / PRX;
    int py = (int)(t % PD); t /= PD;
    int pz = (int)(t % PD);
    if (px == 0 || px >= PD - 1 || py == 0 || py == PD - 1 || pz == 0 || pz == PD - 1)
        p[idx] = 0;
}

template <typename T>
__global__ __launch_bounds__(256) void zero_halo_t(T* __restrict__ p, int C, int PD)
{
    long total = (long)C * PD * PD * PD;
    long idx = (long)blockIdx.x * blockDim.x + threadIdx.x;
    if (idx >= total) return;
    int px = (int)(idx % PD); long t = idx / PD;
    int py = (int)(t % PD); t /= PD;
    int pz = (int)(t % PD);
    if (px == 0 || px == PD - 1 || py == 0 || py == PD - 1 || pz == 0 || pz == PD - 1)
        p[idx] = (T)0;
}

// ---------------------------------------------------------------------------
// Conv3d k4 s2 p1 as MFMA implicit GEMM, bf16 hi/lo pair inputs (unchanged)
// ---------------------------------------------------------------------------
template <int CIN, int COUT, int DOUT, int PD, int PRX, int MTW, int OWT,
          int OWHALF, int KSPLIT, int OUTSPLIT>
__global__ __launch_bounds__(256)
void conv_s2_mfma(const unsigned short* __restrict__ xhi,
                  const unsigned short* __restrict__ xlo,
                  const short* __restrict__ Whi, const short* __restrict__ Wlo,
                  const float* __restrict__ bias,
                  unsigned short* __restrict__ yhi, unsigned short* __restrict__ ylo,
                  float* __restrict__ yf,
                  int OPD, int OPRX, int po, long sstride)
{
    constexpr int K = CIN * 64;
    constexpr int MWAVES = COUT / (16 * MTW);
    constexpr int RPB = 4 / MWAVES;
    constexpr int KN = (CIN * 2) / KSPLIT;

    int bx = blockIdx.x;
    const int ks = (KSPLIT > 1) ? (bx % KSPLIT) : 0;
    const int rowblk = (KSPLIT > 1) ? (bx / KSPLIT) : bx;
    const int lane = (int)threadIdx.x & 63, w = (int)threadIdx.x >> 6;
    const int mi = (MWAVES == 4) ? w : 0;
    const int ri = (MWAVES == 4) ? 0 : w;
    const int rowid = rowblk * RPB + ri;
    const int n16 = lane & 15, quad = lane >> 4;

    int b, od, oh, ow;
    if (OWHALF) {
        constexpr int NOH = DOUT / 2;
        const int ohb = rowid % NOH; int t = rowid / NOH;
        od = t % DOUT; b = t / DOUT;
        oh = ohb * 2 + (n16 >> 3);
        ow = n16 & 7;
    } else {
        const int owt = rowid % OWT; int t = rowid / OWT;
        oh = t % DOUT; t /= DOUT;
        od = t % DOUT; b = t / DOUT;
        ow = owt * 16 + n16;
    }

    const int co0 = mi * (MTW * 16);

    f32x4 acc[MTW];
    #pragma unroll
    for (int mt = 0; mt < MTW; ++mt)
        #pragma unroll
        for (int r = 0; r < 4; ++r) {
            int co = co0 + mt * 16 + quad * 4 + r;
            acc[mt][r] = (ks == 0) ? bias[co] : 0.0f;
        }

    const int sg0 = ks * KN;
    const long chs = (long)PD * PD * PRX;
    long off = ((long)(b * CIN + (sg0 >> 1)) * PD + (2 * od + (quad >> 1))) * PD * PRX
             + (long)(2 * oh + (quad & 1) * 2) * PRX + 2 * ow;
    const unsigned short* phi = xhi + off;
    const unsigned short* plo = xlo + off;
    const long incA = 2L * PD * PRX;
    const long incB = chs - 2L * PD * PRX;

    const short* a0h = Whi + (long)(co0 + n16) * K + sg0 * 32 + quad * 8;
    const short* a0l = Wlo + (long)(co0 + n16) * K + sg0 * 32 + quad * 8;

    #pragma unroll 2
    for (int s = 0; s < KN; ++s) {
        u16x4u h0 = *(const u16x4u*)phi;
        u16x4u h1 = *(const u16x4u*)(phi + PRX);
        u16x4u l0 = *(const u16x4u*)plo;
        u16x4u l1 = *(const u16x4u*)(plo + PRX);
        bf16x8 bhi = pack_b(h0, h1);
        bf16x8 blo = pack_b(l0, l1);
        #pragma unroll
        for (int mt = 0; mt < MTW; ++mt) {
            bf16x8 ah = *(const bf16x8*)(a0h + (long)mt * 16 * K + s * 32);
            bf16x8 al = *(const bf16x8*)(a0l + (long)mt * 16 * K + s * 32);
            acc[mt] = __builtin_amdgcn_mfma_f32_16x16x32_bf16(ah, bhi, acc[mt], 0, 0, 0);
            acc[mt] = __builtin_amdgcn_mfma_f32_16x16x32_bf16(ah, blo, acc[mt], 0, 0, 0);
            acc[mt] = __builtin_amdgcn_mfma_f32_16x16x32_bf16(al, bhi, acc[mt], 0, 0, 0);
        }
        long inc = (s & 1) ? incB : incA;
        phi += inc; plo += inc;
    }

    if (OUTSPLIT) {
        #pragma unroll
        for (int mt = 0; mt < MTW; ++mt)
            #pragma unroll
            for (int r = 0; r < 4; ++r) {
                int co = co0 + mt * 16 + quad * 4 + r;
                float v = fmaxf(acc[mt][r], 0.0f);
                unsigned short h, l;
                split_bf16(v, h, l);
                long o = (((long)(b * COUT + co) * OPD + od + po) * OPD + oh + po) * OPRX
                       + ow + po;
                yhi[o] = h; ylo[o] = l;
            }
    } else {
        #pragma unroll
        for (int mt = 0; mt < MTW; ++mt)
            #pragma unroll
            for (int r = 0; r < 4; ++r) {
                int co = co0 + mt * 16 + quad * 4 + r;
                long o = (long)ks * sstride
                       + (((long)(b * COUT + co) * OPD + od) * OPD + oh) * OPRX + ow;
                yf[o] = acc[mt][r];
            }
    }
}

__global__ __launch_bounds__(256)
void combine4_relu(const float* __restrict__ p, float* __restrict__ y, long N, long ss)
{
    long idx = (long)blockIdx.x * blockDim.x + threadIdx.x;
    if (idx >= N) return;
    float v = p[idx] + p[idx + ss] + p[idx + 2 * ss] + p[idx + 3 * ss];
    y[idx] = fmaxf(v, 0.0f);
}

// ---------------- 1x1 conv (fp32 exact) ----------------
__global__ __launch_bounds__(128)
void conv1x1_b(const float* __restrict__ x, const float* __restrict__ w,
               const float* __restrict__ bias, float* __restrict__ y)
{
    const int co = blockIdx.x & 255, b = blockIdx.x >> 8;
    const int s4 = (int)threadIdx.x * 4;
    const float* xb = x + (long)b * 256 * 512 + s4;
    const float* wr = w + (long)co * 256;      // uniform -> s_load
    float bv = bias[co];
    float4 acc = {bv, bv, bv, bv};
    for (int ci = 0; ci < 256; ++ci) {
        float wv = wr[ci];
        float4 xv = *(const float4*)(xb + (long)ci * 512);
        acc.x = fmaf(xv.x, wv, acc.x); acc.y = fmaf(xv.y, wv, acc.y);
        acc.z = fmaf(xv.z, wv, acc.z); acc.w = fmaf(xv.w, wv, acc.w);
    }
    *(float4*)(y + (long)(b * 256 + co) * 512 + s4) = acc;
}

// ---------------- VQ (fp32 exact; unchanged) ----------------
__global__ void codenorm_kernel(const float* __restrict__ cb, float* __restrict__ norms)
{
    int k = blockIdx.x;
    int lane = threadIdx.x;
    float s = 0.0f;
    const float* row = cb + (long)k * 256;
    for (int d = lane; d < 256; d += 64) { float v = row[d]; s = fmaf(v, v, s); }
    for (int off = 32; off > 0; off >>= 1) s += __shfl_down(s, off);
    if (lane == 0) norms[k] = s;
}

__global__ __launch_bounds__(256)
void vq_kernel(const float* __restrict__ lat, const float* __restrict__ cb,
               const float* __restrict__ norms, unsigned short* __restrict__ q,
               float* __restrict__ idx_out)
{
    __shared__ __align__(16) float row[256];
    __shared__ float s_best[256];
    __shared__ int   s_bidx[256];
    int r = blockIdx.x;
    int t = threadIdx.x;
    row[t] = lat[(long)r * 256 + t];
    __syncthreads();

    const float4* rowv = (const float4*)row;
    float latn = 0.0f;
    #pragma unroll 4
    for (int d = 0; d < 64; ++d) {
        float4 rv = rowv[d];
        latn = fmaf(rv.x, rv.x, latn); latn = fmaf(rv.y, rv.y, latn);
        latn = fmaf(rv.z, rv.z, latn); latn = fmaf(rv.w, rv.w, latn);
    }

    float best = FLT_MAX;
    int bidx = 0x7fffffff;
    for (int j = 0; j < 4; ++j) {
        int k = t + 256 * j;
        const float4* cr = (const float4*)(cb + (long)k * 256);
        float dot = 0.0f;
        #pragma unroll 4
        for (int d = 0; d < 64; ++d) {
            float4 c = cr[d]; float4 rv = rowv[d];
            dot = fmaf(rv.x, c.x, dot); dot = fmaf(rv.y, c.y, dot);
            dot = fmaf(rv.z, c.z, dot); dot = fmaf(rv.w, c.w, dot);
        }
        float sc = latn - 2.0f * dot + norms[k];
        if (sc < best || (sc == best && k < bidx)) { best = sc; bidx = k; }
    }
    s_best[t] = best; s_bidx[t] = bidx;
    __syncthreads();
    for (int off = 128; off > 0; off >>= 1) {
        if (t < off) {
            float o = s_best[t + off]; int oi = s_bidx[t + off];
            if (o < s_best[t] || (o == s_best[t] && oi < s_bidx[t])) {
                s_best[t] = o; s_bidx[t] = oi;
            }
        }
        __syncthreads();
    }
    int bk = s_bidx[0];
    int b = r >> 9, n = r & 511;
    int zz = n >> 6, yy = (n >> 3) & 7, xx = n & 7;
    q[(long)(b * 256 + t) * 1000 + ((long)(zz + 1) * 10 + (yy + 1)) * 10 + (xx + 1)]
        = f32_to_bf16(cb[(long)bk * 256 + t]);
    if (t == 0) idx_out[r] = (float)bk;
}

// ---------------- decoder: MFMA implicit-GEMM ConvTranspose ----------------
// xflip=0: B slot a <-> x offset (1-ax), kw=(1-px)+2*ax (old cube kernel).
// xflip=1: B slot a <-> x offset ax,     kw=(1-px)+2*(1-ax) (dword-pair kernel).
__global__ __launch_bounds__(256)
void prep_convt_w(const float* __restrict__ w, short* __restrict__ Ap,
                  int Cin, int Cout, int xflip)
{
    const int K = Cin * 8;
    long total = 8L * Cout * K;
    long idx = (long)blockIdx.x * blockDim.x + threadIdx.x;
    if (idx >= total) return;
    int k = (int)(idx % K);
    int co = (int)((idx / K) % Cout);
    int p = (int)(idx / ((long)K * Cout));
    int ci = k >> 3, a = k & 7;
    int az = (a >> 2) & 1, ay = (a >> 1) & 1, ax = a & 1;
    int pz = p >> 2, py = (p >> 1) & 1, px = p & 1;
    int axw = xflip ? (1 - ax) : ax;
    int kd = (1 - pz) + 2 * az, kh = (1 - py) + 2 * ay, kw = (1 - px) + 2 * axw;
    float v = w[((long)ci * Cout + co) * 64 + kd * 16 + kh * 4 + kw];
    Ap[idx] = (short)f32_to_bf16(v);
}

// Old cube-N layout (kept for dec1, DIN=8): nt-slab XCD swizzle + px inner.
template <int CIN, int COUT, int DIN, int OPAD, typename OutT>
__global__ __launch_bounds__(256)
void convt_mfma(const unsigned short* __restrict__ Xp, const short* __restrict__ Ap,
                const float* __restrict__ bias, OutT* __restrict__ Y)
{
    constexpr int PD = DIN + 2;
    constexpr int PD3 = PD * PD * PD;
    constexpr int T = DIN >> 2;
    constexpr int NT = T * T * T;
    constexpr int SLAB = NT / 8;
    constexpr int OPD = 2 * DIN + 2 * OPAD;
    constexpr int K = CIN * 8;
    constexpr int MG = COUT >> 6;
    constexpr int nsteps = K >> 5;

    int bx = blockIdx.x;
    const int xcd = bx & 7;
    int local = bx >> 3;
    const int px = local & 1; local >>= 1;
    const int mg = local % MG; local /= MG;
    const int ntin = local % SLAB;
    const int pzy = local / SLAB;            // 0..3
    const int pz = pzy >> 1, py = pzy & 1;
    const int p = pz * 4 + py * 2 + px;
    const int nt = xcd * SLAB + ntin;

    const int lane = threadIdx.x & 63, wave = threadIdx.x >> 6;
    const int n16 = lane & 15, quad = lane >> 4;

    const int tx = nt % T, ty = (nt / T) % T, tz = nt / (T * T);
    const int mz = tz * 4 + wave, my = ty * 4 + (n16 >> 2), mx = tx * 4 + (n16 & 3);
    const int sp = ((mz + pz) * PD + (my + py)) * PD + (mx + px);

    const unsigned short* xq = Xp + (long)quad * PD3 + sp;

    const int cobase = mg * 64;
    const short* ap0 = Ap + ((long)p * COUT + cobase + n16) * K + quad * 8;

    f32x4 acc[4];
    #pragma unroll
    for (int cb = 0; cb < 4; ++cb) {
        const float* bp = bias + cobase + cb * 16 + quad * 4;
        acc[cb][0] = bp[0]; acc[cb][1] = bp[1]; acc[cb][2] = bp[2]; acc[cb][3] = bp[3];
    }

    #pragma unroll 4
    for (int s = 0; s < nsteps; ++s) {
        const unsigned short* xs = xq + (long)s * 4 * PD3;
        bf16x8 bf;
        bf[0] = (short)xs[(PD + 1) * PD + 1];
        bf[1] = (short)xs[(PD + 1) * PD];
        bf[2] = (short)xs[PD * PD + 1];
        bf[3] = (short)xs[PD * PD];
        bf[4] = (short)xs[PD + 1];
        bf[5] = (short)xs[PD];
        bf[6] = (short)xs[1];
        bf[7] = (short)xs[0];
        #pragma unroll
        for (int cb = 0; cb < 4; ++cb) {
            bf16x8 af = *(const bf16x8*)(ap0 + (long)cb * 16 * K + s * 32);
            acc[cb] = __builtin_amdgcn_mfma_f32_16x16x32_bf16(af, bf, acc[cb], 0, 0, 0);
        }
    }

    const int opz = 2 * mz + pz + OPAD, opy = 2 * my + py + OPAD, opx = 2 * mx + px + OPAD;
    const long spo = ((long)opz * OPD + opy) * OPD + opx;
    #pragma unroll
    for (int cb = 0; cb < 4; ++cb) {
        #pragma unroll
        for (int r = 0; r < 4; ++r) {
            int co = cobase + cb * 16 + quad * 4 + r;
            float v = fmaxf(acc[cb][r], 0.0f);
            store_act(Y + (long)co * OPD * OPD * OPD + spo, v);
        }
    }
}

// Dword-pair B-gather (dec2/dec3): per (z,y)-row ONE aligned u16x4 load at
// (mx&~1); the lane's x-tap pair {px,px+1} is (u64 >> 16*o), o=(n16&1)+px.
// Uses the xflip=1 A-table. MXP mx-tiles share each A-load.
template <int CIN, int COUT, int DIN, int OPAD, int MXP, typename OutT>
__global__ __launch_bounds__(256)
void convt_mfma_v2(const unsigned short* __restrict__ Xp, const short* __restrict__ Ap,
                   const float* __restrict__ bias, OutT* __restrict__ Y)
{
    constexpr int PD = DIN + 2;
    constexpr int PD3 = PD * PD * PD;
    constexpr int OPD = 2 * DIN + 2 * OPAD;
    constexpr int K = CIN * 8;
    constexpr int MG = COUT >> 6;
    constexpr int nsteps = K >> 5;
    constexpr int MXT = DIN / (16 * MXP);
    constexpr int MYT = DIN / 4;
    constexpr int MZS = DIN / 8;             // mz per XCD slab

    int bx = blockIdx.x;
    const int xcd = bx & 7;
    int local = bx >> 3;
    const int px = local & 1; local >>= 1;
    const int py = local & 1; local >>= 1;
    const int mg = local % MG; local /= MG;
    const int mxt = local % MXT; local /= MXT;
    const int myt = local % MYT; local /= MYT;
    const int pz = local & 1; local >>= 1;
    const int mzin = local;                  // 0..MZS-1
    const int mz = xcd * MZS + mzin;
    const int p = pz * 4 + py * 2 + px;

    const int lane = threadIdx.x & 63, wave = threadIdx.x >> 6;
    const int n16 = lane & 15, quad = lane >> 4;

    const int mx0 = mxt * (16 * MXP) + n16;
    const int my = myt * 4 + wave;
    const int baseX = mx0 & ~1;
    const int sh = 16 * ((n16 & 1) + px);    // 0, 16, or 32
    const long sp = ((long)(mz + pz) * PD + (my + py)) * PD + baseX;

    const unsigned short* xq = Xp + (long)quad * PD3 + sp;

    const int cobase = mg * 64;
    const short* ap0 = Ap + ((long)p * COUT + cobase + n16) * K + quad * 8;

    f32x4 acc[MXP][4];
    #pragma unroll
    for (int t = 0; t < MXP; ++t)
        #pragma unroll
        for (int cb = 0; cb < 4; ++cb) {
            const float* bp = bias + cobase + cb * 16 + quad * 4;
            acc[t][cb][0] = bp[0]; acc[t][cb][1] = bp[1];
            acc[t][cb][2] = bp[2]; acc[t][cb][3] = bp[3];
        }

    constexpr int rowoff[4] = { (PD + 1) * PD, PD * PD, PD, 0 };

    #pragma unroll 2
    for (int s = 0; s < nsteps; ++s) {
        const unsigned short* xs = xq + (long)s * 4 * PD3;
        union Frag { unsigned u[4]; bf16x8 b; } fr[MXP];
        #pragma unroll
        for (int t = 0; t < MXP; ++t) {
            #pragma unroll
            for (int j = 0; j < 4; ++j) {
                union { u16x4u v; unsigned long long u64; } ld;
                ld.v = *(const u16x4u*)(xs + t * 16 + rowoff[j]);
                fr[t].u[j] = (unsigned)(ld.u64 >> sh);
            }
        }
        #pragma unroll
        for (int cb = 0; cb < 4; ++cb) {
            bf16x8 af = *(const bf16x8*)(ap0 + (long)cb * 16 * K + s * 32);
            #pragma unroll
            for (int t = 0; t < MXP; ++t)
                acc[t][cb] = __builtin_amdgcn_mfma_f32_16x16x32_bf16(af, fr[t].b,
                                                                     acc[t][cb], 0, 0, 0);
        }
    }

    const int opz = 2 * mz + pz + OPAD, opy = 2 * my + py + OPAD;
    #pragma unroll
    for (int t = 0; t < MXP; ++t) {
        const int opx = 2 * (mx0 + t * 16) + px + OPAD;
        const long spo = ((long)opz * OPD + opy) * OPD + opx;
        #pragma unroll
        for (int cb = 0; cb < 4; ++cb) {
            #pragma unroll
            for (int r = 0; r < 4; ++r) {
                int co = cobase + cb * 16 + quad * 4 + r;
                float v = fmaxf(acc[t][cb][r], 0.0f);
                store_act(Y + (long)co * OPD * OPD * OPD + spo, v);
            }
        }
    }
}

// ---------------- dec4 as MFMA GEMM: 4 oh rows per wave (unchanged) ---------
__global__ __launch_bounds__(256)
void prep_dec4A(const float* __restrict__ w, short* __restrict__ Aw)
{
    int idx = blockIdx.x * 256 + (int)threadIdx.x;    // 0..65535
    int m = idx >> 12, k = idx & 4095;
    float v = (m < 3) ? w[m * 4096 + k] : 0.0f;
    Aw[idx] = (short)f32_to_bf16(v);
}

__global__ __launch_bounds__(256)
void conv_dec4_mfma(const float* __restrict__ d3, const short* __restrict__ Aw,
                    const float* __restrict__ bias, float* __restrict__ y)
{
    constexpr int D = 64, Dout = 61;
    int bx = blockIdx.x;
    const int slab = bx & 7;
    const int i = bx >> 3;                 // 0..127
    const int od = slab * 8 + (i >> 4);
    const int oh0 = (i & 15) * 4;          // covers oh0..oh0+3 (guard < 61)
    if (od >= Dout) return;
    const int lane = (int)threadIdx.x & 63, wave = (int)threadIdx.x >> 6;
    const int n16 = lane & 15, quad = lane >> 4;
    const int ow = wave * 16 + n16;

    f32x4 acc[4];
    #pragma unroll
    for (int j = 0; j < 4; ++j)
        #pragma unroll
        for (int r = 0; r < 4; ++r) {
            int co = quad * 4 + r;
            acc[j][r] = (co < 3) ? bias[co] : 0.0f;
        }

    const short* ap = Aw + (long)n16 * 4096 + quad * 8;   // m = lane&15
    const int kd0 = quad >> 1;
    const int kh0 = (quad & 1) * 2;
    const float* basez = d3 + ((long)(od + kd0) * D) * D + ow;
    int yoff[5];
    #pragma unroll
    for (int r = 0; r < 5; ++r) yoff[r] = min(oh0 + kh0 + r, D - 1) * D;

    #pragma unroll 4
    for (int s = 0; s < 128; ++s) {
        const int ci = s >> 1;
        const float* plane = basez + ((long)ci * D + (s & 1) * 2) * D * D;
        unsigned p0[5], p1[5];
        #pragma unroll
        for (int r = 0; r < 5; ++r) {
            f32x4u v = *(const f32x4u*)(plane + yoff[r]);
            p0[r] = (__float_as_uint(v[0]) >> 16) | (__float_as_uint(v[1]) & 0xffff0000u);
            p1[r] = (__float_as_uint(v[2]) >> 16) | (__float_as_uint(v[3]) & 0xffff0000u);
        }
        bf16x8 af = *(const bf16x8*)(ap + s * 32);
        #pragma unroll
        for (int j = 0; j < 4; ++j) {
            union { unsigned u[4]; bf16x8 b; } fr;
            fr.u[0] = p0[j];     fr.u[1] = p1[j];
            fr.u[2] = p0[j + 1]; fr.u[3] = p1[j + 1];
            acc[j] = __builtin_amdgcn_mfma_f32_16x16x32_bf16(af, fr.b, acc[j], 0, 0, 0);
        }
    }

    if (ow < Dout && quad == 0) {
        #pragma unroll
        for (int j = 0; j < 4; ++j) {
            const int oh = oh0 + j;
            if (oh >= Dout) continue;
            #pragma unroll
            for (int r = 0; r < 3; ++r)
                y[((long)(r * Dout + od) * Dout + oh) * Dout + ow] = tanhf(acc[j][r]);
        }
    }
}

extern "C" void kernel_launch(void* const* d_in, const int* in_sizes, int n_in,
                              void* d_out, int out_size, void* d_ws, size_t ws_size,
                              hipStream_t stream)
{
    const float* x        = (const float*)d_in[0];
    const float* enc_w1   = (const float*)d_in[1];
    const float* enc_b1   = (const float*)d_in[2];
    const float* enc_w2   = (const float*)d_in[3];
    const float* enc_b2   = (const float*)d_in[4];
    const float* enc_w3   = (const float*)d_in[5];
    const float* enc_b3   = (const float*)d_in[6];
    const float* enc_w4   = (const float*)d_in[7];
    const float* enc_b4   = (const float*)d_in[8];
    const float* codebook = (const float*)d_in[9];
    const float* dec_w1   = (const float*)d_in[10];
    const float* dec_b1   = (const float*)d_in[11];
    const float* dec_w2   = (const float*)d_in[12];
    const float* dec_b2   = (const float*)d_in[13];
    const float* dec_w3   = (const float*)d_in[14];
    const float* dec_b3   = (const float*)d_in[15];
    const float* dec_w4   = (const float*)d_in[16];
    const float* dec_b4   = (const float*)d_in[17];

    float* out = (float*)d_out;
    float* idx_out = out + 2L * 3 * 61 * 61 * 61;

    // ---- workspace (byte offsets) ----
    char* wsb = (char*)d_ws;
    float*          cn   = (float*)wsb;                        //      4,096
    unsigned short* qp   = (unsigned short*)(wsb + 4096);      //  1,024,000
    short*          Ap1  = (short*)(wsb + 1028096);            //  8,388,608
    short*          Ap2  = (short*)(wsb + 9416704);            //  4,194,304
    short*          Ap3  = (short*)(wsb + 13611008);           //  1,048,576
    short*          Aw4  = (short*)(wsb + 14659584);           //    131,072
    short*          W1hi = (short*)(wsb + 14790656);           //     24,576
    short*          W1lo = (short*)(wsb + 14815232);           //     24,576
    short*          W2hi = (short*)(wsb + 14839808);           //  1,048,576
    short*          W2lo = (short*)(wsb + 15888384);           //  1,048,576
    short*          W3hi = (short*)(wsb + 16936960);           //  4,194,304
    short*          W3lo = (short*)(wsb + 21131264);           //  4,194,304
    char* arena = wsb + 25325568;
    // encoder phase:
    unsigned short* xphi = (unsigned short*)arena;                    // (2,3,66,66,68)
    unsigned short* xplo = (unsigned short*)(arena + 3554496);
    unsigned short* h1hi = (unsigned short*)(arena + 7108992);        // (2,64,34,34,36)
    unsigned short* h1lo = (unsigned short*)(arena + 17762688);
    unsigned short* h2hi = (unsigned short*)(arena + 28416384);       // (2,128,18,18,20)
    unsigned short* h2lo = (unsigned short*)(arena + 31734144);
    float*          pp3  = (float*)(arena + 35051904);                // 4x(2,256,8^3)
    float*          h3   = (float*)(arena + 39246208);                // (2,256,512)
    float*          lat  = (float*)(arena + 40294784);                // (2,256,512)
    // decoder phase (after VQ; overlaps encoder buffers):
    unsigned short* d1 = (unsigned short*)arena;                      // (256,18^3) bf16
    unsigned short* d2 = (unsigned short*)(arena + 2985984);          // (128,34^3) bf16
    float*          d3 = (float*)(arena + 13047808);                  // (64,64^3) fp32
    // arena peak 80.2 MB; total 105.5 MB (< 112.2 MB proven in R0)

    dim3 blk(256);
    auto nblk = [](long n) { return dim3((unsigned)((n + 255) / 256)); };

    // ---- weight prep ----
    prep_convt_w<<<nblk(8L * 256 * 2048), blk, 0, stream>>>(dec_w1, Ap1, 256, 256, 0);
    prep_convt_w<<<nblk(8L * 128 * 2048), blk, 0, stream>>>(dec_w2, Ap2, 256, 128, 1);
    prep_convt_w<<<nblk(8L * 64 * 1024), blk, 0, stream>>>(dec_w3, Ap3, 128, 64, 1);
    prep_dec4A<<<dim3(256), blk, 0, stream>>>(dec_w4, Aw4);
    prep_split_w<<<nblk(12288), blk, 0, stream>>>(enc_w1, W1hi, W1lo, 12288);
    prep_split_w<<<nblk(524288), blk, 0, stream>>>(enc_w2, W2hi, W2lo, 524288);
    prep_split_w<<<nblk(2097152), blk, 0, stream>>>(enc_w3, W3hi, W3lo, 2097152);

    // ---- encoder (MFMA, bf16-pair) ----
    pad_input_split<<<nblk(6L * 66 * 66 * 68), blk, 0, stream>>>(x, xphi, xplo);
    zero_halo_ps<<<nblk(128L * 34 * 34 * 36), blk, 0, stream>>>(h1hi, 128, 34, 36);
    zero_halo_ps<<<nblk(128L * 34 * 34 * 36), blk, 0, stream>>>(h1lo, 128, 34, 36);
    conv_s2_mfma<3, 64, 32, 66, 68, 4, 2, 0, 1, 1><<<dim3(1024), blk, 0, stream>>>(
        xphi, xplo, W1hi, W1lo, enc_b1, h1hi, h1lo, nullptr, 34, 36, 1, 0);
    zero_halo_ps<<<nblk(256L * 18 * 18 * 20), blk, 0, stream>>>(h2hi, 256, 18, 20);
    zero_halo_ps<<<nblk(256L * 18 * 18 * 20), blk, 0, stream>>>(h2lo, 256, 18, 20);
    conv_s2_mfma<64, 128, 16, 34, 36, 2, 1, 0, 1, 1><<<dim3(512), blk, 0, stream>>>(
        h1hi, h1lo, W2hi, W2lo, enc_b2, h2hi, h2lo, nullptr, 18, 20, 1, 0);
    conv_s2_mfma<128, 256, 8, 18, 20, 4, 1, 1, 4, 0><<<dim3(256), blk, 0, stream>>>(
        h2hi, h2lo, W3hi, W3lo, enc_b3, nullptr, nullptr, pp3, 8, 8, 0, 262144);
    combine4_relu<<<nblk(262144), blk, 0, stream>>>(pp3, h3, 262144, 262144);
    conv1x1_b<<<dim3(512), dim3(128), 0, stream>>>(h3, enc_w4, enc_b4, lat);

    // ---- VQ (fp32 exact) ----
    codenorm_kernel<<<dim3(1024), dim3(64), 0, stream>>>(codebook, cn);
    zero_halo_t<unsigned short><<<nblk(512L * 10 * 10 * 10), blk, 0, stream>>>(qp, 512, 10);
    vq_kernel<<<dim3(1024), blk, 0, stream>>>(lat, codebook, cn, qp, idx_out);

    // ---- decoder halos ----
    zero_halo_t<unsigned short><<<nblk(256L * 18 * 18 * 18), blk, 0, stream>>>(d1, 256, 18);
    zero_halo_t<unsigned short><<<nblk(128L * 34 * 34 * 34), blk, 0, stream>>>(d2, 128, 34);

    // ---- decoder (MFMA) per batch ----
    for (int b = 0; b < 2; ++b) {
        const unsigned short* qb = qp + (long)b * 256 * 1000;
        float* outb = out + (long)b * 3 * 226981;
        // dec1 (DIN=8, old layout): grid = 8*2*4*1*4 = 256
        convt_mfma<256, 256, 8, 1, unsigned short><<<dim3(256), blk, 0, stream>>>(
            qb, Ap1, dec_b1, d1);
        // dec2 (v2, MXP=1): grid = 8 * (2*2*2*1*4*2*2) = 1024
        convt_mfma_v2<256, 128, 16, 1, 1, unsigned short><<<dim3(1024), blk, 0, stream>>>(
            d1, Ap2, dec_b2, d2);
        // dec3 (v2, MXP=2): grid = 8 * (2*2*1*1*8*2*4) = 2048
        convt_mfma_v2<128, 64, 32, 0, 2, float><<<dim3(2048), blk, 0, stream>>>(
            d2, Ap3, dec_b3, d3);
        conv_dec4_mfma<<<dim3(8 * 8 * 16), blk, 0, stream>>>(d3, Aw4, dec_b4, outb);
    }
}

// Round 16
// 1517.158 us; speedup vs baseline: 1.6241x; 1.0409x over previous
//
#include <hip/hip_runtime.h>
#include <cfloat>
#include <cmath>

// ---------------------------------------------------------------------------
// Round 15: deepen the v2 convt pipeline.
// (1) K-loop unroll 2 -> 4 (R15's VGPR=64 showed only one step's loads in
//     flight; R12 proved unroll-4 pipelining on this loop shape).
// (2) v2 gains MYP (my-pairing): dec2 = MXP1/MYP2 -> A-loads amortized over
//     8 MFMAs (was 4), grid 512. dec3 keeps MXP2. Scheduling-only change;
//     per-output K-order untouched => bit-identical output.
// Everything else unchanged from R15.
// ---------------------------------------------------------------------------

using f32x4  = __attribute__((ext_vector_type(4))) float;
using bf16x8 = __attribute__((ext_vector_type(8))) short;
typedef float f32x4u __attribute__((ext_vector_type(4), aligned(4)));
typedef unsigned short u16x4u __attribute__((ext_vector_type(4), aligned(4)));

__device__ __forceinline__ unsigned short f32_to_bf16(float f) {
    unsigned int u = __float_as_uint(f);
    u += 0x7fffu + ((u >> 16) & 1u);          // round-to-nearest-even
    return (unsigned short)(u >> 16);
}
__device__ __forceinline__ void split_bf16(float v, unsigned short& h, unsigned short& l) {
    h = f32_to_bf16(v);
    float hf = __uint_as_float((unsigned)h << 16);
    l = f32_to_bf16(v - hf);
}
__device__ __forceinline__ void store_act(float* p, float v) { *p = v; }
__device__ __forceinline__ void store_act(unsigned short* p, float v) { *p = f32_to_bf16(v); }

template <typename V>
__device__ __forceinline__ bf16x8 pack_b(V r0, V r1) {
    bf16x8 b;
    b[0] = (short)r0[0]; b[1] = (short)r0[1]; b[2] = (short)r0[2]; b[3] = (short)r0[3];
    b[4] = (short)r1[0]; b[5] = (short)r1[1]; b[6] = (short)r1[2]; b[7] = (short)r1[3];
    return b;
}

// ---------------- prep: weight hi/lo split ----------------
__global__ __launch_bounds__(256)
void prep_split_w(const float* __restrict__ w, short* __restrict__ whi,
                  short* __restrict__ wlo, long total)
{
    long idx = (long)blockIdx.x * blockDim.x + threadIdx.x;
    if (idx >= total) return;
    unsigned short h, l;
    split_bf16(w[idx], h, l);
    whi[idx] = (short)h; wlo[idx] = (short)l;
}

// ---------------- pad input -> hi/lo bf16 pitched planes --------------------
__global__ __launch_bounds__(256)
void pad_input_split(const float* __restrict__ x, unsigned short* __restrict__ xhi,
                     unsigned short* __restrict__ xlo)
{
    const int D = 64, PD = 66, PRX = 68, BC = 6;
    long total = (long)BC * PD * PD * PRX;
    long idx = (long)blockIdx.x * blockDim.x + threadIdx.x;
    if (idx >= total) return;
    int px = (int)(idx % PRX); long t = idx / PRX;
    int py = (int)(t % PD); t /= PD;
    int pz = (int)(t % PD); int c = (int)(t / PD);
    int ix = px - 1, iy = py - 1, iz = pz - 1;
    float v = 0.0f;
    if ((unsigned)ix < (unsigned)D && (unsigned)iy < (unsigned)D && (unsigned)iz < (unsigned)D)
        v = x[(((long)c * D + iz) * D + iy) * D + ix];
    unsigned short h, l;
    split_bf16(v, h, l);
    xhi[idx] = h; xlo[idx] = l;
}

__global__ __launch_bounds__(256)
void zero_halo_ps(unsigned short* __restrict__ p, int C, int PD, int PRX)
{
    long total = (long)C * PD * PD * PRX;
    long idx = (long)blockIdx.x * blockDim.x + threadIdx.x;
    if (idx >= total) return;
    int px = (int)(idx % PRX); long t = idx / PRX;
    int py = (int)(t % PD); t /= PD;
    int pz = (int)(t % PD);
    if (px == 0 || px >= PD - 1 || py == 0 || py == PD - 1 || pz == 0 || pz == PD - 1)
        p[idx] = 0;
}

template <typename T>
__global__ __launch_bounds__(256) void zero_halo_t(T* __restrict__ p, int C, int PD)
{
    long total = (long)C * PD * PD * PD;
    long idx = (long)blockIdx.x * blockDim.x + threadIdx.x;
    if (idx >= total) return;
    int px = (int)(idx % PD); long t = idx / PD;
    int py = (int)(t % PD); t /= PD;
    int pz = (int)(t % PD);
    if (px == 0 || px == PD - 1 || py == 0 || py == PD - 1 || pz == 0 || pz == PD - 1)
        p[idx] = (T)0;
}

// ---------------------------------------------------------------------------
// Conv3d k4 s2 p1 as MFMA implicit GEMM, bf16 hi/lo pair inputs (unchanged)
// ---------------------------------------------------------------------------
template <int CIN, int COUT, int DOUT, int PD, int PRX, int MTW, int OWT,
          int OWHALF, int KSPLIT, int OUTSPLIT>
__global__ __launch_bounds__(256)
void conv_s2_mfma(const unsigned short* __restrict__ xhi,
                  const unsigned short* __restrict__ xlo,
                  const short* __restrict__ Whi, const short* __restrict__ Wlo,
                  const float* __restrict__ bias,
                  unsigned short* __restrict__ yhi, unsigned short* __restrict__ ylo,
                  float* __restrict__ yf,
                  int OPD, int OPRX, int po, long sstride)
{
    constexpr int K = CIN * 64;
    constexpr int MWAVES = COUT / (16 * MTW);
    constexpr int RPB = 4 / MWAVES;
    constexpr int KN = (CIN * 2) / KSPLIT;

    int bx = blockIdx.x;
    const int ks = (KSPLIT > 1) ? (bx % KSPLIT) : 0;
    const int rowblk = (KSPLIT > 1) ? (bx / KSPLIT) : bx;
    const int lane = (int)threadIdx.x & 63, w = (int)threadIdx.x >> 6;
    const int mi = (MWAVES == 4) ? w : 0;
    const int ri = (MWAVES == 4) ? 0 : w;
    const int rowid = rowblk * RPB + ri;
    const int n16 = lane & 15, quad = lane >> 4;

    int b, od, oh, ow;
    if (OWHALF) {
        constexpr int NOH = DOUT / 2;
        const int ohb = rowid % NOH; int t = rowid / NOH;
        od = t % DOUT; b = t / DOUT;
        oh = ohb * 2 + (n16 >> 3);
        ow = n16 & 7;
    } else {
        const int owt = rowid % OWT; int t = rowid / OWT;
        oh = t % DOUT; t /= DOUT;
        od = t % DOUT; b = t / DOUT;
        ow = owt * 16 + n16;
    }

    const int co0 = mi * (MTW * 16);

    f32x4 acc[MTW];
    #pragma unroll
    for (int mt = 0; mt < MTW; ++mt)
        #pragma unroll
        for (int r = 0; r < 4; ++r) {
            int co = co0 + mt * 16 + quad * 4 + r;
            acc[mt][r] = (ks == 0) ? bias[co] : 0.0f;
        }

    const int sg0 = ks * KN;
    const long chs = (long)PD * PD * PRX;
    long off = ((long)(b * CIN + (sg0 >> 1)) * PD + (2 * od + (quad >> 1))) * PD * PRX
             + (long)(2 * oh + (quad & 1) * 2) * PRX + 2 * ow;
    const unsigned short* phi = xhi + off;
    const unsigned short* plo = xlo + off;
    const long incA = 2L * PD * PRX;
    const long incB = chs - 2L * PD * PRX;

    const short* a0h = Whi + (long)(co0 + n16) * K + sg0 * 32 + quad * 8;
    const short* a0l = Wlo + (long)(co0 + n16) * K + sg0 * 32 + quad * 8;

    #pragma unroll 2
    for (int s = 0; s < KN; ++s) {
        u16x4u h0 = *(const u16x4u*)phi;
        u16x4u h1 = *(const u16x4u*)(phi + PRX);
        u16x4u l0 = *(const u16x4u*)plo;
        u16x4u l1 = *(const u16x4u*)(plo + PRX);
        bf16x8 bhi = pack_b(h0, h1);
        bf16x8 blo = pack_b(l0, l1);
        #pragma unroll
        for (int mt = 0; mt < MTW; ++mt) {
            bf16x8 ah = *(const bf16x8*)(a0h + (long)mt * 16 * K + s * 32);
            bf16x8 al = *(const bf16x8*)(a0l + (long)mt * 16 * K + s * 32);
            acc[mt] = __builtin_amdgcn_mfma_f32_16x16x32_bf16(ah, bhi, acc[mt], 0, 0, 0);
            acc[mt] = __builtin_amdgcn_mfma_f32_16x16x32_bf16(ah, blo, acc[mt], 0, 0, 0);
            acc[mt] = __builtin_amdgcn_mfma_f32_16x16x32_bf16(al, bhi, acc[mt], 0, 0, 0);
        }
        long inc = (s & 1) ? incB : incA;
        phi += inc; plo += inc;
    }

    if (OUTSPLIT) {
        #pragma unroll
        for (int mt = 0; mt < MTW; ++mt)
            #pragma unroll
            for (int r = 0; r < 4; ++r) {
                int co = co0 + mt * 16 + quad * 4 + r;
                float v = fmaxf(acc[mt][r], 0.0f);
                unsigned short h, l;
                split_bf16(v, h, l);
                long o = (((long)(b * COUT + co) * OPD + od + po) * OPD + oh + po) * OPRX
                       + ow + po;
                yhi[o] = h; ylo[o] = l;
            }
    } else {
        #pragma unroll
        for (int mt = 0; mt < MTW; ++mt)
            #pragma unroll
            for (int r = 0; r < 4; ++r) {
                int co = co0 + mt * 16 + quad * 4 + r;
                long o = (long)ks * sstride
                       + (((long)(b * COUT + co) * OPD + od) * OPD + oh) * OPRX + ow;
                yf[o] = acc[mt][r];
            }
    }
}

__global__ __launch_bounds__(256)
void combine4_relu(const float* __restrict__ p, float* __restrict__ y, long N, long ss)
{
    long idx = (long)blockIdx.x * blockDim.x + threadIdx.x;
    if (idx >= N) return;
    float v = p[idx] + p[idx + ss] + p[idx + 2 * ss] + p[idx + 3 * ss];
    y[idx] = fmaxf(v, 0.0f);
}

// ---------------- 1x1 conv (fp32 exact) ----------------
__global__ __launch_bounds__(128)
void conv1x1_b(const float* __restrict__ x, const float* __restrict__ w,
               const float* __restrict__ bias, float* __restrict__ y)
{
    const int co = blockIdx.x & 255, b = blockIdx.x >> 8;
    const int s4 = (int)threadIdx.x * 4;
    const float* xb = x + (long)b * 256 * 512 + s4;
    const float* wr = w + (long)co * 256;      // uniform -> s_load
    float bv = bias[co];
    float4 acc = {bv, bv, bv, bv};
    for (int ci = 0; ci < 256; ++ci) {
        float wv = wr[ci];
        float4 xv = *(const float4*)(xb + (long)ci * 512);
        acc.x = fmaf(xv.x, wv, acc.x); acc.y = fmaf(xv.y, wv, acc.y);
        acc.z = fmaf(xv.z, wv, acc.z); acc.w = fmaf(xv.w, wv, acc.w);
    }
    *(float4*)(y + (long)(b * 256 + co) * 512 + s4) = acc;
}

// ---------------- VQ (fp32 exact; unchanged) ----------------
__global__ void codenorm_kernel(const float* __restrict__ cb, float* __restrict__ norms)
{
    int k = blockIdx.x;
    int lane = threadIdx.x;
    float s = 0.0f;
    const float* row = cb + (long)k * 256;
    for (int d = lane; d < 256; d += 64) { float v = row[d]; s = fmaf(v, v, s); }
    for (int off = 32; off > 0; off >>= 1) s += __shfl_down(s, off);
    if (lane == 0) norms[k] = s;
}

__global__ __launch_bounds__(256)
void vq_kernel(const float* __restrict__ lat, const float* __restrict__ cb,
               const float* __restrict__ norms, unsigned short* __restrict__ q,
               float* __restrict__ idx_out)
{
    __shared__ __align__(16) float row[256];
    __shared__ float s_best[256];
    __shared__ int   s_bidx[256];
    int r = blockIdx.x;
    int t = threadIdx.x;
    row[t] = lat[(long)r * 256 + t];
    __syncthreads();

    const float4* rowv = (const float4*)row;
    float latn = 0.0f;
    #pragma unroll 4
    for (int d = 0; d < 64; ++d) {
        float4 rv = rowv[d];
        latn = fmaf(rv.x, rv.x, latn); latn = fmaf(rv.y, rv.y, latn);
        latn = fmaf(rv.z, rv.z, latn); latn = fmaf(rv.w, rv.w, latn);
    }

    float best = FLT_MAX;
    int bidx = 0x7fffffff;
    for (int j = 0; j < 4; ++j) {
        int k = t + 256 * j;
        const float4* cr = (const float4*)(cb + (long)k * 256);
        float dot = 0.0f;
        #pragma unroll 4
        for (int d = 0; d < 64; ++d) {
            float4 c = cr[d]; float4 rv = rowv[d];
            dot = fmaf(rv.x, c.x, dot); dot = fmaf(rv.y, c.y, dot);
            dot = fmaf(rv.z, c.z, dot); dot = fmaf(rv.w, c.w, dot);
        }
        float sc = latn - 2.0f * dot + norms[k];
        if (sc < best || (sc == best && k < bidx)) { best = sc; bidx = k; }
    }
    s_best[t] = best; s_bidx[t] = bidx;
    __syncthreads();
    for (int off = 128; off > 0; off >>= 1) {
        if (t < off) {
            float o = s_best[t + off]; int oi = s_bidx[t + off];
            if (o < s_best[t] || (o == s_best[t] && oi < s_bidx[t])) {
                s_best[t] = o; s_bidx[t] = oi;
            }
        }
        __syncthreads();
    }
    int bk = s_bidx[0];
    int b = r >> 9, n = r & 511;
    int zz = n >> 6, yy = (n >> 3) & 7, xx = n & 7;
    q[(long)(b * 256 + t) * 1000 + ((long)(zz + 1) * 10 + (yy + 1)) * 10 + (xx + 1)]
        = f32_to_bf16(cb[(long)bk * 256 + t]);
    if (t == 0) idx_out[r] = (float)bk;
}

// ---------------- decoder: MFMA implicit-GEMM ConvTranspose ----------------
// xflip=0: B slot a <-> x offset (1-ax), kw=(1-px)+2*ax (old cube kernel).
// xflip=1: B slot a <-> x offset ax,     kw=(1-px)+2*(1-ax) (dword-pair kernel).
__global__ __launch_bounds__(256)
void prep_convt_w(const float* __restrict__ w, short* __restrict__ Ap,
                  int Cin, int Cout, int xflip)
{
    const int K = Cin * 8;
    long total = 8L * Cout * K;
    long idx = (long)blockIdx.x * blockDim.x + threadIdx.x;
    if (idx >= total) return;
    int k = (int)(idx % K);
    int co = (int)((idx / K) % Cout);
    int p = (int)(idx / ((long)K * Cout));
    int ci = k >> 3, a = k & 7;
    int az = (a >> 2) & 1, ay = (a >> 1) & 1, ax = a & 1;
    int pz = p >> 2, py = (p >> 1) & 1, px = p & 1;
    int axw = xflip ? (1 - ax) : ax;
    int kd = (1 - pz) + 2 * az, kh = (1 - py) + 2 * ay, kw = (1 - px) + 2 * axw;
    float v = w[((long)ci * Cout + co) * 64 + kd * 16 + kh * 4 + kw];
    Ap[idx] = (short)f32_to_bf16(v);
}

// Old cube-N layout (kept for dec1, DIN=8): nt-slab XCD swizzle + px inner.
template <int CIN, int COUT, int DIN, int OPAD, typename OutT>
__global__ __launch_bounds__(256)
void convt_mfma(const unsigned short* __restrict__ Xp, const short* __restrict__ Ap,
                const float* __restrict__ bias, OutT* __restrict__ Y)
{
    constexpr int PD = DIN + 2;
    constexpr int PD3 = PD * PD * PD;
    constexpr int T = DIN >> 2;
    constexpr int NT = T * T * T;
    constexpr int SLAB = NT / 8;
    constexpr int OPD = 2 * DIN + 2 * OPAD;
    constexpr int K = CIN * 8;
    constexpr int MG = COUT >> 6;
    constexpr int nsteps = K >> 5;

    int bx = blockIdx.x;
    const int xcd = bx & 7;
    int local = bx >> 3;
    const int px = local & 1; local >>= 1;
    const int mg = local % MG; local /= MG;
    const int ntin = local % SLAB;
    const int pzy = local / SLAB;            // 0..3
    const int pz = pzy >> 1, py = pzy & 1;
    const int p = pz * 4 + py * 2 + px;
    const int nt = xcd * SLAB + ntin;

    const int lane = threadIdx.x & 63, wave = threadIdx.x >> 6;
    const int n16 = lane & 15, quad = lane >> 4;

    const int tx = nt % T, ty = (nt / T) % T, tz = nt / (T * T);
    const int mz = tz * 4 + wave, my = ty * 4 + (n16 >> 2), mx = tx * 4 + (n16 & 3);
    const int sp = ((mz + pz) * PD + (my + py)) * PD + (mx + px);

    const unsigned short* xq = Xp + (long)quad * PD3 + sp;

    const int cobase = mg * 64;
    const short* ap0 = Ap + ((long)p * COUT + cobase + n16) * K + quad * 8;

    f32x4 acc[4];
    #pragma unroll
    for (int cb = 0; cb < 4; ++cb) {
        const float* bp = bias + cobase + cb * 16 + quad * 4;
        acc[cb][0] = bp[0]; acc[cb][1] = bp[1]; acc[cb][2] = bp[2]; acc[cb][3] = bp[3];
    }

    #pragma unroll 4
    for (int s = 0; s < nsteps; ++s) {
        const unsigned short* xs = xq + (long)s * 4 * PD3;
        bf16x8 bf;
        bf[0] = (short)xs[(PD + 1) * PD + 1];
        bf[1] = (short)xs[(PD + 1) * PD];
        bf[2] = (short)xs[PD * PD + 1];
        bf[3] = (short)xs[PD * PD];
        bf[4] = (short)xs[PD + 1];
        bf[5] = (short)xs[PD];
        bf[6] = (short)xs[1];
        bf[7] = (short)xs[0];
        #pragma unroll
        for (int cb = 0; cb < 4; ++cb) {
            bf16x8 af = *(const bf16x8*)(ap0 + (long)cb * 16 * K + s * 32);
            acc[cb] = __builtin_amdgcn_mfma_f32_16x16x32_bf16(af, bf, acc[cb], 0, 0, 0);
        }
    }

    const int opz = 2 * mz + pz + OPAD, opy = 2 * my + py + OPAD, opx = 2 * mx + px + OPAD;
    const long spo = ((long)opz * OPD + opy) * OPD + opx;
    #pragma unroll
    for (int cb = 0; cb < 4; ++cb) {
        #pragma unroll
        for (int r = 0; r < 4; ++r) {
            int co = cobase + cb * 16 + quad * 4 + r;
            float v = fmaxf(acc[cb][r], 0.0f);
            store_act(Y + (long)co * OPD * OPD * OPD + spo, v);
        }
    }
}

// Dword-pair B-gather (dec2/dec3). MXP mx-tiles or MYP my-tiles per wave
// share each A-load. Per (z,y)-row ONE aligned u16x4 load; x-tap pair
// {px,px+1} extracted via 64-bit shift. xflip=1 A-table.
template <int CIN, int COUT, int DIN, int OPAD, int MXP, int MYP, typename OutT>
__global__ __launch_bounds__(256)
void convt_mfma_v2(const unsigned short* __restrict__ Xp, const short* __restrict__ Ap,
                   const float* __restrict__ bias, OutT* __restrict__ Y)
{
    constexpr int PD = DIN + 2;
    constexpr int PD3 = PD * PD * PD;
    constexpr int OPD = 2 * DIN + 2 * OPAD;
    constexpr int K = CIN * 8;
    constexpr int MG = COUT >> 6;
    constexpr int nsteps = K >> 5;
    constexpr int MXT = DIN / (16 * MXP);
    constexpr int MYT = DIN / (4 * MYP);
    constexpr int MZS = DIN / 8;             // mz per XCD slab
    constexpr int TPE = MXP * MYP;           // tiles per wave (one of MXP/MYP is 1)

    int bx = blockIdx.x;
    const int xcd = bx & 7;
    int local = bx >> 3;
    const int px = local & 1; local >>= 1;
    const int py = local & 1; local >>= 1;
    const int mg = local % MG; local /= MG;
    const int mxt = local % MXT; local /= MXT;
    const int myt = local % MYT; local /= MYT;
    const int pz = local & 1; local >>= 1;
    const int mzin = local;                  // 0..MZS-1
    const int mz = xcd * MZS + mzin;
    const int p = pz * 4 + py * 2 + px;

    const int lane = threadIdx.x & 63, wave = threadIdx.x >> 6;
    const int n16 = lane & 15, quad = lane >> 4;

    const int mx0 = mxt * (16 * MXP) + n16;
    const int my0 = myt * (4 * MYP) + wave * MYP;
    const int baseX = mx0 & ~1;
    const int sh = 16 * ((n16 & 1) + px);    // 0, 16, or 32
    const long sp = ((long)(mz + pz) * PD + (my0 + py)) * PD + baseX;

    const unsigned short* xq = Xp + (long)quad * PD3 + sp;

    const int cobase = mg * 64;
    const short* ap0 = Ap + ((long)p * COUT + cobase + n16) * K + quad * 8;

    f32x4 acc[TPE][4];
    #pragma unroll
    for (int t = 0; t < TPE; ++t)
        #pragma unroll
        for (int cb = 0; cb < 4; ++cb) {
            const float* bp = bias + cobase + cb * 16 + quad * 4;
            acc[t][cb][0] = bp[0]; acc[t][cb][1] = bp[1];
            acc[t][cb][2] = bp[2]; acc[t][cb][3] = bp[3];
        }

    constexpr int rowoff[4] = { (PD + 1) * PD, PD * PD, PD, 0 };

    #pragma unroll 4
    for (int s = 0; s < nsteps; ++s) {
        const unsigned short* xs = xq + (long)s * 4 * PD3;
        union Frag { unsigned u[4]; bf16x8 b; } fr[TPE];
        #pragma unroll
        for (int t = 0; t < TPE; ++t) {
            const int toff = (MXP > 1) ? t * 16 : t * PD;
            #pragma unroll
            for (int j = 0; j < 4; ++j) {
                union { u16x4u v; unsigned long long u64; } ld;
                ld.v = *(const u16x4u*)(xs + toff + rowoff[j]);
                fr[t].u[j] = (unsigned)(ld.u64 >> sh);
            }
        }
        #pragma unroll
        for (int cb = 0; cb < 4; ++cb) {
            bf16x8 af = *(const bf16x8*)(ap0 + (long)cb * 16 * K + s * 32);
            #pragma unroll
            for (int t = 0; t < TPE; ++t)
                acc[t][cb] = __builtin_amdgcn_mfma_f32_16x16x32_bf16(af, fr[t].b,
                                                                     acc[t][cb], 0, 0, 0);
        }
    }

    const int opz = 2 * mz + pz + OPAD;
    #pragma unroll
    for (int t = 0; t < TPE; ++t) {
        const int opx = 2 * (mx0 + ((MXP > 1) ? t * 16 : 0)) + px + OPAD;
        const int opy = 2 * (my0 + ((MYP > 1) ? t : 0)) + py + OPAD;
        const long spo = ((long)opz * OPD + opy) * OPD + opx;
        #pragma unroll
        for (int cb = 0; cb < 4; ++cb) {
            #pragma unroll
            for (int r = 0; r < 4; ++r) {
                int co = cobase + cb * 16 + quad * 4 + r;
                float v = fmaxf(acc[t][cb][r], 0.0f);
                store_act(Y + (long)co * OPD * OPD * OPD + spo, v);
            }
        }
    }
}

// ---------------- dec4 as MFMA GEMM: 4 oh rows per wave (unchanged) ---------
__global__ __launch_bounds__(256)
void prep_dec4A(const float* __restrict__ w, short* __restrict__ Aw)
{
    int idx = blockIdx.x * 256 + (int)threadIdx.x;    // 0..65535
    int m = idx >> 12, k = idx & 4095;
    float v = (m < 3) ? w[m * 4096 + k] : 0.0f;
    Aw[idx] = (short)f32_to_bf16(v);
}

__global__ __launch_bounds__(256)
void conv_dec4_mfma(const float* __restrict__ d3, const short* __restrict__ Aw,
                    const float* __restrict__ bias, float* __restrict__ y)
{
    constexpr int D = 64, Dout = 61;
    int bx = blockIdx.x;
    const int slab = bx & 7;
    const int i = bx >> 3;                 // 0..127
    const int od = slab * 8 + (i >> 4);
    const int oh0 = (i & 15) * 4;          // covers oh0..oh0+3 (guard < 61)
    if (od >= Dout) return;
    const int lane = (int)threadIdx.x & 63, wave = (int)threadIdx.x >> 6;
    const int n16 = lane & 15, quad = lane >> 4;
    const int ow = wave * 16 + n16;

    f32x4 acc[4];
    #pragma unroll
    for (int j = 0; j < 4; ++j)
        #pragma unroll
        for (int r = 0; r < 4; ++r) {
            int co = quad * 4 + r;
            acc[j][r] = (co < 3) ? bias[co] : 0.0f;
        }

    const short* ap = Aw + (long)n16 * 4096 + quad * 8;   // m = lane&15
    const int kd0 = quad >> 1;
    const int kh0 = (quad & 1) * 2;
    const float* basez = d3 + ((long)(od + kd0) * D) * D + ow;
    int yoff[5];
    #pragma unroll
    for (int r = 0; r < 5; ++r) yoff[r] = min(oh0 + kh0 + r, D - 1) * D;

    #pragma unroll 4
    for (int s = 0; s < 128; ++s) {
        const int ci = s >> 1;
        const float* plane = basez + ((long)ci * D + (s & 1) * 2) * D * D;
        unsigned p0[5], p1[5];
        #pragma unroll
        for (int r = 0; r < 5; ++r) {
            f32x4u v = *(const f32x4u*)(plane + yoff[r]);
            p0[r] = (__float_as_uint(v[0]) >> 16) | (__float_as_uint(v[1]) & 0xffff0000u);
            p1[r] = (__float_as_uint(v[2]) >> 16) | (__float_as_uint(v[3]) & 0xffff0000u);
        }
        bf16x8 af = *(const bf16x8*)(ap + s * 32);
        #pragma unroll
        for (int j = 0; j < 4; ++j) {
            union { unsigned u[4]; bf16x8 b; } fr;
            fr.u[0] = p0[j];     fr.u[1] = p1[j];
            fr.u[2] = p0[j + 1]; fr.u[3] = p1[j + 1];
            acc[j] = __builtin_amdgcn_mfma_f32_16x16x32_bf16(af, fr.b, acc[j], 0, 0, 0);
        }
    }

    if (ow < Dout && quad == 0) {
        #pragma unroll
        for (int j = 0; j < 4; ++j) {
            const int oh = oh0 + j;
            if (oh >= Dout) continue;
            #pragma unroll
            for (int r = 0; r < 3; ++r)
                y[((long)(r * Dout + od) * Dout + oh) * Dout + ow] = tanhf(acc[j][r]);
        }
    }
}

extern "C" void kernel_launch(void* const* d_in, const int* in_sizes, int n_in,
                              void* d_out, int out_size, void* d_ws, size_t ws_size,
                              hipStream_t stream)
{
    const float* x        = (const float*)d_in[0];
    const float* enc_w1   = (const float*)d_in[1];
    const float* enc_b1   = (const float*)d_in[2];
    const float* enc_w2   = (const float*)d_in[3];
    const float* enc_b2   = (const float*)d_in[4];
    const float* enc_w3   = (const float*)d_in[5];
    const float* enc_b3   = (const float*)d_in[6];
    const float* enc_w4   = (const float*)d_in[7];
    const float* enc_b4   = (const float*)d_in[8];
    const float* codebook = (const float*)d_in[9];
    const float* dec_w1   = (const float*)d_in[10];
    const float* dec_b1   = (const float*)d_in[11];
    const float* dec_w2   = (const float*)d_in[12];
    const float* dec_b2   = (const float*)d_in[13];
    const float* dec_w3   = (const float*)d_in[14];
    const float* dec_b3   = (const float*)d_in[15];
    const float* dec_w4   = (const float*)d_in[16];
    const float* dec_b4   = (const float*)d_in[17];

    float* out = (float*)d_out;
    float* idx_out = out + 2L * 3 * 61 * 61 * 61;

    // ---- workspace (byte offsets) ----
    char* wsb = (char*)d_ws;
    float*          cn   = (float*)wsb;                        //      4,096
    unsigned short* qp   = (unsigned short*)(wsb + 4096);      //  1,024,000
    short*          Ap1  = (short*)(wsb + 1028096);            //  8,388,608
    short*          Ap2  = (short*)(wsb + 9416704);            //  4,194,304
    short*          Ap3  = (short*)(wsb + 13611008);           //  1,048,576
    short*          Aw4  = (short*)(wsb + 14659584);           //    131,072
    short*          W1hi = (short*)(wsb + 14790656);           //     24,576
    short*          W1lo = (short*)(wsb + 14815232);           //     24,576
    short*          W2hi = (short*)(wsb + 14839808);           //  1,048,576
    short*          W2lo = (short*)(wsb + 15888384);           //  1,048,576
    short*          W3hi = (short*)(wsb + 16936960);           //  4,194,304
    short*          W3lo = (short*)(wsb + 21131264);           //  4,194,304
    char* arena = wsb + 25325568;
    // encoder phase:
    unsigned short* xphi = (unsigned short*)arena;                    // (2,3,66,66,68)
    unsigned short* xplo = (unsigned short*)(arena + 3554496);
    unsigned short* h1hi = (unsigned short*)(arena + 7108992);        // (2,64,34,34,36)
    unsigned short* h1lo = (unsigned short*)(arena + 17762688);
    unsigned short* h2hi = (unsigned short*)(arena + 28416384);       // (2,128,18,18,20)
    unsigned short* h2lo = (unsigned short*)(arena + 31734144);
    float*          pp3  = (float*)(arena + 35051904);                // 4x(2,256,8^3)
    float*          h3   = (float*)(arena + 39246208);                // (2,256,512)
    float*          lat  = (float*)(arena + 40294784);                // (2,256,512)
    // decoder phase (after VQ; overlaps encoder buffers):
    unsigned short* d1 = (unsigned short*)arena;                      // (256,18^3) bf16
    unsigned short* d2 = (unsigned short*)(arena + 2985984);          // (128,34^3) bf16
    float*          d3 = (float*)(arena + 13047808);                  // (64,64^3) fp32
    // arena peak 80.2 MB; total 105.5 MB (< 112.2 MB proven in R0)

    dim3 blk(256);
    auto nblk = [](long n) { return dim3((unsigned)((n + 255) / 256)); };

    // ---- weight prep ----
    prep_convt_w<<<nblk(8L * 256 * 2048), blk, 0, stream>>>(dec_w1, Ap1, 256, 256, 0);
    prep_convt_w<<<nblk(8L * 128 * 2048), blk, 0, stream>>>(dec_w2, Ap2, 256, 128, 1);
    prep_convt_w<<<nblk(8L * 64 * 1024), blk, 0, stream>>>(dec_w3, Ap3, 128, 64, 1);
    prep_dec4A<<<dim3(256), blk, 0, stream>>>(dec_w4, Aw4);
    prep_split_w<<<nblk(12288), blk, 0, stream>>>(enc_w1, W1hi, W1lo, 12288);
    prep_split_w<<<nblk(524288), blk, 0, stream>>>(enc_w2, W2hi, W2lo, 524288);
    prep_split_w<<<nblk(2097152), blk, 0, stream>>>(enc_w3, W3hi, W3lo, 2097152);

    // ---- encoder (MFMA, bf16-pair) ----
    pad_input_split<<<nblk(6L * 66 * 66 * 68), blk, 0, stream>>>(x, xphi, xplo);
    zero_halo_ps<<<nblk(128L * 34 * 34 * 36), blk, 0, stream>>>(h1hi, 128, 34, 36);
    zero_halo_ps<<<nblk(128L * 34 * 34 * 36), blk, 0, stream>>>(h1lo, 128, 34, 36);
    conv_s2_mfma<3, 64, 32, 66, 68, 4, 2, 0, 1, 1><<<dim3(1024), blk, 0, stream>>>(
        xphi, xplo, W1hi, W1lo, enc_b1, h1hi, h1lo, nullptr, 34, 36, 1, 0);
    zero_halo_ps<<<nblk(256L * 18 * 18 * 20), blk, 0, stream>>>(h2hi, 256, 18, 20);
    zero_halo_ps<<<nblk(256L * 18 * 18 * 20), blk, 0, stream>>>(h2lo, 256, 18, 20);
    conv_s2_mfma<64, 128, 16, 34, 36, 2, 1, 0, 1, 1><<<dim3(512), blk, 0, stream>>>(
        h1hi, h1lo, W2hi, W2lo, enc_b2, h2hi, h2lo, nullptr, 18, 20, 1, 0);
    conv_s2_mfma<128, 256, 8, 18, 20, 4, 1, 1, 4, 0><<<dim3(256), blk, 0, stream>>>(
        h2hi, h2lo, W3hi, W3lo, enc_b3, nullptr, nullptr, pp3, 8, 8, 0, 262144);
    combine4_relu<<<nblk(262144), blk, 0, stream>>>(pp3, h3, 262144, 262144);
    conv1x1_b<<<dim3(512), dim3(128), 0, stream>>>(h3, enc_w4, enc_b4, lat);

    // ---- VQ (fp32 exact) ----
    codenorm_kernel<<<dim3(1024), dim3(64), 0, stream>>>(codebook, cn);
    zero_halo_t<unsigned short><<<nblk(512L * 10 * 10 * 10), blk, 0, stream>>>(qp, 512, 10);
    vq_kernel<<<dim3(1024), blk, 0, stream>>>(lat, codebook, cn, qp, idx_out);

    // ---- decoder halos ----
    zero_halo_t<unsigned short><<<nblk(256L * 18 * 18 * 18), blk, 0, stream>>>(d1, 256, 18);
    zero_halo_t<unsigned short><<<nblk(128L * 34 * 34 * 34), blk, 0, stream>>>(d2, 128, 34);

    // ---- decoder (MFMA) per batch ----
    for (int b = 0; b < 2; ++b) {
        const unsigned short* qb = qp + (long)b * 256 * 1000;
        float* outb = out + (long)b * 3 * 226981;
        // dec1 (DIN=8, old layout): grid = 8*2*4*1*4 = 256
        convt_mfma<256, 256, 8, 1, unsigned short><<<dim3(256), blk, 0, stream>>>(
            qb, Ap1, dec_b1, d1);
        // dec2 (v2, MXP=1 MYP=2): grid = 8 * (2*2*2*1*2*2*2) = 512
        convt_mfma_v2<256, 128, 16, 1, 1, 2, unsigned short><<<dim3(512), blk, 0, stream>>>(
            d1, Ap2, dec_b2, d2);
        // dec3 (v2, MXP=2 MYP=1): grid = 8 * (2*2*1*1*8*2*4) = 2048
        convt_mfma_v2<128, 64, 32, 0, 2, 1, float><<<dim3(2048), blk, 0, stream>>>(
            d2, Ap3, dec_b3, d3);
        conv_dec4_mfma<<<dim3(8 * 8 * 16), blk, 0, stream>>>(d3, Aw4, dec_b4, outb);
    }
}

// Round 17
// 1459.215 us; speedup vs baseline: 1.6886x; 1.0397x over previous
//
#include <hip/hip_runtime.h>
#include <cfloat>
#include <cmath>

// ---------------------------------------------------------------------------
// Round 16: hand-pipelined convt_mfma_v2.
// R16 showed dec2 AND dec3 both at ~192 us, VGPR=52: the compiler capped
// registers for 8-wave occupancy and kept only ONE step's loads in flight
// (one L2 round trip per K-step, serial). Fix: explicit 2-stage double-
// buffered pipeline (step s+1's 12 loads issue before step s's MFMAs) +
// __launch_bounds__(256,4) to raise the VGPR cap to 128. Per-accumulator
// K-order unchanged => bit-identical. Everything else = R16.
// ---------------------------------------------------------------------------

using f32x4  = __attribute__((ext_vector_type(4))) float;
using bf16x8 = __attribute__((ext_vector_type(8))) short;
typedef float f32x4u __attribute__((ext_vector_type(4), aligned(4)));
typedef unsigned short u16x4u __attribute__((ext_vector_type(4), aligned(4)));

__device__ __forceinline__ unsigned short f32_to_bf16(float f) {
    unsigned int u = __float_as_uint(f);
    u += 0x7fffu + ((u >> 16) & 1u);          // round-to-nearest-even
    return (unsigned short)(u >> 16);
}
__device__ __forceinline__ void split_bf16(float v, unsigned short& h, unsigned short& l) {
    h = f32_to_bf16(v);
    float hf = __uint_as_float((unsigned)h << 16);
    l = f32_to_bf16(v - hf);
}
__device__ __forceinline__ void store_act(float* p, float v) { *p = v; }
__device__ __forceinline__ void store_act(unsigned short* p, float v) { *p = f32_to_bf16(v); }

template <typename V>
__device__ __forceinline__ bf16x8 pack_b(V r0, V r1) {
    bf16x8 b;
    b[0] = (short)r0[0]; b[1] = (short)r0[1]; b[2] = (short)r0[2]; b[3] = (short)r0[3];
    b[4] = (short)r1[0]; b[5] = (short)r1[1]; b[6] = (short)r1[2]; b[7] = (short)r1[3];
    return b;
}

// ---------------- prep: weight hi/lo split ----------------
__global__ __launch_bounds__(256)
void prep_split_w(const float* __restrict__ w, short* __restrict__ whi,
                  short* __restrict__ wlo, long total)
{
    long idx = (long)blockIdx.x * blockDim.x + threadIdx.x;
    if (idx >= total) return;
    unsigned short h, l;
    split_bf16(w[idx], h, l);
    whi[idx] = (short)h; wlo[idx] = (short)l;
}

// ---------------- pad input -> hi/lo bf16 pitched planes --------------------
__global__ __launch_bounds__(256)
void pad_input_split(const float* __restrict__ x, unsigned short* __restrict__ xhi,
                     unsigned short* __restrict__ xlo)
{
    const int D = 64, PD = 66, PRX = 68, BC = 6;
    long total = (long)BC * PD * PD * PRX;
    long idx = (long)blockIdx.x * blockDim.x + threadIdx.x;
    if (idx >= total) return;
    int px = (int)(idx % PRX); long t = idx / PRX;
    int py = (int)(t % PD); t /= PD;
    int pz = (int)(t % PD); int c = (int)(t / PD);
    int ix = px - 1, iy = py - 1, iz = pz - 1;
    float v = 0.0f;
    if ((unsigned)ix < (unsigned)D && (unsigned)iy < (unsigned)D && (unsigned)iz < (unsigned)D)
        v = x[(((long)c * D + iz) * D + iy) * D + ix];
    unsigned short h, l;
    split_bf16(v, h, l);
    xhi[idx] = h; xlo[idx] = l;
}

__global__ __launch_bounds__(256)
void zero_halo_ps(unsigned short* __restrict__ p, int C, int PD, int PRX)
{
    long total = (long)C * PD * PD * PRX;
    long idx = (long)blockIdx.x * blockDim.x + threadIdx.x;
    if (idx >= total) return;
    int px = (int)(idx % PRX); long t = idx / PRX;
    int py = (int)(t % PD); t /= PD;
    int pz = (int)(t % PD);
    if (px == 0 || px >= PD - 1 || py == 0 || py == PD - 1 || pz == 0 || pz == PD - 1)
        p[idx] = 0;
}

template <typename T>
__global__ __launch_bounds__(256) void zero_halo_t(T* __restrict__ p, int C, int PD)
{
    long total = (long)C * PD * PD * PD;
    long idx = (long)blockIdx.x * blockDim.x + threadIdx.x;
    if (idx >= total) return;
    int px = (int)(idx % PD); long t = idx / PD;
    int py = (int)(t % PD); t /= PD;
    int pz = (int)(t % PD);
    if (px == 0 || px == PD - 1 || py == 0 || py == PD - 1 || pz == 0 || pz == PD - 1)
        p[idx] = (T)0;
}

// ---------------------------------------------------------------------------
// Conv3d k4 s2 p1 as MFMA implicit GEMM, bf16 hi/lo pair inputs (unchanged)
// ---------------------------------------------------------------------------
template <int CIN, int COUT, int DOUT, int PD, int PRX, int MTW, int OWT,
          int OWHALF, int KSPLIT, int OUTSPLIT>
__global__ __launch_bounds__(256)
void conv_s2_mfma(const unsigned short* __restrict__ xhi,
                  const unsigned short* __restrict__ xlo,
                  const short* __restrict__ Whi, const short* __restrict__ Wlo,
                  const float* __restrict__ bias,
                  unsigned short* __restrict__ yhi, unsigned short* __restrict__ ylo,
                  float* __restrict__ yf,
                  int OPD, int OPRX, int po, long sstride)
{
    constexpr int K = CIN * 64;
    constexpr int MWAVES = COUT / (16 * MTW);
    constexpr int RPB = 4 / MWAVES;
    constexpr int KN = (CIN * 2) / KSPLIT;

    int bx = blockIdx.x;
    const int ks = (KSPLIT > 1) ? (bx % KSPLIT) : 0;
    const int rowblk = (KSPLIT > 1) ? (bx / KSPLIT) : bx;
    const int lane = (int)threadIdx.x & 63, w = (int)threadIdx.x >> 6;
    const int mi = (MWAVES == 4) ? w : 0;
    const int ri = (MWAVES == 4) ? 0 : w;
    const int rowid = rowblk * RPB + ri;
    const int n16 = lane & 15, quad = lane >> 4;

    int b, od, oh, ow;
    if (OWHALF) {
        constexpr int NOH = DOUT / 2;
        const int ohb = rowid % NOH; int t = rowid / NOH;
        od = t % DOUT; b = t / DOUT;
        oh = ohb * 2 + (n16 >> 3);
        ow = n16 & 7;
    } else {
        const int owt = rowid % OWT; int t = rowid / OWT;
        oh = t % DOUT; t /= DOUT;
        od = t % DOUT; b = t / DOUT;
        ow = owt * 16 + n16;
    }

    const int co0 = mi * (MTW * 16);

    f32x4 acc[MTW];
    #pragma unroll
    for (int mt = 0; mt < MTW; ++mt)
        #pragma unroll
        for (int r = 0; r < 4; ++r) {
            int co = co0 + mt * 16 + quad * 4 + r;
            acc[mt][r] = (ks == 0) ? bias[co] : 0.0f;
        }

    const int sg0 = ks * KN;
    const long chs = (long)PD * PD * PRX;
    long off = ((long)(b * CIN + (sg0 >> 1)) * PD + (2 * od + (quad >> 1))) * PD * PRX
             + (long)(2 * oh + (quad & 1) * 2) * PRX + 2 * ow;
    const unsigned short* phi = xhi + off;
    const unsigned short* plo = xlo + off;
    const long incA = 2L * PD * PRX;
    const long incB = chs - 2L * PD * PRX;

    const short* a0h = Whi + (long)(co0 + n16) * K + sg0 * 32 + quad * 8;
    const short* a0l = Wlo + (long)(co0 + n16) * K + sg0 * 32 + quad * 8;

    #pragma unroll 2
    for (int s = 0; s < KN; ++s) {
        u16x4u h0 = *(const u16x4u*)phi;
        u16x4u h1 = *(const u16x4u*)(phi + PRX);
        u16x4u l0 = *(const u16x4u*)plo;
        u16x4u l1 = *(const u16x4u*)(plo + PRX);
        bf16x8 bhi = pack_b(h0, h1);
        bf16x8 blo = pack_b(l0, l1);
        #pragma unroll
        for (int mt = 0; mt < MTW; ++mt) {
            bf16x8 ah = *(const bf16x8*)(a0h + (long)mt * 16 * K + s * 32);
            bf16x8 al = *(const bf16x8*)(a0l + (long)mt * 16 * K + s * 32);
            acc[mt] = __builtin_amdgcn_mfma_f32_16x16x32_bf16(ah, bhi, acc[mt], 0, 0, 0);
            acc[mt] = __builtin_amdgcn_mfma_f32_16x16x32_bf16(ah, blo, acc[mt], 0, 0, 0);
            acc[mt] = __builtin_amdgcn_mfma_f32_16x16x32_bf16(al, bhi, acc[mt], 0, 0, 0);
        }
        long inc = (s & 1) ? incB : incA;
        phi += inc; plo += inc;
    }

    if (OUTSPLIT) {
        #pragma unroll
        for (int mt = 0; mt < MTW; ++mt)
            #pragma unroll
            for (int r = 0; r < 4; ++r) {
                int co = co0 + mt * 16 + quad * 4 + r;
                float v = fmaxf(acc[mt][r], 0.0f);
                unsigned short h, l;
                split_bf16(v, h, l);
                long o = (((long)(b * COUT + co) * OPD + od + po) * OPD + oh + po) * OPRX
                       + ow + po;
                yhi[o] = h; ylo[o] = l;
            }
    } else {
        #pragma unroll
        for (int mt = 0; mt < MTW; ++mt)
            #pragma unroll
            for (int r = 0; r < 4; ++r) {
                int co = co0 + mt * 16 + quad * 4 + r;
                long o = (long)ks * sstride
                       + (((long)(b * COUT + co) * OPD + od) * OPD + oh) * OPRX + ow;
                yf[o] = acc[mt][r];
            }
    }
}

__global__ __launch_bounds__(256)
void combine4_relu(const float* __restrict__ p, float* __restrict__ y, long N, long ss)
{
    long idx = (long)blockIdx.x * blockDim.x + threadIdx.x;
    if (idx >= N) return;
    float v = p[idx] + p[idx + ss] + p[idx + 2 * ss] + p[idx + 3 * ss];
    y[idx] = fmaxf(v, 0.0f);
}

// ---------------- 1x1 conv (fp32 exact) ----------------
__global__ __launch_bounds__(128)
void conv1x1_b(const float* __restrict__ x, const float* __restrict__ w,
               const float* __restrict__ bias, float* __restrict__ y)
{
    const int co = blockIdx.x & 255, b = blockIdx.x >> 8;
    const int s4 = (int)threadIdx.x * 4;
    const float* xb = x + (long)b * 256 * 512 + s4;
    const float* wr = w + (long)co * 256;      // uniform -> s_load
    float bv = bias[co];
    float4 acc = {bv, bv, bv, bv};
    for (int ci = 0; ci < 256; ++ci) {
        float wv = wr[ci];
        float4 xv = *(const float4*)(xb + (long)ci * 512);
        acc.x = fmaf(xv.x, wv, acc.x); acc.y = fmaf(xv.y, wv, acc.y);
        acc.z = fmaf(xv.z, wv, acc.z); acc.w = fmaf(xv.w, wv, acc.w);
    }
    *(float4*)(y + (long)(b * 256 + co) * 512 + s4) = acc;
}

// ---------------- VQ (fp32 exact; unchanged) ----------------
__global__ void codenorm_kernel(const float* __restrict__ cb, float* __restrict__ norms)
{
    int k = blockIdx.x;
    int lane = threadIdx.x;
    float s = 0.0f;
    const float* row = cb + (long)k * 256;
    for (int d = lane; d < 256; d += 64) { float v = row[d]; s = fmaf(v, v, s); }
    for (int off = 32; off > 0; off >>= 1) s += __shfl_down(s, off);
    if (lane == 0) norms[k] = s;
}

__global__ __launch_bounds__(256)
void vq_kernel(const float* __restrict__ lat, const float* __restrict__ cb,
               const float* __restrict__ norms, unsigned short* __restrict__ q,
               float* __restrict__ idx_out)
{
    __shared__ __align__(16) float row[256];
    __shared__ float s_best[256];
    __shared__ int   s_bidx[256];
    int r = blockIdx.x;
    int t = threadIdx.x;
    row[t] = lat[(long)r * 256 + t];
    __syncthreads();

    const float4* rowv = (const float4*)row;
    float latn = 0.0f;
    #pragma unroll 4
    for (int d = 0; d < 64; ++d) {
        float4 rv = rowv[d];
        latn = fmaf(rv.x, rv.x, latn); latn = fmaf(rv.y, rv.y, latn);
        latn = fmaf(rv.z, rv.z, latn); latn = fmaf(rv.w, rv.w, latn);
    }

    float best = FLT_MAX;
    int bidx = 0x7fffffff;
    for (int j = 0; j < 4; ++j) {
        int k = t + 256 * j;
        const float4* cr = (const float4*)(cb + (long)k * 256);
        float dot = 0.0f;
        #pragma unroll 4
        for (int d = 0; d < 64; ++d) {
            float4 c = cr[d]; float4 rv = rowv[d];
            dot = fmaf(rv.x, c.x, dot); dot = fmaf(rv.y, c.y, dot);
            dot = fmaf(rv.z, c.z, dot); dot = fmaf(rv.w, c.w, dot);
        }
        float sc = latn - 2.0f * dot + norms[k];
        if (sc < best || (sc == best && k < bidx)) { best = sc; bidx = k; }
    }
    s_best[t] = best; s_bidx[t] = bidx;
    __syncthreads();
    for (int off = 128; off > 0; off >>= 1) {
        if (t < off) {
            float o = s_best[t + off]; int oi = s_bidx[t + off];
            if (o < s_best[t] || (o == s_best[t] && oi < s_bidx[t])) {
                s_best[t] = o; s_bidx[t] = oi;
            }
        }
        __syncthreads();
    }
    int bk = s_bidx[0];
    int b = r >> 9, n = r & 511;
    int zz = n >> 6, yy = (n >> 3) & 7, xx = n & 7;
    q[(long)(b * 256 + t) * 1000 + ((long)(zz + 1) * 10 + (yy + 1)) * 10 + (xx + 1)]
        = f32_to_bf16(cb[(long)bk * 256 + t]);
    if (t == 0) idx_out[r] = (float)bk;
}

// ---------------- decoder: MFMA implicit-GEMM ConvTranspose ----------------
// xflip=0: B slot a <-> x offset (1-ax), kw=(1-px)+2*ax (old cube kernel).
// xflip=1: B slot a <-> x offset ax,     kw=(1-px)+2*(1-ax) (dword-pair kernel).
__global__ __launch_bounds__(256)
void prep_convt_w(const float* __restrict__ w, short* __restrict__ Ap,
                  int Cin, int Cout, int xflip)
{
    const int K = Cin * 8;
    long total = 8L * Cout * K;
    long idx = (long)blockIdx.x * blockDim.x + threadIdx.x;
    if (idx >= total) return;
    int k = (int)(idx % K);
    int co = (int)((idx / K) % Cout);
    int p = (int)(idx / ((long)K * Cout));
    int ci = k >> 3, a = k & 7;
    int az = (a >> 2) & 1, ay = (a >> 1) & 1, ax = a & 1;
    int pz = p >> 2, py = (p >> 1) & 1, px = p & 1;
    int axw = xflip ? (1 - ax) : ax;
    int kd = (1 - pz) + 2 * az, kh = (1 - py) + 2 * ay, kw = (1 - px) + 2 * axw;
    float v = w[((long)ci * Cout + co) * 64 + kd * 16 + kh * 4 + kw];
    Ap[idx] = (short)f32_to_bf16(v);
}

// Old cube-N layout (kept for dec1, DIN=8): nt-slab XCD swizzle + px inner.
template <int CIN, int COUT, int DIN, int OPAD, typename OutT>
__global__ __launch_bounds__(256)
void convt_mfma(const unsigned short* __restrict__ Xp, const short* __restrict__ Ap,
                const float* __restrict__ bias, OutT* __restrict__ Y)
{
    constexpr int PD = DIN + 2;
    constexpr int PD3 = PD * PD * PD;
    constexpr int T = DIN >> 2;
    constexpr int NT = T * T * T;
    constexpr int SLAB = NT / 8;
    constexpr int OPD = 2 * DIN + 2 * OPAD;
    constexpr int K = CIN * 8;
    constexpr int MG = COUT >> 6;
    constexpr int nsteps = K >> 5;

    int bx = blockIdx.x;
    const int xcd = bx & 7;
    int local = bx >> 3;
    const int px = local & 1; local >>= 1;
    const int mg = local % MG; local /= MG;
    const int ntin = local % SLAB;
    const int pzy = local / SLAB;            // 0..3
    const int pz = pzy >> 1, py = pzy & 1;
    const int p = pz * 4 + py * 2 + px;
    const int nt = xcd * SLAB + ntin;

    const int lane = threadIdx.x & 63, wave = threadIdx.x >> 6;
    const int n16 = lane & 15, quad = lane >> 4;

    const int tx = nt % T, ty = (nt / T) % T, tz = nt / (T * T);
    const int mz = tz * 4 + wave, my = ty * 4 + (n16 >> 2), mx = tx * 4 + (n16 & 3);
    const int sp = ((mz + pz) * PD + (my + py)) * PD + (mx + px);

    const unsigned short* xq = Xp + (long)quad * PD3 + sp;

    const int cobase = mg * 64;
    const short* ap0 = Ap + ((long)p * COUT + cobase + n16) * K + quad * 8;

    f32x4 acc[4];
    #pragma unroll
    for (int cb = 0; cb < 4; ++cb) {
        const float* bp = bias + cobase + cb * 16 + quad * 4;
        acc[cb][0] = bp[0]; acc[cb][1] = bp[1]; acc[cb][2] = bp[2]; acc[cb][3] = bp[3];
    }

    #pragma unroll 4
    for (int s = 0; s < nsteps; ++s) {
        const unsigned short* xs = xq + (long)s * 4 * PD3;
        bf16x8 bf;
        bf[0] = (short)xs[(PD + 1) * PD + 1];
        bf[1] = (short)xs[(PD + 1) * PD];
        bf[2] = (short)xs[PD * PD + 1];
        bf[3] = (short)xs[PD * PD];
        bf[4] = (short)xs[PD + 1];
        bf[5] = (short)xs[PD];
        bf[6] = (short)xs[1];
        bf[7] = (short)xs[0];
        #pragma unroll
        for (int cb = 0; cb < 4; ++cb) {
            bf16x8 af = *(const bf16x8*)(ap0 + (long)cb * 16 * K + s * 32);
            acc[cb] = __builtin_amdgcn_mfma_f32_16x16x32_bf16(af, bf, acc[cb], 0, 0, 0);
        }
    }

    const int opz = 2 * mz + pz + OPAD, opy = 2 * my + py + OPAD, opx = 2 * mx + px + OPAD;
    const long spo = ((long)opz * OPD + opy) * OPD + opx;
    #pragma unroll
    for (int cb = 0; cb < 4; ++cb) {
        #pragma unroll
        for (int r = 0; r < 4; ++r) {
            int co = cobase + cb * 16 + quad * 4 + r;
            float v = fmaxf(acc[cb][r], 0.0f);
            store_act(Y + (long)co * OPD * OPD * OPD + spo, v);
        }
    }
}

// Dword-pair B-gather (dec2/dec3) with explicit 2-stage software pipeline.
// launch_bounds(256,4): VGPR cap 128 so both stages' loads stay in flight.
template <int CIN, int COUT, int DIN, int OPAD, int MXP, int MYP, typename OutT>
__global__ __launch_bounds__(256, 4)
void convt_mfma_v2(const unsigned short* __restrict__ Xp, const short* __restrict__ Ap,
                   const float* __restrict__ bias, OutT* __restrict__ Y)
{
    constexpr int PD = DIN + 2;
    constexpr int PD3 = PD * PD * PD;
    constexpr int OPD = 2 * DIN + 2 * OPAD;
    constexpr int K = CIN * 8;
    constexpr int MG = COUT >> 6;
    constexpr int nsteps = K >> 5;           // even for all our layers
    constexpr int MXT = DIN / (16 * MXP);
    constexpr int MYT = DIN / (4 * MYP);
    constexpr int MZS = DIN / 8;             // mz per XCD slab
    constexpr int TPE = MXP * MYP;           // tiles per wave (one of MXP/MYP is 1)

    int bx = blockIdx.x;
    const int xcd = bx & 7;
    int local = bx >> 3;
    const int px = local & 1; local >>= 1;
    const int py = local & 1; local >>= 1;
    const int mg = local % MG; local /= MG;
    const int mxt = local % MXT; local /= MXT;
    const int myt = local % MYT; local /= MYT;
    const int pz = local & 1; local >>= 1;
    const int mzin = local;                  // 0..MZS-1
    const int mz = xcd * MZS + mzin;
    const int p = pz * 4 + py * 2 + px;

    const int lane = threadIdx.x & 63, wave = threadIdx.x >> 6;
    const int n16 = lane & 15, quad = lane >> 4;

    const int mx0 = mxt * (16 * MXP) + n16;
    const int my0 = myt * (4 * MYP) + wave * MYP;
    const int baseX = mx0 & ~1;
    const int sh = 16 * ((n16 & 1) + px);    // 0, 16, or 32
    const long sp = ((long)(mz + pz) * PD + (my0 + py)) * PD + baseX;

    const unsigned short* xq = Xp + (long)quad * PD3 + sp;

    const int cobase = mg * 64;
    const short* ap0 = Ap + ((long)p * COUT + cobase + n16) * K + quad * 8;

    f32x4 acc[TPE][4];
    #pragma unroll
    for (int t = 0; t < TPE; ++t)
        #pragma unroll
        for (int cb = 0; cb < 4; ++cb) {
            const float* bp = bias + cobase + cb * 16 + quad * 4;
            acc[t][cb][0] = bp[0]; acc[t][cb][1] = bp[1];
            acc[t][cb][2] = bp[2]; acc[t][cb][3] = bp[3];
        }

    constexpr int rowoff[4] = { (PD + 1) * PD, PD * PD, PD, 0 };

    union Frag { unsigned u[4]; bf16x8 b; };
    Frag fr0[TPE], fr1[TPE];
    bf16x8 a0[4], a1[4];

    auto loadStep = [&](int s, Frag* fr, bf16x8* af) {
        const unsigned short* xs = xq + (long)s * 4 * PD3;
        #pragma unroll
        for (int t = 0; t < TPE; ++t) {
            const int toff = (MXP > 1) ? t * 16 : t * PD;
            #pragma unroll
            for (int j = 0; j < 4; ++j) {
                union { u16x4u v; unsigned long long u64; } ld;
                ld.v = *(const u16x4u*)(xs + toff + rowoff[j]);
                fr[t].u[j] = (unsigned)(ld.u64 >> sh);
            }
        }
        #pragma unroll
        for (int cb = 0; cb < 4; ++cb)
            af[cb] = *(const bf16x8*)(ap0 + (long)cb * 16 * K + s * 32);
    };

    loadStep(0, fr0, a0);
    for (int s = 0; s < nsteps; s += 2) {
        loadStep(s + 1, fr1, a1);                 // next step's loads in flight
        #pragma unroll
        for (int cb = 0; cb < 4; ++cb)
            #pragma unroll
            for (int t = 0; t < TPE; ++t)
                acc[t][cb] = __builtin_amdgcn_mfma_f32_16x16x32_bf16(a0[cb], fr0[t].b,
                                                                     acc[t][cb], 0, 0, 0);
        if (s + 2 < nsteps) loadStep(s + 2, fr0, a0);
        #pragma unroll
        for (int cb = 0; cb < 4; ++cb)
            #pragma unroll
            for (int t = 0; t < TPE; ++t)
                acc[t][cb] = __builtin_amdgcn_mfma_f32_16x16x32_bf16(a1[cb], fr1[t].b,
                                                                     acc[t][cb], 0, 0, 0);
    }

    const int opz = 2 * mz + pz + OPAD;
    #pragma unroll
    for (int t = 0; t < TPE; ++t) {
        const int opx = 2 * (mx0 + ((MXP > 1) ? t * 16 : 0)) + px + OPAD;
        const int opy = 2 * (my0 + ((MYP > 1) ? t : 0)) + py + OPAD;
        const long spo = ((long)opz * OPD + opy) * OPD + opx;
        #pragma unroll
        for (int cb = 0; cb < 4; ++cb) {
            #pragma unroll
            for (int r = 0; r < 4; ++r) {
                int co = cobase + cb * 16 + quad * 4 + r;
                float v = fmaxf(acc[t][cb][r], 0.0f);
                store_act(Y + (long)co * OPD * OPD * OPD + spo, v);
            }
        }
    }
}

// ---------------- dec4 as MFMA GEMM: 4 oh rows per wave (unchanged) ---------
__global__ __launch_bounds__(256)
void prep_dec4A(const float* __restrict__ w, short* __restrict__ Aw)
{
    int idx = blockIdx.x * 256 + (int)threadIdx.x;    // 0..65535
    int m = idx >> 12, k = idx & 4095;
    float v = (m < 3) ? w[m * 4096 + k] : 0.0f;
    Aw[idx] = (short)f32_to_bf16(v);
}

__global__ __launch_bounds__(256)
void conv_dec4_mfma(const float* __restrict__ d3, const short* __restrict__ Aw,
                    const float* __restrict__ bias, float* __restrict__ y)
{
    constexpr int D = 64, Dout = 61;
    int bx = blockIdx.x;
    const int slab = bx & 7;
    const int i = bx >> 3;                 // 0..127
    const int od = slab * 8 + (i >> 4);
    const int oh0 = (i & 15) * 4;          // covers oh0..oh0+3 (guard < 61)
    if (od >= Dout) return;
    const int lane = (int)threadIdx.x & 63, wave = (int)threadIdx.x >> 6;
    const int n16 = lane & 15, quad = lane >> 4;
    const int ow = wave * 16 + n16;

    f32x4 acc[4];
    #pragma unroll
    for (int j = 0; j < 4; ++j)
        #pragma unroll
        for (int r = 0; r < 4; ++r) {
            int co = quad * 4 + r;
            acc[j][r] = (co < 3) ? bias[co] : 0.0f;
        }

    const short* ap = Aw + (long)n16 * 4096 + quad * 8;   // m = lane&15
    const int kd0 = quad >> 1;
    const int kh0 = (quad & 1) * 2;
    const float* basez = d3 + ((long)(od + kd0) * D) * D + ow;
    int yoff[5];
    #pragma unroll
    for (int r = 0; r < 5; ++r) yoff[r] = min(oh0 + kh0 + r, D - 1) * D;

    #pragma unroll 4
    for (int s = 0; s < 128; ++s) {
        const int ci = s >> 1;
        const float* plane = basez + ((long)ci * D + (s & 1) * 2) * D * D;
        unsigned p0[5], p1[5];
        #pragma unroll
        for (int r = 0; r < 5; ++r) {
            f32x4u v = *(const f32x4u*)(plane + yoff[r]);
            p0[r] = (__float_as_uint(v[0]) >> 16) | (__float_as_uint(v[1]) & 0xffff0000u);
            p1[r] = (__float_as_uint(v[2]) >> 16) | (__float_as_uint(v[3]) & 0xffff0000u);
        }
        bf16x8 af = *(const bf16x8*)(ap + s * 32);
        #pragma unroll
        for (int j = 0; j < 4; ++j) {
            union { unsigned u[4]; bf16x8 b; } fr;
            fr.u[0] = p0[j];     fr.u[1] = p1[j];
            fr.u[2] = p0[j + 1]; fr.u[3] = p1[j + 1];
            acc[j] = __builtin_amdgcn_mfma_f32_16x16x32_bf16(af, fr.b, acc[j], 0, 0, 0);
        }
    }

    if (ow < Dout && quad == 0) {
        #pragma unroll
        for (int j = 0; j < 4; ++j) {
            const int oh = oh0 + j;
            if (oh >= Dout) continue;
            #pragma unroll
            for (int r = 0; r < 3; ++r)
                y[((long)(r * Dout + od) * Dout + oh) * Dout + ow] = tanhf(acc[j][r]);
        }
    }
}

extern "C" void kernel_launch(void* const* d_in, const int* in_sizes, int n_in,
                              void* d_out, int out_size, void* d_ws, size_t ws_size,
                              hipStream_t stream)
{
    const float* x        = (const float*)d_in[0];
    const float* enc_w1   = (const float*)d_in[1];
    const float* enc_b1   = (const float*)d_in[2];
    const float* enc_w2   = (const float*)d_in[3];
    const float* enc_b2   = (const float*)d_in[4];
    const float* enc_w3   = (const float*)d_in[5];
    const float* enc_b3   = (const float*)d_in[6];
    const float* enc_w4   = (const float*)d_in[7];
    const float* enc_b4   = (const float*)d_in[8];
    const float* codebook = (const float*)d_in[9];
    const float* dec_w1   = (const float*)d_in[10];
    const float* dec_b1   = (const float*)d_in[11];
    const float* dec_w2   = (const float*)d_in[12];
    const float* dec_b2   = (const float*)d_in[13];
    const float* dec_w3   = (const float*)d_in[14];
    const float* dec_b3   = (const float*)d_in[15];
    const float* dec_w4   = (const float*)d_in[16];
    const float* dec_b4   = (const float*)d_in[17];

    float* out = (float*)d_out;
    float* idx_out = out + 2L * 3 * 61 * 61 * 61;

    // ---- workspace (byte offsets) ----
    char* wsb = (char*)d_ws;
    float*          cn   = (float*)wsb;                        //      4,096
    unsigned short* qp   = (unsigned short*)(wsb + 4096);      //  1,024,000
    short*          Ap1  = (short*)(wsb + 1028096);            //  8,388,608
    short*          Ap2  = (short*)(wsb + 9416704);            //  4,194,304
    short*          Ap3  = (short*)(wsb + 13611008);           //  1,048,576
    short*          Aw4  = (short*)(wsb + 14659584);           //    131,072
    short*          W1hi = (short*)(wsb + 14790656);           //     24,576
    short*          W1lo = (short*)(wsb + 14815232);           //     24,576
    short*          W2hi = (short*)(wsb + 14839808);           //  1,048,576
    short*          W2lo = (short*)(wsb + 15888384);           //  1,048,576
    short*          W3hi = (short*)(wsb + 16936960);           //  4,194,304
    short*          W3lo = (short*)(wsb + 21131264);           //  4,194,304
    char* arena = wsb + 25325568;
    // encoder phase:
    unsigned short* xphi = (unsigned short*)arena;                    // (2,3,66,66,68)
    unsigned short* xplo = (unsigned short*)(arena + 3554496);
    unsigned short* h1hi = (unsigned short*)(arena + 7108992);        // (2,64,34,34,36)
    unsigned short* h1lo = (unsigned short*)(arena + 17762688);
    unsigned short* h2hi = (unsigned short*)(arena + 28416384);       // (2,128,18,18,20)
    unsigned short* h2lo = (unsigned short*)(arena + 31734144);
    float*          pp3  = (float*)(arena + 35051904);                // 4x(2,256,8^3)
    float*          h3   = (float*)(arena + 39246208);                // (2,256,512)
    float*          lat  = (float*)(arena + 40294784);                // (2,256,512)
    // decoder phase (after VQ; overlaps encoder buffers):
    unsigned short* d1 = (unsigned short*)arena;                      // (256,18^3) bf16
    unsigned short* d2 = (unsigned short*)(arena + 2985984);          // (128,34^3) bf16
    float*          d3 = (float*)(arena + 13047808);                  // (64,64^3) fp32
    // arena peak 80.2 MB; total 105.5 MB (< 112.2 MB proven in R0)

    dim3 blk(256);
    auto nblk = [](long n) { return dim3((unsigned)((n + 255) / 256)); };

    // ---- weight prep ----
    prep_convt_w<<<nblk(8L * 256 * 2048), blk, 0, stream>>>(dec_w1, Ap1, 256, 256, 0);
    prep_convt_w<<<nblk(8L * 128 * 2048), blk, 0, stream>>>(dec_w2, Ap2, 256, 128, 1);
    prep_convt_w<<<nblk(8L * 64 * 1024), blk, 0, stream>>>(dec_w3, Ap3, 128, 64, 1);
    prep_dec4A<<<dim3(256), blk, 0, stream>>>(dec_w4, Aw4);
    prep_split_w<<<nblk(12288), blk, 0, stream>>>(enc_w1, W1hi, W1lo, 12288);
    prep_split_w<<<nblk(524288), blk, 0, stream>>>(enc_w2, W2hi, W2lo, 524288);
    prep_split_w<<<nblk(2097152), blk, 0, stream>>>(enc_w3, W3hi, W3lo, 2097152);

    // ---- encoder (MFMA, bf16-pair) ----
    pad_input_split<<<nblk(6L * 66 * 66 * 68), blk, 0, stream>>>(x, xphi, xplo);
    zero_halo_ps<<<nblk(128L * 34 * 34 * 36), blk, 0, stream>>>(h1hi, 128, 34, 36);
    zero_halo_ps<<<nblk(128L * 34 * 34 * 36), blk, 0, stream>>>(h1lo, 128, 34, 36);
    conv_s2_mfma<3, 64, 32, 66, 68, 4, 2, 0, 1, 1><<<dim3(1024), blk, 0, stream>>>(
        xphi, xplo, W1hi, W1lo, enc_b1, h1hi, h1lo, nullptr, 34, 36, 1, 0);
    zero_halo_ps<<<nblk(256L * 18 * 18 * 20), blk, 0, stream>>>(h2hi, 256, 18, 20);
    zero_halo_ps<<<nblk(256L * 18 * 18 * 20), blk, 0, stream>>>(h2lo, 256, 18, 20);
    conv_s2_mfma<64, 128, 16, 34, 36, 2, 1, 0, 1, 1><<<dim3(512), blk, 0, stream>>>(
        h1hi, h1lo, W2hi, W2lo, enc_b2, h2hi, h2lo, nullptr, 18, 20, 1, 0);
    conv_s2_mfma<128, 256, 8, 18, 20, 4, 1, 1, 4, 0><<<dim3(256), blk, 0, stream>>>(
        h2hi, h2lo, W3hi, W3lo, enc_b3, nullptr, nullptr, pp3, 8, 8, 0, 262144);
    combine4_relu<<<nblk(262144), blk, 0, stream>>>(pp3, h3, 262144, 262144);
    conv1x1_b<<<dim3(512), dim3(128), 0, stream>>>(h3, enc_w4, enc_b4, lat);

    // ---- VQ (fp32 exact) ----
    codenorm_kernel<<<dim3(1024), dim3(64), 0, stream>>>(codebook, cn);
    zero_halo_t<unsigned short><<<nblk(512L * 10 * 10 * 10), blk, 0, stream>>>(qp, 512, 10);
    vq_kernel<<<dim3(1024), blk, 0, stream>>>(lat, codebook, cn, qp, idx_out);

    // ---- decoder halos ----
    zero_halo_t<unsigned short><<<nblk(256L * 18 * 18 * 18), blk, 0, stream>>>(d1, 256, 18);
    zero_halo_t<unsigned short><<<nblk(128L * 34 * 34 * 34), blk, 0, stream>>>(d2, 128, 34);

    // ---- decoder (MFMA) per batch ----
    for (int b = 0; b < 2; ++b) {
        const unsigned short* qb = qp + (long)b * 256 * 1000;
        float* outb = out + (long)b * 3 * 226981;
        // dec1 (DIN=8, old layout): grid = 8*2*4*1*4 = 256
        convt_mfma<256, 256, 8, 1, unsigned short><<<dim3(256), blk, 0, stream>>>(
            qb, Ap1, dec_b1, d1);
        // dec2 (v2, MXP=1 MYP=2): grid = 8 * (2*2*2*1*2*2*2) = 512
        convt_mfma_v2<256, 128, 16, 1, 1, 2, unsigned short><<<dim3(512), blk, 0, stream>>>(
            d1, Ap2, dec_b2, d2);
        // dec3 (v2, MXP=2 MYP=1): grid = 8 * (2*2*1*1*8*2*4) = 2048
        convt_mfma_v2<128, 64, 32, 0, 2, 1, float><<<dim3(2048), blk, 0, stream>>>(
            d2, Ap3, dec_b3, d3);
        conv_dec4_mfma<<<dim3(8 * 8 * 16), blk, 0, stream>>>(d3, Aw4, dec_b4, outb);
    }
}